// Round 10
// baseline (473.384 us; speedup 1.0000x reference)
//
#include <hip/hip_runtime.h>
#include <cmath>

#define N_NODES 8192
#define N_EDGES 131072
#define NB      256
#define NH      128
#define D3      384
#define D6      768
#define SMM     96   // max nodes per (graph,side); Binomial(8192,1/256) mean 32, 96 = 11 sigma

typedef __attribute__((ext_vector_type(8))) short short8v;
typedef __attribute__((ext_vector_type(4))) float f32x4;
typedef unsigned short bf16t;

__device__ __forceinline__ float sigf(float x){ return 1.0f/(1.0f+__expf(-x)); }
__device__ __forceinline__ unsigned short f2bf(float x){
  unsigned u = __float_as_uint(x);
  unsigned r = u + 0x7FFF + ((u>>16)&1);   // round-to-nearest-even
  return (unsigned short)(r>>16);
}
__device__ __forceinline__ float bfl(unsigned u){ return __uint_as_float(u<<16); }
__device__ __forceinline__ float bfh(unsigned u){ return __uint_as_float(u & 0xFFFF0000u); }
__device__ __forceinline__ float b2f(bf16t u){ return __uint_as_float(((unsigned)u)<<16); }

// ---------- setup ----------

__global__ void k_init(float* deg1, float* deg2, int* ecnt1, int* ecnt2, int* cnt1, int* cnt2){
  int t = blockIdx.x*blockDim.x + threadIdx.x;
  if (t < N_NODES){ deg1[t]=1.f; deg2[t]=1.f; ecnt1[t]=0; ecnt2[t]=0; }
  if (t < NB){ cnt1[t]=0; cnt2[t]=0; }
}

__global__ void k_deg(const int* __restrict__ ei1, const float* __restrict__ ea1, float* deg1, int* ecnt1,
                      const int* __restrict__ ei2, const float* __restrict__ ea2, float* deg2, int* ecnt2,
                      const int* __restrict__ b1, const int* __restrict__ b2, int* cnt1, int* cnt2){
  int idx = blockIdx.x*blockDim.x + threadIdx.x;
  int side = idx >= N_EDGES;
  int e = idx & (N_EDGES-1);
  const int* ei = side? ei2:ei1; const float* ea = side? ea2:ea1;
  float* deg = side? deg2:deg1;  int* ecnt = side? ecnt2:ecnt1;
  int d = ei[N_EDGES+e];
  atomicAdd(&deg[d], ea[e]);
  atomicAdd(&ecnt[d], 1);
  if (idx < N_NODES){ atomicAdd(&cnt1[b1[idx]],1); atomicAdd(&cnt2[b2[idx]],1); }
}

__global__ void k_dinv(float* deg1, float* deg2){
  int t = blockIdx.x*blockDim.x + threadIdx.x;
  if (t < N_NODES){ deg1[t]=rsqrtf(deg1[t]); deg2[t]=rsqrtf(deg2[t]); }
}

__global__ __launch_bounds__(256) void k_scan256(const int* c1, const int* c2, int* s1, int* s2){
  const int* c = blockIdx.x? c2:c1; int* st = blockIdx.x? s2:s1;
  __shared__ int ps[256];
  int t = threadIdx.x;
  ps[t]=c[t]; __syncthreads();
  for (int d=1; d<256; d<<=1){
    int v = (t>=d)? ps[t-d]:0;
    __syncthreads();
    ps[t]+=v;
    __syncthreads();
  }
  st[t+1]=ps[t];
  if (t==0) st[0]=0;
}

__global__ __launch_bounds__(1024) void k_escan(const int* ec1, const int* ec2,
                                                int* off1, int* cur1, int* off2, int* cur2){
  const int* cnt = blockIdx.x? ec2:ec1;
  int* off = blockIdx.x? off2:off1;
  int* cur = blockIdx.x? cur2:cur1;
  __shared__ int ps[1024];
  int t = threadIdx.x;
  int base = t*8;
  int loc[8]; int s=0;
  #pragma unroll
  for (int k=0;k<8;k++){ loc[k]=s; s+=cnt[base+k]; }
  ps[t]=s; __syncthreads();
  for (int d=1; d<1024; d<<=1){
    int v = (t>=d)? ps[t-d]:0;
    __syncthreads();
    ps[t]+=v;
    __syncthreads();
  }
  int pre = (t==0)? 0 : ps[t-1];
  #pragma unroll
  for (int k=0;k<8;k++){ int v=pre+loc[k]; off[base+k]=v; cur[base+k]=v; }
  if (t==1023) off[N_NODES]=ps[1023];
}

__global__ void k_fill(const int* __restrict__ ei1, const float* __restrict__ ea1, const float* __restrict__ d1,
                       int* cur1, int* es1, float* ec1,
                       const int* __restrict__ ei2, const float* __restrict__ ea2, const float* __restrict__ d2,
                       int* cur2, int* es2, float* ec2){
  int idx = blockIdx.x*blockDim.x + threadIdx.x;
  int side = idx >= N_EDGES;
  int e = idx & (N_EDGES-1);
  const int* ei = side? ei2:ei1; const float* ea = side? ea2:ea1;
  const float* dinv = side? d2:d1;
  int* cur = side? cur2:cur1; int* es = side? es2:es1; float* ec = side? ec2:ec1;
  int s = ei[e], d = ei[N_EDGES+e];
  int pos = atomicAdd(&cur[d], 1);
  es[pos] = s;
  ec[pos] = dinv[s]*ea[e]*dinv[d];
}

// ---------- GCN ----------

__global__ __launch_bounds__(128) void k_xw(const float* __restrict__ x1, const float* __restrict__ x2,
                                            int xs, int K, const float* __restrict__ W,
                                            float* __restrict__ xw1, float* __restrict__ xw2){
  __shared__ float xr[8][128];
  int blk = blockIdx.x;
  int side = blk >> 10; int b = blk & 1023;
  const float* x = side? x2:x1;
  float* xw = side? xw2:xw1;
  int i0 = b*8;
  int c = threadIdx.x;
  for (int idx=c; idx<8*K; idx+=128){
    int r = idx / K, k = idx - r*K;
    xr[r][k] = x[(size_t)(i0+r)*xs + k];
  }
  __syncthreads();
  float acc[8]={0,0,0,0,0,0,0,0};
  for (int k=0;k<K;k++){
    float w = W[k*NH+c];
    #pragma unroll
    for (int r=0;r<8;r++) acc[r]+=xr[r][k]*w;
  }
  #pragma unroll
  for (int r=0;r<8;r++) xw[(size_t)(i0+r)*NH+c]=acc[r];
}

__global__ __launch_bounds__(256) void k_gather(const float* __restrict__ xw1, const float* __restrict__ xw2,
                                                const int* __restrict__ off1, const int* __restrict__ off2,
                                                const int* __restrict__ es1, const int* __restrict__ es2,
                                                const float* __restrict__ ec1, const float* __restrict__ ec2,
                                                const float* __restrict__ d1, const float* __restrict__ d2,
                                                const float* __restrict__ b,
                                                float* __restrict__ h1, float* __restrict__ h2, int loff){
  int blk = blockIdx.x;
  int side = blk >> 10; int bb = blk & 1023;
  const float4* xw = (const float4*)(side? xw2:xw1);
  const int* off = side? off2:off1;
  const int* es  = side? es2:es1;
  const float* ec= side? ec2:ec1;
  const float* dinv = side? d2:d1;
  float* h = side? h2:h1;
  int t = threadIdx.x;
  int i = bb*8 + (t>>5);
  int c4 = t & 31;
  float dv = dinv[i];
  float4 v = xw[(size_t)i*32 + c4];
  float sc = dv*dv;
  float4 acc = {v.x*sc, v.y*sc, v.z*sc, v.w*sc};
  int r = off[i], r1 = off[i+1];
  for (; r+3<r1; r+=4){
    int s0=es[r], s1=es[r+1], s2=es[r+2], s3=es[r+3];
    float w0=ec[r], w1=ec[r+1], w2=ec[r+2], w3=ec[r+3];
    float4 u0 = xw[(size_t)s0*32 + c4];
    float4 u1 = xw[(size_t)s1*32 + c4];
    float4 u2 = xw[(size_t)s2*32 + c4];
    float4 u3 = xw[(size_t)s3*32 + c4];
    acc.x += u0.x*w0 + u1.x*w1 + u2.x*w2 + u3.x*w3;
    acc.y += u0.y*w0 + u1.y*w1 + u2.y*w2 + u3.y*w3;
    acc.z += u0.z*w0 + u1.z*w1 + u2.z*w2 + u3.z*w3;
    acc.w += u0.w*w0 + u1.w*w1 + u2.w*w2 + u3.w*w3;
  }
  for (; r<r1; r++){
    int s0=es[r]; float w0=ec[r];
    float4 u0 = xw[(size_t)s0*32 + c4];
    acc.x+=u0.x*w0; acc.y+=u0.y*w0; acc.z+=u0.z*w0; acc.w+=u0.w*w0;
  }
  float4 bv = ((const float4*)b)[c4];
  acc.x+=bv.x; acc.y+=bv.y; acc.z+=bv.z; acc.w+=bv.w;
  acc.x = (acc.x>0.f)?acc.x:0.2f*acc.x;
  acc.y = (acc.y>0.f)?acc.y:0.2f*acc.y;
  acc.z = (acc.z>0.f)?acc.z:0.2f*acc.z;
  acc.w = (acc.w>0.f)?acc.w:0.2f*acc.w;
  ((float4*)(h + (size_t)i*D3 + loff))[c4] = acc;
}

// ---------- l2 normalize -> bf16 f[:, 0:384] ----------
__global__ __launch_bounds__(128) void k_l2norm(const float* __restrict__ h1, const float* __restrict__ h2,
                                                bf16t* __restrict__ f1, bf16t* __restrict__ f2){
  int blk = blockIdx.x;
  int side = blk >> 13; int i = blk & (N_NODES-1);
  const float* h = side? h2:h1; bf16t* f = side? f2:f1;
  int t = threadIdx.x;
  float v0=h[(size_t)i*D3+t], v1=h[(size_t)i*D3+128+t], v2=h[(size_t)i*D3+256+t];
  float ss = v0*v0+v1*v1+v2*v2;
  #pragma unroll
  for (int o=32;o;o>>=1) ss += __shfl_down(ss,o,64);
  __shared__ float ws[2];
  if ((t&63)==0) ws[t>>6]=ss;
  __syncthreads();
  float scale = 1.0f/fmaxf(sqrtf(ws[0]+ws[1]), 1e-12f);
  f[(size_t)i*D6+t]      = f2bf(v0*scale);
  f[(size_t)i*D6+128+t]  = f2bf(v1*scale);
  f[(size_t)i*D6+256+t]  = f2bf(v2*scale);
}

// ---------- interaction part 1: S = A.B^T (bf16 in, bf16 out), thread-per-dot 16x16 tiles ----------
__global__ __launch_bounds__(256) void k_smat(const bf16t* __restrict__ f1, const bf16t* __restrict__ f2,
                                              const int* __restrict__ st1, const int* __restrict__ st2,
                                              bf16t* __restrict__ S){
  int g = blockIdx.x;
  int tile = blockIdx.y;
  int it = tile/6, jt = tile - it*6;
  int i0 = st1[g]; int n1 = st1[g+1]-i0; if (n1>SMM) n1=SMM;
  int j0 = st2[g]; int n2 = st2[g+1]-j0; if (n2>SMM) n2=SMM;
  if (it*16 >= n1 || jt*16 >= n2) return;
  __shared__ float4 As[16*97];
  __shared__ float4 Bs[16*97];
  const bf16t* A = f1 + (size_t)(i0 + it*16)*D6;
  const bf16t* B = f2 + (size_t)(j0 + jt*16)*D6;
  int na = n1 - it*16; if (na>16) na=16;
  int nb = n2 - jt*16; if (nb>16) nb=16;
  int t = threadIdx.x;
  for (int idx=t; idx<16*48; idx+=256){
    int r = idx/48, q = idx - r*48;    // q over uint4 = 8 bf16
    uint4 ra = (r<na)? ((const uint4*)(A + (size_t)r*D6))[q] : make_uint4(0,0,0,0);
    uint4 rb = (r<nb)? ((const uint4*)(B + (size_t)r*D6))[q] : make_uint4(0,0,0,0);
    As[r*97+2*q]   = make_float4(bfl(ra.x),bfh(ra.x),bfl(ra.y),bfh(ra.y));
    As[r*97+2*q+1] = make_float4(bfl(ra.z),bfh(ra.z),bfl(ra.w),bfh(ra.w));
    Bs[r*97+2*q]   = make_float4(bfl(rb.x),bfh(rb.x),bfl(rb.y),bfh(rb.y));
    Bs[r*97+2*q+1] = make_float4(bfl(rb.z),bfh(rb.z),bfl(rb.w),bfh(rb.w));
  }
  __syncthreads();
  int i = t >> 4, j = t & 15;
  const float4* ar = As + i*97;
  const float4* br = Bs + j*97;
  float acc = 0.f;
  #pragma unroll 8
  for (int k=0;k<96;k++){
    float4 a = ar[k], b = br[k];
    acc += a.x*b.x + a.y*b.y + a.z*b.z + a.w*b.w;
  }
  if (i<na && j<nb)
    S[(size_t)g*SMM*SMM + (size_t)(it*16+i)*SMM + (jt*16+j)] = f2bf(acc);
}

// ---------- interaction part 2: out = S.B / S^T.A ----------
// grid (512, 3, 2): x = side*256+g, y = 32-row chunk, z = 192-col half.  28.6 KB LDS -> 5 blocks/CU
__global__ __launch_bounds__(256) void k_apply(bf16t* __restrict__ f1, bf16t* __restrict__ f2,
                                               const int* __restrict__ st1, const int* __restrict__ st2,
                                               const bf16t* __restrict__ S){
  __shared__ float sbuf[32*192];   // 24 KB: 32 src rows x 192-col half (fp32)
  __shared__ float Sc[32][33];     // 4.2 KB
  int bx = blockIdx.x;
  int side = bx >> 8, g = bx & (NB-1);
  int a0 = st1[g]; int n1 = st1[g+1]-a0; if (n1>SMM) n1=SMM;
  int b0 = st2[g]; int n2 = st2[g+1]-b0; if (n2>SMM) n2=SMM;
  int cnt = side? n2 : n1;
  int J   = side? n1 : n2;
  int r0 = blockIdx.y*32;
  if (r0 >= cnt) return;
  int nr = cnt - r0; if (nr>32) nr=32;
  int c0 = blockIdx.z*192;
  const bf16t* src = (side? (f1 + (size_t)a0*D6) : (f2 + (size_t)b0*D6)) + c0;
  bf16t* dst       = (side? (f2 + (size_t)b0*D6) : (f1 + (size_t)a0*D6)) + D3 + c0;
  const bf16t* Sg = S + (size_t)g*SMM*SMM;
  int t = threadIdx.x, w = t>>6, lane = t&63;
  float acc[8][3] = {};
  for (int jc = 0; jc < J; jc += 32){
    int nj = J - jc; if (nj>32) nj=32;
    __syncthreads();
    for (int idx = t; idx < nj*24; idx += 256){
      int r = idx/24, q = idx - r*24;      // q over uint4 = 8 bf16; 192 cols = 24 uint4
      uint4 rv = ((const uint4*)(src + (size_t)(jc+r)*D6))[q];
      ((float4*)sbuf)[r*48 + 2*q]   = make_float4(bfl(rv.x),bfh(rv.x),bfl(rv.y),bfh(rv.y));
      ((float4*)sbuf)[r*48 + 2*q+1] = make_float4(bfl(rv.z),bfh(rv.z),bfl(rv.w),bfh(rv.w));
    }
    for (int idx = t; idx < 1024; idx += 256){
      int rr, jj;
      if (side){ jj = idx >> 5; rr = idx & 31; }
      else     { rr = idx >> 5; jj = idx & 31; }
      float v = 0.f;
      if (rr < nr && jj < nj)
        v = b2f(side? Sg[(size_t)(jc+jj)*SMM + (r0+rr)] : Sg[(size_t)(r0+rr)*SMM + (jc+jj)]);
      Sc[rr][jj] = v;
    }
    __syncthreads();
    for (int ri = 0; ri*4 + w < nr; ri++){
      int row = ri*4 + w;
      for (int jj = 0; jj < nj; jj++){
        float s = Sc[row][jj];                  // wave-uniform broadcast
        const float* p = sbuf + jj*192 + lane;  // b32 sweeps, 2 lanes/bank = free
        acc[ri][0] += s*p[0];
        acc[ri][1] += s*p[64];
        acc[ri][2] += s*p[128];
      }
    }
  }
  for (int ri = 0; ri*4 + w < nr; ri++){
    int row = r0 + ri*4 + w;
    bf16t* d = dst + (size_t)row*D6 + lane;
    d[0]   = f2bf(acc[ri][0]);
    d[64]  = f2bf(acc[ri][1]);
    d[128] = f2bf(acc[ri][2]);
  }
}

// ---------- set2set ----------

__global__ void k_h0(const float* bih, const float* bhh, float* h0, float* c0){
  int j = threadIdx.x;
  float gi = bih[j]      + bhh[j];
  float gg = bih[2*D6+j] + bhh[2*D6+j];
  float go = bih[3*D6+j] + bhh[3*D6+j];
  float c = sigf(gi)*tanhf(gg);
  c0[j]=c;
  h0[j]=sigf(go)*tanhf(c);
}

__global__ __launch_bounds__(64) void k_cvec(const float* __restrict__ Wih, const float* __restrict__ Whh,
                                             const float* bih, const float* bhh,
                                             const float* __restrict__ h0, float* __restrict__ cvec){
  int j = blockIdx.x, lane = threadIdx.x;
  const float4* wi = (const float4*)(Wih + (size_t)j*(2*D6));
  const float4* wh = (const float4*)(Whh + (size_t)j*D6);
  const float4* h4 = (const float4*)h0;
  float acc=0;
  #pragma unroll
  for (int m=0;m<3;m++){
    float4 hv = h4[m*64+lane];
    float4 a = wi[m*64+lane];
    float4 b = wh[m*64+lane];
    acc += hv.x*(a.x+b.x) + hv.y*(a.y+b.y) + hv.z*(a.z+b.z) + hv.w*(a.w+b.w);
  }
  #pragma unroll
  for (int m=1;m<64;m<<=1) acc += __shfl_xor(acc,m,64);
  if (lane==0) cvec[j]=acc+bih[j]+bhh[j];
}

// fused attention: e=x.hv, segment softmax, r=sum a*x; x is bf16
__global__ __launch_bounds__(256) void k_att(const bf16t* __restrict__ f1, const bf16t* __restrict__ f2,
                                             const float* __restrict__ hbase, int perseg,
                                             const int* __restrict__ st1, const int* __restrict__ st2,
                                             float* __restrict__ dst0, bf16t* __restrict__ dst16,
                                             long sidestep, long dstride){
  __shared__ float4 hs[192];
  __shared__ float e_s[SMM];
  int side = blockIdx.x >> 8, g = blockIdx.x & (NB-1);
  const int* st = side? st2:st1;
  int n0 = st[g]; int cnt = st[g+1]-n0; if (cnt>SMM) cnt=SMM;
  const bf16t* x = (side? f2:f1) + (size_t)n0*D6;
  const float* hv = hbase + (perseg? (size_t)(side*NB+g)*D6 : 0);
  int t = threadIdx.x, w = t>>6, lane = t&63;
  if (t<192) hs[t] = ((const float4*)hv)[t];
  __syncthreads();
  for (int n=w; n<cnt; n+=4){
    const uint2* xr = (const uint2*)(x + (size_t)n*D6);   // uint2 = 4 bf16
    float p = 0;
    #pragma unroll
    for (int m=0;m<3;m++){
      uint2 rv = xr[m*64+lane];
      float4 hvv = hs[m*64+lane];
      p += bfl(rv.x)*hvv.x + bfh(rv.x)*hvv.y + bfl(rv.y)*hvv.z + bfh(rv.y)*hvv.w;
    }
    #pragma unroll
    for (int m=1;m<64;m<<=1) p += __shfl_xor(p,m,64);
    if (lane==0) e_s[n]=p;
  }
  __syncthreads();
  if (w==0){
    float mx=-INFINITY;
    for (int n=lane;n<cnt;n+=64) mx=fmaxf(mx,e_s[n]);
    #pragma unroll
    for (int m=1;m<64;m<<=1) mx=fmaxf(mx,__shfl_xor(mx,m,64));
    float s=0;
    for (int n=lane;n<cnt;n+=64) s+=__expf(e_s[n]-mx);
    #pragma unroll
    for (int m=1;m<64;m<<=1) s+=__shfl_xor(s,m,64);
    float inv=1.0f/s;
    for (int n=lane;n<cnt;n+=64) e_s[n]=__expf(e_s[n]-mx)*inv;
  }
  __syncthreads();
  if (t<192){
    float4 acc={0,0,0,0};
    for (int n=0;n<cnt;n++){
      float a = e_s[n];
      uint2 rv = ((const uint2*)(x + (size_t)n*D6))[t];
      acc.x+=a*bfl(rv.x); acc.y+=a*bfh(rv.x); acc.z+=a*bfl(rv.y); acc.w+=a*bfh(rv.y);
    }
    if (dst16){
      ushort4 o = make_ushort4(f2bf(acc.x), f2bf(acc.y), f2bf(acc.z), f2bf(acc.w));
      ((ushort4*)(dst16 + side*sidestep + (size_t)g*dstride))[t]=o;
    } else {
      ((float4*)(dst0 + side*sidestep + (size_t)g*dstride))[t]=acc;
    }
  }
}

// gates GEMM via bf16 MFMA, no split-K: pout[512][3072]
__global__ __launch_bounds__(256) void k_gemm_mfma(const short* __restrict__ A16,
                                                   const short* __restrict__ B16,
                                                   float* __restrict__ pout){
  int w = threadIdx.x >> 6, lane = threadIdx.x & 63;
  int lm = lane & 15, quad = lane >> 4;
  int bm = blockIdx.x * 16;
  int bn = blockIdx.y * 256 + w * 64;
  const short* a = A16 + (size_t)(bm + lm)*768 + quad*8;
  const short* b = B16 + (size_t)(bn + lm)*768 + quad*8;
  f32x4 acc0={0,0,0,0}, acc1={0,0,0,0}, acc2={0,0,0,0}, acc3={0,0,0,0};
  for (int k=0; k<768; k+=32){
    short8v af = *(const short8v*)(a + k);
    short8v b0 = *(const short8v*)(b + k);
    short8v b1 = *(const short8v*)(b + 16*768 + k);
    short8v b2 = *(const short8v*)(b + 32*768 + k);
    short8v b3 = *(const short8v*)(b + 48*768 + k);
    acc0 = __builtin_amdgcn_mfma_f32_16x16x32_bf16(af, b0, acc0, 0, 0, 0);
    acc1 = __builtin_amdgcn_mfma_f32_16x16x32_bf16(af, b1, acc1, 0, 0, 0);
    acc2 = __builtin_amdgcn_mfma_f32_16x16x32_bf16(af, b2, acc2, 0, 0, 0);
    acc3 = __builtin_amdgcn_mfma_f32_16x16x32_bf16(af, b3, acc3, 0, 0, 0);
  }
  #pragma unroll
  for (int r=0;r<4;r++){
    size_t base = (size_t)(bm + quad*4 + r)*3072 + bn + lm;
    pout[base]      = acc0[r];
    pout[base + 16] = acc1[r];
    pout[base + 32] = acc2[r];
    pout[base + 48] = acc3[r];
  }
}

// Wih right half -> contiguous bf16 [3072][768]
__global__ __launch_bounds__(256) void k_conv_w(const float* __restrict__ W, short* __restrict__ dst){
  int t = blockIdx.x*256 + threadIdx.x;
  int n = t/192, q = t - n*192;
  float4 v = ((const float4*)(W + (size_t)n*1536 + 768))[q];
  short4 o = { (short)f2bf(v.x), (short)f2bf(v.y), (short)f2bf(v.z), (short)f2bf(v.w) };
  ((short4*)dst)[t] = o;
}

// split-K GEMM (small MLP layers)
__global__ __launch_bounds__(256) void k_gemm_sk(const float* __restrict__ A, int lda,
                                                 const float* __restrict__ B, int ldb,
                                                 float* __restrict__ partial,
                                                 int M, int N, int kchunk){
  __shared__ float As[16][68];
  __shared__ float Bs[16][68];
  int bm = blockIdx.y*64, bn = blockIdx.x*64;
  int kbase = blockIdx.z*kchunk;
  int t = threadIdx.x;
  int tx = t & 15, ty = t >> 4;
  float acc[4][4] = {};
  for (int k0=kbase;k0<kbase+kchunk;k0+=16){
    for (int l=t;l<64*16;l+=256){
      int m = l>>4, k = l&15;
      As[k][m] = A[(size_t)(bm+m)*lda + k0+k];
      Bs[k][m] = B[(size_t)(bn+m)*ldb + k0+k];
    }
    __syncthreads();
    #pragma unroll
    for (int k=0;k<16;k++){
      float4 av = *(const float4*)&As[k][ty*4];
      float4 bv = *(const float4*)&Bs[k][tx*4];
      float a4[4]={av.x,av.y,av.z,av.w};
      float b4[4]={bv.x,bv.y,bv.z,bv.w};
      #pragma unroll
      for (int i=0;i<4;i++)
        #pragma unroll
        for (int j=0;j<4;j++) acc[i][j]+=a4[i]*b4[j];
    }
    __syncthreads();
  }
  float* pout = partial + (size_t)blockIdx.z*M*N;
  #pragma unroll
  for (int i=0;i<4;i++)
    #pragma unroll
    for (int j=0;j<4;j++){
      int m = bm+ty*4+i, n = bn+tx*4+j;
      pout[(size_t)m*N+n]=acc[i][j];
    }
}

__global__ __launch_bounds__(256) void k_reduce(const float* __restrict__ partial, int S, long MN,
                                                const float* __restrict__ cv, float* __restrict__ dst,
                                                int N, int act){
  long idx = (long)blockIdx.x*256 + threadIdx.x;
  if (idx >= MN) return;
  float s = 0;
  for (int p=0;p<S;p++) s += partial[(size_t)p*MN + idx];
  s += cv[idx % N];
  if (act) s = fmaxf(s,0.f);
  dst[idx]=s;
}

// fused: gates + cvec + LSTM step-1 pointwise (single MFMA partial)
__global__ __launch_bounds__(256) void k_lstm_red(const float* __restrict__ pbuf,
                                                  const float* __restrict__ cvec,
                                                  const float* __restrict__ c0,
                                                  float* __restrict__ h1s, float* __restrict__ z){
  int t = blockIdx.x*256 + threadIdx.x;   // 512*768
  int m = t/D6, j = t - m*D6;
  const float* p0 = pbuf + (size_t)m*3072 + j;
  float g4[4];
  #pragma unroll
  for (int q=0;q<4;q++) g4[q] = cvec[q*D6 + j] + p0[q*D6];
  float c = sigf(g4[1])*c0[j] + sigf(g4[0])*tanhf(g4[2]);
  float h = sigf(g4[3])*tanhf(c);
  h1s[(size_t)m*D6 + j] = h;
  int side = m>>8, g = m&255;
  z[(size_t)g*3072 + side*1536 + j] = h;
}

__global__ __launch_bounds__(128) void k_p3(const float* __restrict__ z2, const float* __restrict__ W,
                                            const float* b, float* __restrict__ out){
  int m=blockIdx.x, t=threadIdx.x;
  float p = z2[m*128+t]*W[t];
  #pragma unroll
  for (int o=32;o;o>>=1) p += __shfl_down(p,o,64);
  __shared__ float ws[2];
  if ((t&63)==0) ws[t>>6]=p;
  __syncthreads();
  if (t==0){ float v=ws[0]+ws[1]+b[0]; out[m]=1.0f/(1.0f+__expf(-v)); }
}

// ---------- launch ----------

extern "C" void kernel_launch(void* const* d_in, const int* in_sizes, int n_in,
                              void* d_out, int out_size, void* d_ws, size_t ws_size,
                              hipStream_t stream){
  const float* feat1=(const float*)d_in[0];
  const float* feat2=(const float*)d_in[1];
  const float* ea1  =(const float*)d_in[2];
  const float* ea2  =(const float*)d_in[3];
  const float* W0=(const float*)d_in[4];  const float* b0=(const float*)d_in[5];
  const float* W1=(const float*)d_in[6];  const float* b1=(const float*)d_in[7];
  const float* W2=(const float*)d_in[8];  const float* b2=(const float*)d_in[9];
  const float* Wih=(const float*)d_in[10]; const float* bih=(const float*)d_in[11];
  const float* Whh=(const float*)d_in[12]; const float* bhh=(const float*)d_in[13];
  const float* Wp1=(const float*)d_in[14]; const float* bp1=(const float*)d_in[15];
  const float* Wp2=(const float*)d_in[16]; const float* bp2=(const float*)d_in[17];
  const float* Wp3=(const float*)d_in[18]; const float* bp3=(const float*)d_in[19];
  const int* ei1=(const int*)d_in[20]; const int* ei2=(const int*)d_in[21];
  const int* batch1=(const int*)d_in[22]; const int* batch2=(const int*)d_in[23];
  float* out = (float*)d_out;

  float* base = (float*)d_ws;
  size_t off = 0;
  auto alloc = [&](size_t n)->float* { float* r = base + off; off += (n + 255) & ~(size_t)255; return r; };
  float* deg1 = alloc(N_NODES);          float* deg2 = alloc(N_NODES);
  float* xw1  = alloc((size_t)N_NODES*NH); float* xw2 = alloc((size_t)N_NODES*NH);
  float* h1   = alloc((size_t)N_NODES*D3);
  float* h2   = alloc((size_t)N_NODES*D3);
  bf16t* f1   = (bf16t*)alloc((size_t)N_NODES*D6/2);
  bf16t* f2   = (bf16t*)alloc((size_t)N_NODES*D6/2);
  float* ecoef1 = alloc(N_EDGES);        float* ecoef2 = alloc(N_EDGES);
  float* h0   = alloc(D6);  float* c0 = alloc(D6);  float* cvec = alloc(4*D6);
  bf16t* Sbuf = (bf16t*)alloc((size_t)NB*SMM*SMM/2);
  float* h1s  = alloc((size_t)512*D6);
  float* zbuf = alloc((size_t)256*3072);
  float* z1   = alloc((size_t)256*256);
  float* z2b  = alloc((size_t)256*128);
  float* pbuf = alloc((size_t)4*512*3072);
  short* Abuf16 = (short*)alloc((size_t)512*D6/2);
  short* Wih16  = (short*)alloc((size_t)3072*D6/2);
  int* cnt1 = (int*)alloc(NB);   int* cnt2 = (int*)alloc(NB);
  int* st1  = (int*)alloc(NB+1); int* st2  = (int*)alloc(NB+1);
  int* ecnt1= (int*)alloc(N_NODES); int* ecnt2 = (int*)alloc(N_NODES);
  int* eoff1= (int*)alloc(N_NODES+1); int* eoff2 = (int*)alloc(N_NODES+1);
  int* ecur1= (int*)alloc(N_NODES); int* ecur2 = (int*)alloc(N_NODES);
  int* esrc1= (int*)alloc(N_EDGES); int* esrc2 = (int*)alloc(N_EDGES);
  (void)ws_size; (void)in_sizes; (void)n_in; (void)out_size;

  k_init   <<<32,256,0,stream>>>(deg1,deg2,ecnt1,ecnt2,cnt1,cnt2);
  k_deg    <<<1024,256,0,stream>>>(ei1,ea1,deg1,ecnt1, ei2,ea2,deg2,ecnt2, batch1,batch2,cnt1,cnt2);
  k_dinv   <<<32,256,0,stream>>>(deg1,deg2);
  k_scan256<<<2,256,0,stream>>>(cnt1,cnt2,st1,st2);
  k_escan  <<<2,1024,0,stream>>>(ecnt1,ecnt2,eoff1,ecur1,eoff2,ecur2);
  k_fill   <<<1024,256,0,stream>>>(ei1,ea1,deg1,ecur1,esrc1,ecoef1, ei2,ea2,deg2,ecur2,esrc2,ecoef2);
  k_conv_w <<<2304,256,0,stream>>>(Wih, Wih16);

  const float* Ws[3]={W0,W1,W2}; const float* bs[3]={b0,b1,b2};
  for (int l=0;l<3;l++){
    const float* x1 = (l==0)? feat1 : (h1 + (l-1)*NH);
    const float* x2 = (l==0)? feat2 : (h2 + (l-1)*NH);
    int xs = (l==0)? 64 : D3;
    int K  = (l==0)? 64 : NH;
    k_xw    <<<2048,128,0,stream>>>(x1,x2,xs,K,Ws[l],xw1,xw2);
    k_gather<<<2048,256,0,stream>>>(xw1,xw2,eoff1,eoff2,esrc1,esrc2,ecoef1,ecoef2,
                                    deg1,deg2,bs[l],h1,h2,l*NH);
  }

  k_l2norm<<<16384,128,0,stream>>>(h1,h2,f1,f2);
  k_smat  <<<dim3(256,36),256,0,stream>>>(f1,f2,st1,st2,Sbuf);
  k_apply <<<dim3(512,3,2),256,0,stream>>>(f1,f2,st1,st2,Sbuf);

  k_h0  <<<1,768,0,stream>>>(bih,bhh,h0,c0);
  k_cvec<<<3072,64,0,stream>>>(Wih,Whh,bih,bhh,h0,cvec);

  // step-1 attention (shared h0) -> Abuf16 bf16 rows [side*256+g]
  k_att<<<512,256,0,stream>>>(f1,f2,h0,0,st1,st2,(float*)nullptr,(bf16t*)Abuf16,(long)256*D6,(long)D6);

  // gates = Abuf16 @ Wih16^T + cvec via bf16 MFMA (no split-K), fused reduce+LSTM
  k_gemm_mfma<<<dim3(32,12),256,0,stream>>>(Abuf16, Wih16, pbuf);
  k_lstm_red <<<1536,256,0,stream>>>(pbuf,cvec,c0,h1s,zbuf);

  // step-2 attention (per-segment h) -> zbuf r-slots fp32
  k_att<<<512,256,0,stream>>>(f1,f2,h1s,1,st1,st2,zbuf+768,(bf16t*)nullptr,(long)1536,(long)3072);

  // MLP
  k_gemm_sk<<<dim3(4,4,16),256,0,stream>>>(zbuf,3072, Wp1,3072, pbuf, 256, 256, 192);
  k_reduce <<<256,256,0,stream>>>(pbuf,16,(long)256*256, bp1, z1, 256, 1);
  k_gemm_sk<<<dim3(2,4,4),256,0,stream>>>(z1,256, Wp2,256, pbuf, 256, 128, 64);
  k_reduce <<<128,256,0,stream>>>(pbuf,4,(long)256*128, bp2, z2b, 128, 1);
  k_p3  <<<256,128,0,stream>>>(z2b,Wp3,bp3,out);
}

// Round 11
// 435.388 us; speedup vs baseline: 1.0873x; 1.0873x over previous
//
#include <hip/hip_runtime.h>
#include <cmath>

#define N_NODES 8192
#define N_EDGES 131072
#define NB      256
#define NH      128
#define D3      384
#define D6      768
#define SMM     96   // max nodes per (graph,side); Binomial(8192,1/256) mean 32, 96 = 11 sigma

typedef __attribute__((ext_vector_type(8))) short short8v;
typedef __attribute__((ext_vector_type(4))) float f32x4;
typedef unsigned short bf16t;

__device__ __forceinline__ float sigf(float x){ return 1.0f/(1.0f+__expf(-x)); }
__device__ __forceinline__ unsigned short f2bf(float x){
  unsigned u = __float_as_uint(x);
  unsigned r = u + 0x7FFF + ((u>>16)&1);   // round-to-nearest-even
  return (unsigned short)(r>>16);
}
__device__ __forceinline__ float bfl(unsigned u){ return __uint_as_float(u<<16); }
__device__ __forceinline__ float bfh(unsigned u){ return __uint_as_float(u & 0xFFFF0000u); }

// ---------- setup ----------

__global__ void k_init(float* deg1, float* deg2, int* ecnt1, int* ecnt2, int* cnt1, int* cnt2){
  int t = blockIdx.x*blockDim.x + threadIdx.x;
  if (t < N_NODES){ deg1[t]=1.f; deg2[t]=1.f; ecnt1[t]=0; ecnt2[t]=0; }
  if (t < NB){ cnt1[t]=0; cnt2[t]=0; }
}

__global__ void k_deg(const int* __restrict__ ei1, const float* __restrict__ ea1, float* deg1, int* ecnt1,
                      const int* __restrict__ ei2, const float* __restrict__ ea2, float* deg2, int* ecnt2,
                      const int* __restrict__ b1, const int* __restrict__ b2, int* cnt1, int* cnt2){
  int idx = blockIdx.x*blockDim.x + threadIdx.x;
  int side = idx >= N_EDGES;
  int e = idx & (N_EDGES-1);
  const int* ei = side? ei2:ei1; const float* ea = side? ea2:ea1;
  float* deg = side? deg2:deg1;  int* ecnt = side? ecnt2:ecnt1;
  int d = ei[N_EDGES+e];
  atomicAdd(&deg[d], ea[e]);
  atomicAdd(&ecnt[d], 1);
  if (idx < N_NODES){ atomicAdd(&cnt1[b1[idx]],1); atomicAdd(&cnt2[b2[idx]],1); }
}

__global__ void k_dinv(float* deg1, float* deg2){
  int t = blockIdx.x*blockDim.x + threadIdx.x;
  if (t < N_NODES){ deg1[t]=rsqrtf(deg1[t]); deg2[t]=rsqrtf(deg2[t]); }
}

__global__ __launch_bounds__(256) void k_scan256(const int* c1, const int* c2, int* s1, int* s2){
  const int* c = blockIdx.x? c2:c1; int* st = blockIdx.x? s2:s1;
  __shared__ int ps[256];
  int t = threadIdx.x;
  ps[t]=c[t]; __syncthreads();
  for (int d=1; d<256; d<<=1){
    int v = (t>=d)? ps[t-d]:0;
    __syncthreads();
    ps[t]+=v;
    __syncthreads();
  }
  st[t+1]=ps[t];
  if (t==0) st[0]=0;
}

__global__ __launch_bounds__(1024) void k_escan(const int* ec1, const int* ec2,
                                                int* off1, int* cur1, int* off2, int* cur2){
  const int* cnt = blockIdx.x? ec2:ec1;
  int* off = blockIdx.x? off2:off1;
  int* cur = blockIdx.x? cur2:cur1;
  __shared__ int ps[1024];
  int t = threadIdx.x;
  int base = t*8;
  int loc[8]; int s=0;
  #pragma unroll
  for (int k=0;k<8;k++){ loc[k]=s; s+=cnt[base+k]; }
  ps[t]=s; __syncthreads();
  for (int d=1; d<1024; d<<=1){
    int v = (t>=d)? ps[t-d]:0;
    __syncthreads();
    ps[t]+=v;
    __syncthreads();
  }
  int pre = (t==0)? 0 : ps[t-1];
  #pragma unroll
  for (int k=0;k<8;k++){ int v=pre+loc[k]; off[base+k]=v; cur[base+k]=v; }
  if (t==1023) off[N_NODES]=ps[1023];
}

__global__ void k_fill(const int* __restrict__ ei1, const float* __restrict__ ea1, const float* __restrict__ d1,
                       int* cur1, int* es1, float* ec1,
                       const int* __restrict__ ei2, const float* __restrict__ ea2, const float* __restrict__ d2,
                       int* cur2, int* es2, float* ec2){
  int idx = blockIdx.x*blockDim.x + threadIdx.x;
  int side = idx >= N_EDGES;
  int e = idx & (N_EDGES-1);
  const int* ei = side? ei2:ei1; const float* ea = side? ea2:ea1;
  const float* dinv = side? d2:d1;
  int* cur = side? cur2:cur1; int* es = side? es2:es1; float* ec = side? ec2:ec1;
  int s = ei[e], d = ei[N_EDGES+e];
  int pos = atomicAdd(&cur[d], 1);
  es[pos] = s;
  ec[pos] = dinv[s]*ea[e]*dinv[d];
}

// zero S and ST padding (both contiguous): 2 * NB*96*96 bf16 = 589824 uint4
__global__ __launch_bounds__(256) void k_szero(uint4* p){
  p[blockIdx.x*256 + threadIdx.x] = make_uint4(0,0,0,0);
}

// ---------- GCN ----------

__global__ __launch_bounds__(128) void k_xw(const float* __restrict__ x1, const float* __restrict__ x2,
                                            int xs, int K, const float* __restrict__ W,
                                            float* __restrict__ xw1, float* __restrict__ xw2){
  __shared__ float xr[8][128];
  int blk = blockIdx.x;
  int side = blk >> 10; int b = blk & 1023;
  const float* x = side? x2:x1;
  float* xw = side? xw2:xw1;
  int i0 = b*8;
  int c = threadIdx.x;
  for (int idx=c; idx<8*K; idx+=128){
    int r = idx / K, k = idx - r*K;
    xr[r][k] = x[(size_t)(i0+r)*xs + k];
  }
  __syncthreads();
  float acc[8]={0,0,0,0,0,0,0,0};
  for (int k=0;k<K;k++){
    float w = W[k*NH+c];
    #pragma unroll
    for (int r=0;r<8;r++) acc[r]+=xr[r][k]*w;
  }
  #pragma unroll
  for (int r=0;r<8;r++) xw[(size_t)(i0+r)*NH+c]=acc[r];
}

__global__ __launch_bounds__(256) void k_gather(const float* __restrict__ xw1, const float* __restrict__ xw2,
                                                const int* __restrict__ off1, const int* __restrict__ off2,
                                                const int* __restrict__ es1, const int* __restrict__ es2,
                                                const float* __restrict__ ec1, const float* __restrict__ ec2,
                                                const float* __restrict__ d1, const float* __restrict__ d2,
                                                const float* __restrict__ b,
                                                float* __restrict__ h1, float* __restrict__ h2, int loff){
  int blk = blockIdx.x;
  int side = blk >> 10; int bb = blk & 1023;
  const float4* xw = (const float4*)(side? xw2:xw1);
  const int* off = side? off2:off1;
  const int* es  = side? es2:es1;
  const float* ec= side? ec2:ec1;
  const float* dinv = side? d2:d1;
  float* h = side? h2:h1;
  int t = threadIdx.x;
  int i = bb*8 + (t>>5);
  int c4 = t & 31;
  float dv = dinv[i];
  float4 v = xw[(size_t)i*32 + c4];
  float sc = dv*dv;
  float4 acc = {v.x*sc, v.y*sc, v.z*sc, v.w*sc};
  int r = off[i], r1 = off[i+1];
  for (; r+3<r1; r+=4){
    int s0=es[r], s1=es[r+1], s2=es[r+2], s3=es[r+3];
    float w0=ec[r], w1=ec[r+1], w2=ec[r+2], w3=ec[r+3];
    float4 u0 = xw[(size_t)s0*32 + c4];
    float4 u1 = xw[(size_t)s1*32 + c4];
    float4 u2 = xw[(size_t)s2*32 + c4];
    float4 u3 = xw[(size_t)s3*32 + c4];
    acc.x += u0.x*w0 + u1.x*w1 + u2.x*w2 + u3.x*w3;
    acc.y += u0.y*w0 + u1.y*w1 + u2.y*w2 + u3.y*w3;
    acc.z += u0.z*w0 + u1.z*w1 + u2.z*w2 + u3.z*w3;
    acc.w += u0.w*w0 + u1.w*w1 + u2.w*w2 + u3.w*w3;
  }
  for (; r<r1; r++){
    int s0=es[r]; float w0=ec[r];
    float4 u0 = xw[(size_t)s0*32 + c4];
    acc.x+=u0.x*w0; acc.y+=u0.y*w0; acc.z+=u0.z*w0; acc.w+=u0.w*w0;
  }
  float4 bv = ((const float4*)b)[c4];
  acc.x+=bv.x; acc.y+=bv.y; acc.z+=bv.z; acc.w+=bv.w;
  acc.x = (acc.x>0.f)?acc.x:0.2f*acc.x;
  acc.y = (acc.y>0.f)?acc.y:0.2f*acc.y;
  acc.z = (acc.z>0.f)?acc.z:0.2f*acc.z;
  acc.w = (acc.w>0.f)?acc.w:0.2f*acc.w;
  ((float4*)(h + (size_t)i*D3 + loff))[c4] = acc;
}

// ---------- l2 normalize -> bf16 f[:, 0:384] ----------
__global__ __launch_bounds__(128) void k_l2norm(const float* __restrict__ h1, const float* __restrict__ h2,
                                                bf16t* __restrict__ f1, bf16t* __restrict__ f2){
  int blk = blockIdx.x;
  int side = blk >> 13; int i = blk & (N_NODES-1);
  const float* h = side? h2:h1; bf16t* f = side? f2:f1;
  int t = threadIdx.x;
  float v0=h[(size_t)i*D3+t], v1=h[(size_t)i*D3+128+t], v2=h[(size_t)i*D3+256+t];
  float ss = v0*v0+v1*v1+v2*v2;
  #pragma unroll
  for (int o=32;o;o>>=1) ss += __shfl_down(ss,o,64);
  __shared__ float ws[2];
  if ((t&63)==0) ws[t>>6]=ss;
  __syncthreads();
  float scale = 1.0f/fmaxf(sqrtf(ws[0]+ws[1]), 1e-12f);
  f[(size_t)i*D6+t]      = f2bf(v0*scale);
  f[(size_t)i*D6+128+t]  = f2bf(v1*scale);
  f[(size_t)i*D6+256+t]  = f2bf(v2*scale);
}

// ---------- interaction part 1: S = A.B^T (bf16), writes S and S^T ----------
__global__ __launch_bounds__(256) void k_smat(const bf16t* __restrict__ f1, const bf16t* __restrict__ f2,
                                              const int* __restrict__ st1, const int* __restrict__ st2,
                                              bf16t* __restrict__ S, bf16t* __restrict__ ST){
  int g = blockIdx.x;
  int tile = blockIdx.y;
  int it = tile/6, jt = tile - it*6;
  int i0 = st1[g]; int n1 = st1[g+1]-i0; if (n1>SMM) n1=SMM;
  int j0 = st2[g]; int n2 = st2[g+1]-j0; if (n2>SMM) n2=SMM;
  if (it*16 >= n1 || jt*16 >= n2) return;
  __shared__ float4 As[16*97];
  __shared__ float4 Bs[16*97];
  const bf16t* A = f1 + (size_t)(i0 + it*16)*D6;
  const bf16t* B = f2 + (size_t)(j0 + jt*16)*D6;
  int na = n1 - it*16; if (na>16) na=16;
  int nb = n2 - jt*16; if (nb>16) nb=16;
  int t = threadIdx.x;
  for (int idx=t; idx<16*48; idx+=256){
    int r = idx/48, q = idx - r*48;    // q over uint4 = 8 bf16
    uint4 ra = (r<na)? ((const uint4*)(A + (size_t)r*D6))[q] : make_uint4(0,0,0,0);
    uint4 rb = (r<nb)? ((const uint4*)(B + (size_t)r*D6))[q] : make_uint4(0,0,0,0);
    As[r*97+2*q]   = make_float4(bfl(ra.x),bfh(ra.x),bfl(ra.y),bfh(ra.y));
    As[r*97+2*q+1] = make_float4(bfl(ra.z),bfh(ra.z),bfl(ra.w),bfh(ra.w));
    Bs[r*97+2*q]   = make_float4(bfl(rb.x),bfh(rb.x),bfl(rb.y),bfh(rb.y));
    Bs[r*97+2*q+1] = make_float4(bfl(rb.z),bfh(rb.z),bfl(rb.w),bfh(rb.w));
  }
  __syncthreads();
  int i = t >> 4, j = t & 15;
  const float4* ar = As + i*97;
  const float4* br = Bs + j*97;
  float acc = 0.f;
  #pragma unroll 8
  for (int k=0;k<96;k++){
    float4 a = ar[k], b = br[k];
    acc += a.x*b.x + a.y*b.y + a.z*b.z + a.w*b.w;
  }
  if (i<na && j<nb){
    bf16t v = f2bf(acc);
    S [(size_t)g*SMM*SMM + (size_t)(it*16+i)*SMM + (jt*16+j)] = v;
    ST[(size_t)g*SMM*SMM + (size_t)(jt*16+j)*SMM + (it*16+i)] = v;
  }
}

// ---------- interaction part 2 via MFMA: out = Srow @ src ----------
// grid (512, 3): x = side*256+g, y = 32-row output chunk.
// A-operand = S (side 0) or S^T (side 1): [outrow][k], k-contiguous, zero-padded.
// B-operand = src features [k=j][n=col], staged naturally in LDS, frag via strided u16 reads.
__global__ __launch_bounds__(256) void k_apply(bf16t* __restrict__ f1, bf16t* __restrict__ f2,
                                               const int* __restrict__ st1, const int* __restrict__ st2,
                                               const bf16t* __restrict__ S, const bf16t* __restrict__ ST){
  __shared__ bf16t tbuf[32*392];   // 24.5 KB: 32 src rows x 384 cols (+8 pad)
  int bx = blockIdx.x;
  int side = bx >> 8, g = bx & (NB-1);
  int a0 = st1[g]; int n1 = st1[g+1]-a0; if (n1>SMM) n1=SMM;
  int b0 = st2[g]; int n2 = st2[g+1]-b0; if (n2>SMM) n2=SMM;
  int cnt = side? n2 : n1;   // output rows
  int J   = side? n1 : n2;   // reduction length
  int r0 = blockIdx.y*32;
  if (r0 >= cnt) return;
  const bf16t* src = side? (f1 + (size_t)a0*D6) : (f2 + (size_t)b0*D6);
  bf16t* dst = (side? (f2 + (size_t)b0*D6) : (f1 + (size_t)a0*D6)) + D3;
  const bf16t* Sg = (side? ST : S) + (size_t)g*SMM*SMM;
  int t = threadIdx.x, w = t>>6, lane = t&63;
  int lm = lane & 15, quad = lane >> 4;
  int mt1 = (cnt - r0 > 16) ? 2 : 1;
  f32x4 acc[2][6] = {};
  for (int kb = 0; kb < J; kb += 32){
    __syncthreads();
    // stage 32 src rows (cols 0..383) naturally; zero rows beyond J
    for (int idx = t; idx < 32*48; idx += 256){
      int j = idx/48, cg = idx - j*48;
      uint4 v = (kb+j < J)? ((const uint4*)(src + (size_t)(kb+j)*D6))[cg] : make_uint4(0,0,0,0);
      *(uint4*)(tbuf + j*392 + cg*8) = v;
    }
    // A-fragments: rows r0+mt*16+lm, k = kb+quad*8 .. +7 (16B-aligned, zero-padded buffer)
    short8v af0, af1;
    {
      const bf16t* ap = Sg + (size_t)(r0 + lm)*SMM + kb + quad*8;
      af0 = *(const short8v*)ap;
      af1 = (mt1 > 1)? *(const short8v*)(ap + 16*SMM) : af0;
    }
    __syncthreads();
    #pragma unroll
    for (int ni = 0; ni < 6; ni++){
      int nt = w*6 + ni;                 // 24 col-tiles of 16
      short8v bf;
      #pragma unroll
      for (int ji = 0; ji < 8; ji++)
        bf[ji] = (short)tbuf[(quad*8 + ji)*392 + nt*16 + lm];
      acc[0][ni] = __builtin_amdgcn_mfma_f32_16x16x32_bf16(af0, bf, acc[0][ni], 0, 0, 0);
      if (mt1 > 1)
        acc[1][ni] = __builtin_amdgcn_mfma_f32_16x16x32_bf16(af1, bf, acc[1][ni], 0, 0, 0);
    }
  }
  for (int mt = 0; mt < mt1; mt++)
    for (int ni = 0; ni < 6; ni++){
      int nt = w*6 + ni;
      #pragma unroll
      for (int r = 0; r < 4; r++){
        int row = r0 + mt*16 + quad*4 + r;     // D: row = quad*4+reg, col = lm
        if (row < cnt) dst[(size_t)row*D6 + nt*16 + lm] = f2bf(acc[mt][ni][r]);
      }
    }
}

// ---------- set2set ----------

__global__ void k_h0(const float* bih, const float* bhh, float* h0, float* c0){
  int j = threadIdx.x;
  float gi = bih[j]      + bhh[j];
  float gg = bih[2*D6+j] + bhh[2*D6+j];
  float go = bih[3*D6+j] + bhh[3*D6+j];
  float c = sigf(gi)*tanhf(gg);
  c0[j]=c;
  h0[j]=sigf(go)*tanhf(c);
}

__global__ __launch_bounds__(64) void k_cvec(const float* __restrict__ Wih, const float* __restrict__ Whh,
                                             const float* bih, const float* bhh,
                                             const float* __restrict__ h0, float* __restrict__ cvec){
  int j = blockIdx.x, lane = threadIdx.x;
  const float4* wi = (const float4*)(Wih + (size_t)j*(2*D6));
  const float4* wh = (const float4*)(Whh + (size_t)j*D6);
  const float4* h4 = (const float4*)h0;
  float acc=0;
  #pragma unroll
  for (int m=0;m<3;m++){
    float4 hv = h4[m*64+lane];
    float4 a = wi[m*64+lane];
    float4 b = wh[m*64+lane];
    acc += hv.x*(a.x+b.x) + hv.y*(a.y+b.y) + hv.z*(a.z+b.z) + hv.w*(a.w+b.w);
  }
  #pragma unroll
  for (int m=1;m<64;m<<=1) acc += __shfl_xor(acc,m,64);
  if (lane==0) cvec[j]=acc+bih[j]+bhh[j];
}

// fused attention: e=x.hv, segment softmax, r=sum a*x; x is bf16
__global__ __launch_bounds__(256) void k_att(const bf16t* __restrict__ f1, const bf16t* __restrict__ f2,
                                             const float* __restrict__ hbase, int perseg,
                                             const int* __restrict__ st1, const int* __restrict__ st2,
                                             float* __restrict__ dst0, bf16t* __restrict__ dst16,
                                             long sidestep, long dstride){
  __shared__ float4 hs[192];
  __shared__ float e_s[SMM];
  int side = blockIdx.x >> 8, g = blockIdx.x & (NB-1);
  const int* st = side? st2:st1;
  int n0 = st[g]; int cnt = st[g+1]-n0; if (cnt>SMM) cnt=SMM;
  const bf16t* x = (side? f2:f1) + (size_t)n0*D6;
  const float* hv = hbase + (perseg? (size_t)(side*NB+g)*D6 : 0);
  int t = threadIdx.x, w = t>>6, lane = t&63;
  if (t<192) hs[t] = ((const float4*)hv)[t];
  __syncthreads();
  for (int n=w; n<cnt; n+=4){
    const uint2* xr = (const uint2*)(x + (size_t)n*D6);   // uint2 = 4 bf16
    float p = 0;
    #pragma unroll
    for (int m=0;m<3;m++){
      uint2 rv = xr[m*64+lane];
      float4 hvv = hs[m*64+lane];
      p += bfl(rv.x)*hvv.x + bfh(rv.x)*hvv.y + bfl(rv.y)*hvv.z + bfh(rv.y)*hvv.w;
    }
    #pragma unroll
    for (int m=1;m<64;m<<=1) p += __shfl_xor(p,m,64);
    if (lane==0) e_s[n]=p;
  }
  __syncthreads();
  if (w==0){
    float mx=-INFINITY;
    for (int n=lane;n<cnt;n+=64) mx=fmaxf(mx,e_s[n]);
    #pragma unroll
    for (int m=1;m<64;m<<=1) mx=fmaxf(mx,__shfl_xor(mx,m,64));
    float s=0;
    for (int n=lane;n<cnt;n+=64) s+=__expf(e_s[n]-mx);
    #pragma unroll
    for (int m=1;m<64;m<<=1) s+=__shfl_xor(s,m,64);
    float inv=1.0f/s;
    for (int n=lane;n<cnt;n+=64) e_s[n]=__expf(e_s[n]-mx)*inv;
  }
  __syncthreads();
  if (t<192){
    float4 acc={0,0,0,0};
    for (int n=0;n<cnt;n++){
      float a = e_s[n];
      uint2 rv = ((const uint2*)(x + (size_t)n*D6))[t];
      acc.x+=a*bfl(rv.x); acc.y+=a*bfh(rv.x); acc.z+=a*bfl(rv.y); acc.w+=a*bfh(rv.y);
    }
    if (dst16){
      ushort4 o = make_ushort4(f2bf(acc.x), f2bf(acc.y), f2bf(acc.z), f2bf(acc.w));
      ((ushort4*)(dst16 + side*sidestep + (size_t)g*dstride))[t]=o;
    } else {
      ((float4*)(dst0 + side*sidestep + (size_t)g*dstride))[t]=acc;
    }
  }
}

// gates GEMM via bf16 MFMA, no split-K: pout[512][3072]
__global__ __launch_bounds__(256) void k_gemm_mfma(const short* __restrict__ A16,
                                                   const short* __restrict__ B16,
                                                   float* __restrict__ pout){
  int w = threadIdx.x >> 6, lane = threadIdx.x & 63;
  int lm = lane & 15, quad = lane >> 4;
  int bm = blockIdx.x * 16;
  int bn = blockIdx.y * 256 + w * 64;
  const short* a = A16 + (size_t)(bm + lm)*768 + quad*8;
  const short* b = B16 + (size_t)(bn + lm)*768 + quad*8;
  f32x4 acc0={0,0,0,0}, acc1={0,0,0,0}, acc2={0,0,0,0}, acc3={0,0,0,0};
  for (int k=0; k<768; k+=32){
    short8v af = *(const short8v*)(a + k);
    short8v b0 = *(const short8v*)(b + k);
    short8v b1 = *(const short8v*)(b + 16*768 + k);
    short8v b2 = *(const short8v*)(b + 32*768 + k);
    short8v b3 = *(const short8v*)(b + 48*768 + k);
    acc0 = __builtin_amdgcn_mfma_f32_16x16x32_bf16(af, b0, acc0, 0, 0, 0);
    acc1 = __builtin_amdgcn_mfma_f32_16x16x32_bf16(af, b1, acc1, 0, 0, 0);
    acc2 = __builtin_amdgcn_mfma_f32_16x16x32_bf16(af, b2, acc2, 0, 0, 0);
    acc3 = __builtin_amdgcn_mfma_f32_16x16x32_bf16(af, b3, acc3, 0, 0, 0);
  }
  #pragma unroll
  for (int r=0;r<4;r++){
    size_t base = (size_t)(bm + quad*4 + r)*3072 + bn + lm;
    pout[base]      = acc0[r];
    pout[base + 16] = acc1[r];
    pout[base + 32] = acc2[r];
    pout[base + 48] = acc3[r];
  }
}

// Wih right half -> contiguous bf16 [3072][768]
__global__ __launch_bounds__(256) void k_conv_w(const float* __restrict__ W, short* __restrict__ dst){
  int t = blockIdx.x*256 + threadIdx.x;
  int n = t/192, q = t - n*192;
  float4 v = ((const float4*)(W + (size_t)n*1536 + 768))[q];
  short4 o = { (short)f2bf(v.x), (short)f2bf(v.y), (short)f2bf(v.z), (short)f2bf(v.w) };
  ((short4*)dst)[t] = o;
}

// split-K GEMM (small MLP layers)
__global__ __launch_bounds__(256) void k_gemm_sk(const float* __restrict__ A, int lda,
                                                 const float* __restrict__ B, int ldb,
                                                 float* __restrict__ partial,
                                                 int M, int N, int kchunk){
  __shared__ float As[16][68];
  __shared__ float Bs[16][68];
  int bm = blockIdx.y*64, bn = blockIdx.x*64;
  int kbase = blockIdx.z*kchunk;
  int t = threadIdx.x;
  int tx = t & 15, ty = t >> 4;
  float acc[4][4] = {};
  for (int k0=kbase;k0<kbase+kchunk;k0+=16){
    for (int l=t;l<64*16;l+=256){
      int m = l>>4, k = l&15;
      As[k][m] = A[(size_t)(bm+m)*lda + k0+k];
      Bs[k][m] = B[(size_t)(bn+m)*ldb + k0+k];
    }
    __syncthreads();
    #pragma unroll
    for (int k=0;k<16;k++){
      float4 av = *(const float4*)&As[k][ty*4];
      float4 bv = *(const float4*)&Bs[k][tx*4];
      float a4[4]={av.x,av.y,av.z,av.w};
      float b4[4]={bv.x,bv.y,bv.z,bv.w};
      #pragma unroll
      for (int i=0;i<4;i++)
        #pragma unroll
        for (int j=0;j<4;j++) acc[i][j]+=a4[i]*b4[j];
    }
    __syncthreads();
  }
  float* pout = partial + (size_t)blockIdx.z*M*N;
  #pragma unroll
  for (int i=0;i<4;i++)
    #pragma unroll
    for (int j=0;j<4;j++){
      int m = bm+ty*4+i, n = bn+tx*4+j;
      pout[(size_t)m*N+n]=acc[i][j];
    }
}

__global__ __launch_bounds__(256) void k_reduce(const float* __restrict__ partial, int S, long MN,
                                                const float* __restrict__ cv, float* __restrict__ dst,
                                                int N, int act){
  long idx = (long)blockIdx.x*256 + threadIdx.x;
  if (idx >= MN) return;
  float s = 0;
  for (int p=0;p<S;p++) s += partial[(size_t)p*MN + idx];
  s += cv[idx % N];
  if (act) s = fmaxf(s,0.f);
  dst[idx]=s;
}

// fused: gates + cvec + LSTM step-1 pointwise (single MFMA partial)
__global__ __launch_bounds__(256) void k_lstm_red(const float* __restrict__ pbuf,
                                                  const float* __restrict__ cvec,
                                                  const float* __restrict__ c0,
                                                  float* __restrict__ h1s, float* __restrict__ z){
  int t = blockIdx.x*256 + threadIdx.x;   // 512*768
  int m = t/D6, j = t - m*D6;
  const float* p0 = pbuf + (size_t)m*3072 + j;
  float g4[4];
  #pragma unroll
  for (int q=0;q<4;q++) g4[q] = cvec[q*D6 + j] + p0[q*D6];
  float c = sigf(g4[1])*c0[j] + sigf(g4[0])*tanhf(g4[2]);
  float h = sigf(g4[3])*tanhf(c);
  h1s[(size_t)m*D6 + j] = h;
  int side = m>>8, g = m&255;
  z[(size_t)g*3072 + side*1536 + j] = h;
}

__global__ __launch_bounds__(128) void k_p3(const float* __restrict__ z2, const float* __restrict__ W,
                                            const float* b, float* __restrict__ out){
  int m=blockIdx.x, t=threadIdx.x;
  float p = z2[m*128+t]*W[t];
  #pragma unroll
  for (int o=32;o;o>>=1) p += __shfl_down(p,o,64);
  __shared__ float ws[2];
  if ((t&63)==0) ws[t>>6]=p;
  __syncthreads();
  if (t==0){ float v=ws[0]+ws[1]+b[0]; out[m]=1.0f/(1.0f+__expf(-v)); }
}

// ---------- launch ----------

extern "C" void kernel_launch(void* const* d_in, const int* in_sizes, int n_in,
                              void* d_out, int out_size, void* d_ws, size_t ws_size,
                              hipStream_t stream){
  const float* feat1=(const float*)d_in[0];
  const float* feat2=(const float*)d_in[1];
  const float* ea1  =(const float*)d_in[2];
  const float* ea2  =(const float*)d_in[3];
  const float* W0=(const float*)d_in[4];  const float* b0=(const float*)d_in[5];
  const float* W1=(const float*)d_in[6];  const float* b1=(const float*)d_in[7];
  const float* W2=(const float*)d_in[8];  const float* b2=(const float*)d_in[9];
  const float* Wih=(const float*)d_in[10]; const float* bih=(const float*)d_in[11];
  const float* Whh=(const float*)d_in[12]; const float* bhh=(const float*)d_in[13];
  const float* Wp1=(const float*)d_in[14]; const float* bp1=(const float*)d_in[15];
  const float* Wp2=(const float*)d_in[16]; const float* bp2=(const float*)d_in[17];
  const float* Wp3=(const float*)d_in[18]; const float* bp3=(const float*)d_in[19];
  const int* ei1=(const int*)d_in[20]; const int* ei2=(const int*)d_in[21];
  const int* batch1=(const int*)d_in[22]; const int* batch2=(const int*)d_in[23];
  float* out = (float*)d_out;

  float* base = (float*)d_ws;
  size_t off = 0;
  auto alloc = [&](size_t n)->float* { float* r = base + off; off += (n + 255) & ~(size_t)255; return r; };
  float* deg1 = alloc(N_NODES);          float* deg2 = alloc(N_NODES);
  float* xw1  = alloc((size_t)N_NODES*NH); float* xw2 = alloc((size_t)N_NODES*NH);
  float* h1   = alloc((size_t)N_NODES*D3);
  float* h2   = alloc((size_t)N_NODES*D3);
  bf16t* f1   = (bf16t*)alloc((size_t)N_NODES*D6/2);
  bf16t* f2   = (bf16t*)alloc((size_t)N_NODES*D6/2);
  float* ecoef1 = alloc(N_EDGES);        float* ecoef2 = alloc(N_EDGES);
  float* h0   = alloc(D6);  float* c0 = alloc(D6);  float* cvec = alloc(4*D6);
  bf16t* Sbuf = (bf16t*)alloc((size_t)NB*SMM*SMM);       // S followed by ST (bf16 each)
  bf16t* STbuf= Sbuf + (size_t)NB*SMM*SMM;
  float* h1s  = alloc((size_t)512*D6);
  float* zbuf = alloc((size_t)256*3072);
  float* z1   = alloc((size_t)256*256);
  float* z2b  = alloc((size_t)256*128);
  float* pbuf = alloc((size_t)4*512*3072);
  short* Abuf16 = (short*)alloc((size_t)512*D6/2);
  short* Wih16  = (short*)alloc((size_t)3072*D6/2);
  int* cnt1 = (int*)alloc(NB);   int* cnt2 = (int*)alloc(NB);
  int* st1  = (int*)alloc(NB+1); int* st2  = (int*)alloc(NB+1);
  int* ecnt1= (int*)alloc(N_NODES); int* ecnt2 = (int*)alloc(N_NODES);
  int* eoff1= (int*)alloc(N_NODES+1); int* eoff2 = (int*)alloc(N_NODES+1);
  int* ecur1= (int*)alloc(N_NODES); int* ecur2 = (int*)alloc(N_NODES);
  int* esrc1= (int*)alloc(N_EDGES); int* esrc2 = (int*)alloc(N_EDGES);
  (void)ws_size; (void)in_sizes; (void)n_in; (void)out_size;

  k_init   <<<32,256,0,stream>>>(deg1,deg2,ecnt1,ecnt2,cnt1,cnt2);
  k_deg    <<<1024,256,0,stream>>>(ei1,ea1,deg1,ecnt1, ei2,ea2,deg2,ecnt2, batch1,batch2,cnt1,cnt2);
  k_dinv   <<<32,256,0,stream>>>(deg1,deg2);
  k_scan256<<<2,256,0,stream>>>(cnt1,cnt2,st1,st2);
  k_escan  <<<2,1024,0,stream>>>(ecnt1,ecnt2,eoff1,ecur1,eoff2,ecur2);
  k_fill   <<<1024,256,0,stream>>>(ei1,ea1,deg1,ecur1,esrc1,ecoef1, ei2,ea2,deg2,ecur2,esrc2,ecoef2);
  k_conv_w <<<2304,256,0,stream>>>(Wih, Wih16);
  k_szero  <<<2304,256,0,stream>>>((uint4*)Sbuf);   // zero S + ST (2 x 4.5 MB bf16 = 589824 uint4)

  const float* Ws[3]={W0,W1,W2}; const float* bs[3]={b0,b1,b2};
  for (int l=0;l<3;l++){
    const float* x1 = (l==0)? feat1 : (h1 + (l-1)*NH);
    const float* x2 = (l==0)? feat2 : (h2 + (l-1)*NH);
    int xs = (l==0)? 64 : D3;
    int K  = (l==0)? 64 : NH;
    k_xw    <<<2048,128,0,stream>>>(x1,x2,xs,K,Ws[l],xw1,xw2);
    k_gather<<<2048,256,0,stream>>>(xw1,xw2,eoff1,eoff2,esrc1,esrc2,ecoef1,ecoef2,
                                    deg1,deg2,bs[l],h1,h2,l*NH);
  }

  k_l2norm<<<16384,128,0,stream>>>(h1,h2,f1,f2);
  k_smat  <<<dim3(256,36),256,0,stream>>>(f1,f2,st1,st2,Sbuf,STbuf);
  k_apply <<<dim3(512,3),256,0,stream>>>(f1,f2,st1,st2,Sbuf,STbuf);

  k_h0  <<<1,768,0,stream>>>(bih,bhh,h0,c0);
  k_cvec<<<3072,64,0,stream>>>(Wih,Whh,bih,bhh,h0,cvec);

  // step-1 attention (shared h0) -> Abuf16 bf16 rows [side*256+g]
  k_att<<<512,256,0,stream>>>(f1,f2,h0,0,st1,st2,(float*)nullptr,(bf16t*)Abuf16,(long)256*D6,(long)D6);

  // gates = Abuf16 @ Wih16^T + cvec via bf16 MFMA (no split-K), fused reduce+LSTM
  k_gemm_mfma<<<dim3(32,12),256,0,stream>>>(Abuf16, Wih16, pbuf);
  k_lstm_red <<<1536,256,0,stream>>>(pbuf,cvec,c0,h1s,zbuf);

  // step-2 attention (per-segment h) -> zbuf r-slots fp32
  k_att<<<512,256,0,stream>>>(f1,f2,h1s,1,st1,st2,zbuf+768,(bf16t*)nullptr,(long)1536,(long)3072);

  // MLP
  k_gemm_sk<<<dim3(4,4,16),256,0,stream>>>(zbuf,3072, Wp1,3072, pbuf, 256, 256, 192);
  k_reduce <<<256,256,0,stream>>>(pbuf,16,(long)256*256, bp1, z1, 256, 1);
  k_gemm_sk<<<dim3(2,4,4),256,0,stream>>>(z1,256, Wp2,256, pbuf, 256, 128, 64);
  k_reduce <<<128,256,0,stream>>>(pbuf,4,(long)256*128, bp2, z2b, 128, 1);
  k_p3  <<<256,128,0,stream>>>(z2b,Wp3,bp3,out);
}

// Round 12
// 402.617 us; speedup vs baseline: 1.1758x; 1.0814x over previous
//
#include <hip/hip_runtime.h>
#include <cmath>

#define N_NODES 8192
#define N_EDGES 131072
#define NB      256
#define NH      128
#define D3      384
#define D6      768
#define SMM     96   // max nodes per (graph,side); Binomial(8192,1/256) mean 32, 96 = 11 sigma

typedef __attribute__((ext_vector_type(8))) short short8v;
typedef __attribute__((ext_vector_type(4))) float f32x4;
typedef unsigned short bf16t;

__device__ __forceinline__ float sigf(float x){ return 1.0f/(1.0f+__expf(-x)); }
__device__ __forceinline__ unsigned short f2bf(float x){
  unsigned u = __float_as_uint(x);
  unsigned r = u + 0x7FFF + ((u>>16)&1);   // round-to-nearest-even
  return (unsigned short)(r>>16);
}
__device__ __forceinline__ float bfl(unsigned u){ return __uint_as_float(u<<16); }
__device__ __forceinline__ float bfh(unsigned u){ return __uint_as_float(u & 0xFFFF0000u); }
__device__ __forceinline__ float b2f(bf16t u){ return __uint_as_float(((unsigned)u)<<16); }

// ---------- setup ----------

__global__ void k_init(float* deg1, float* deg2, int* ecnt1, int* ecnt2, int* cnt1, int* cnt2){
  int t = blockIdx.x*blockDim.x + threadIdx.x;
  if (t < N_NODES){ deg1[t]=1.f; deg2[t]=1.f; ecnt1[t]=0; ecnt2[t]=0; }
  if (t < NB){ cnt1[t]=0; cnt2[t]=0; }
}

__global__ void k_deg(const int* __restrict__ ei1, const float* __restrict__ ea1, float* deg1, int* ecnt1,
                      const int* __restrict__ ei2, const float* __restrict__ ea2, float* deg2, int* ecnt2,
                      const int* __restrict__ b1, const int* __restrict__ b2, int* cnt1, int* cnt2){
  int idx = blockIdx.x*blockDim.x + threadIdx.x;
  int side = idx >= N_EDGES;
  int e = idx & (N_EDGES-1);
  const int* ei = side? ei2:ei1; const float* ea = side? ea2:ea1;
  float* deg = side? deg2:deg1;  int* ecnt = side? ecnt2:ecnt1;
  int d = ei[N_EDGES+e];
  atomicAdd(&deg[d], ea[e]);
  atomicAdd(&ecnt[d], 1);
  if (idx < N_NODES){ atomicAdd(&cnt1[b1[idx]],1); atomicAdd(&cnt2[b2[idx]],1); }
}

__global__ void k_dinv(float* deg1, float* deg2){
  int t = blockIdx.x*blockDim.x + threadIdx.x;
  if (t < N_NODES){ deg1[t]=rsqrtf(deg1[t]); deg2[t]=rsqrtf(deg2[t]); }
}

__global__ __launch_bounds__(256) void k_scan256(const int* c1, const int* c2, int* s1, int* s2){
  const int* c = blockIdx.x? c2:c1; int* st = blockIdx.x? s2:s1;
  __shared__ int ps[256];
  int t = threadIdx.x;
  ps[t]=c[t]; __syncthreads();
  for (int d=1; d<256; d<<=1){
    int v = (t>=d)? ps[t-d]:0;
    __syncthreads();
    ps[t]+=v;
    __syncthreads();
  }
  st[t+1]=ps[t];
  if (t==0) st[0]=0;
}

__global__ __launch_bounds__(1024) void k_escan(const int* ec1, const int* ec2,
                                                int* off1, int* cur1, int* off2, int* cur2){
  const int* cnt = blockIdx.x? ec2:ec1;
  int* off = blockIdx.x? off2:off1;
  int* cur = blockIdx.x? cur2:cur1;
  __shared__ int ps[1024];
  int t = threadIdx.x;
  int base = t*8;
  int loc[8]; int s=0;
  #pragma unroll
  for (int k=0;k<8;k++){ loc[k]=s; s+=cnt[base+k]; }
  ps[t]=s; __syncthreads();
  for (int d=1; d<1024; d<<=1){
    int v = (t>=d)? ps[t-d]:0;
    __syncthreads();
    ps[t]+=v;
    __syncthreads();
  }
  int pre = (t==0)? 0 : ps[t-1];
  #pragma unroll
  for (int k=0;k<8;k++){ int v=pre+loc[k]; off[base+k]=v; cur[base+k]=v; }
  if (t==1023) off[N_NODES]=ps[1023];
}

__global__ void k_fill(const int* __restrict__ ei1, const float* __restrict__ ea1, const float* __restrict__ d1,
                       int* cur1, int* es1, float* ec1,
                       const int* __restrict__ ei2, const float* __restrict__ ea2, const float* __restrict__ d2,
                       int* cur2, int* es2, float* ec2){
  int idx = blockIdx.x*blockDim.x + threadIdx.x;
  int side = idx >= N_EDGES;
  int e = idx & (N_EDGES-1);
  const int* ei = side? ei2:ei1; const float* ea = side? ea2:ea1;
  const float* dinv = side? d2:d1;
  int* cur = side? cur2:cur1; int* es = side? es2:es1; float* ec = side? ec2:ec1;
  int s = ei[e], d = ei[N_EDGES+e];
  int pos = atomicAdd(&cur[d], 1);
  es[pos] = s;
  ec[pos] = dinv[s]*ea[e]*dinv[d];
}

// zero S and ST padding: 2 * NB*96*96 bf16 = 589824 uint4
__global__ __launch_bounds__(256) void k_szero(uint4* p){
  p[blockIdx.x*256 + threadIdx.x] = make_uint4(0,0,0,0);
}

// ---------- GCN ----------

// xw = x@W in fp32, stored bf16 (halves gather's random-read bytes)
__global__ __launch_bounds__(128) void k_xw(const float* __restrict__ x1, const float* __restrict__ x2,
                                            int xs, int K, const float* __restrict__ W,
                                            bf16t* __restrict__ xw1, bf16t* __restrict__ xw2){
  __shared__ float xr[8][128];
  int blk = blockIdx.x;
  int side = blk >> 10; int b = blk & 1023;
  const float* x = side? x2:x1;
  bf16t* xw = side? xw2:xw1;
  int i0 = b*8;
  int c = threadIdx.x;
  for (int idx=c; idx<8*K; idx+=128){
    int r = idx / K, k = idx - r*K;
    xr[r][k] = x[(size_t)(i0+r)*xs + k];
  }
  __syncthreads();
  float acc[8]={0,0,0,0,0,0,0,0};
  for (int k=0;k<K;k++){
    float w = W[k*NH+c];
    #pragma unroll
    for (int r=0;r<8;r++) acc[r]+=xr[r][k]*w;
  }
  #pragma unroll
  for (int r=0;r<8;r++) xw[(size_t)(i0+r)*NH+c]=f2bf(acc[r]);
}

// fused self-loop + CSR gather + bias + leaky; xw is bf16, fp32 accumulate, h fp32
__global__ __launch_bounds__(256) void k_gather(const bf16t* __restrict__ xw1, const bf16t* __restrict__ xw2,
                                                const int* __restrict__ off1, const int* __restrict__ off2,
                                                const int* __restrict__ es1, const int* __restrict__ es2,
                                                const float* __restrict__ ec1, const float* __restrict__ ec2,
                                                const float* __restrict__ d1, const float* __restrict__ d2,
                                                const float* __restrict__ b,
                                                float* __restrict__ h1, float* __restrict__ h2, int loff){
  int blk = blockIdx.x;
  int side = blk >> 10; int bb = blk & 1023;
  const ushort4* xw = (const ushort4*)(side? xw2:xw1);
  const int* off = side? off2:off1;
  const int* es  = side? es2:es1;
  const float* ec= side? ec2:ec1;
  const float* dinv = side? d2:d1;
  float* h = side? h2:h1;
  int t = threadIdx.x;
  int i = bb*8 + (t>>5);
  int c4 = t & 31;
  float dv = dinv[i];
  ushort4 v = xw[(size_t)i*32 + c4];
  float sc = dv*dv;
  float4 acc = {b2f(v.x)*sc, b2f(v.y)*sc, b2f(v.z)*sc, b2f(v.w)*sc};
  int r = off[i], r1 = off[i+1];
  for (; r+3<r1; r+=4){
    int s0=es[r], s1=es[r+1], s2=es[r+2], s3=es[r+3];
    float w0=ec[r], w1=ec[r+1], w2=ec[r+2], w3=ec[r+3];
    ushort4 u0 = xw[(size_t)s0*32 + c4];
    ushort4 u1 = xw[(size_t)s1*32 + c4];
    ushort4 u2 = xw[(size_t)s2*32 + c4];
    ushort4 u3 = xw[(size_t)s3*32 + c4];
    acc.x += b2f(u0.x)*w0 + b2f(u1.x)*w1 + b2f(u2.x)*w2 + b2f(u3.x)*w3;
    acc.y += b2f(u0.y)*w0 + b2f(u1.y)*w1 + b2f(u2.y)*w2 + b2f(u3.y)*w3;
    acc.z += b2f(u0.z)*w0 + b2f(u1.z)*w1 + b2f(u2.z)*w2 + b2f(u3.z)*w3;
    acc.w += b2f(u0.w)*w0 + b2f(u1.w)*w1 + b2f(u2.w)*w2 + b2f(u3.w)*w3;
  }
  for (; r<r1; r++){
    int s0=es[r]; float w0=ec[r];
    ushort4 u0 = xw[(size_t)s0*32 + c4];
    acc.x+=b2f(u0.x)*w0; acc.y+=b2f(u0.y)*w0; acc.z+=b2f(u0.z)*w0; acc.w+=b2f(u0.w)*w0;
  }
  float4 bv = ((const float4*)b)[c4];
  acc.x+=bv.x; acc.y+=bv.y; acc.z+=bv.z; acc.w+=bv.w;
  acc.x = (acc.x>0.f)?acc.x:0.2f*acc.x;
  acc.y = (acc.y>0.f)?acc.y:0.2f*acc.y;
  acc.z = (acc.z>0.f)?acc.z:0.2f*acc.z;
  acc.w = (acc.w>0.f)?acc.w:0.2f*acc.w;
  ((float4*)(h + (size_t)i*D3 + loff))[c4] = acc;
}

// ---------- l2 normalize -> bf16 f[:, 0:384] ----------
__global__ __launch_bounds__(128) void k_l2norm(const float* __restrict__ h1, const float* __restrict__ h2,
                                                bf16t* __restrict__ f1, bf16t* __restrict__ f2){
  int blk = blockIdx.x;
  int side = blk >> 13; int i = blk & (N_NODES-1);
  const float* h = side? h2:h1; bf16t* f = side? f2:f1;
  int t = threadIdx.x;
  float v0=h[(size_t)i*D3+t], v1=h[(size_t)i*D3+128+t], v2=h[(size_t)i*D3+256+t];
  float ss = v0*v0+v1*v1+v2*v2;
  #pragma unroll
  for (int o=32;o;o>>=1) ss += __shfl_down(ss,o,64);
  __shared__ float ws[2];
  if ((t&63)==0) ws[t>>6]=ss;
  __syncthreads();
  float scale = 1.0f/fmaxf(sqrtf(ws[0]+ws[1]), 1e-12f);
  f[(size_t)i*D6+t]      = f2bf(v0*scale);
  f[(size_t)i*D6+128+t]  = f2bf(v1*scale);
  f[(size_t)i*D6+256+t]  = f2bf(v2*scale);
}

// ---------- interaction part 1: S = A.B^T (bf16), writes S and S^T ----------
__global__ __launch_bounds__(256) void k_smat(const bf16t* __restrict__ f1, const bf16t* __restrict__ f2,
                                              const int* __restrict__ st1, const int* __restrict__ st2,
                                              bf16t* __restrict__ S, bf16t* __restrict__ ST){
  int g = blockIdx.x;
  int tile = blockIdx.y;
  int it = tile/6, jt = tile - it*6;
  int i0 = st1[g]; int n1 = st1[g+1]-i0; if (n1>SMM) n1=SMM;
  int j0 = st2[g]; int n2 = st2[g+1]-j0; if (n2>SMM) n2=SMM;
  if (it*16 >= n1 || jt*16 >= n2) return;
  __shared__ float4 As[16*97];
  __shared__ float4 Bs[16*97];
  const bf16t* A = f1 + (size_t)(i0 + it*16)*D6;
  const bf16t* B = f2 + (size_t)(j0 + jt*16)*D6;
  int na = n1 - it*16; if (na>16) na=16;
  int nb = n2 - jt*16; if (nb>16) nb=16;
  int t = threadIdx.x;
  for (int idx=t; idx<16*48; idx+=256){
    int r = idx/48, q = idx - r*48;    // q over uint4 = 8 bf16
    uint4 ra = (r<na)? ((const uint4*)(A + (size_t)r*D6))[q] : make_uint4(0,0,0,0);
    uint4 rb = (r<nb)? ((const uint4*)(B + (size_t)r*D6))[q] : make_uint4(0,0,0,0);
    As[r*97+2*q]   = make_float4(bfl(ra.x),bfh(ra.x),bfl(ra.y),bfh(ra.y));
    As[r*97+2*q+1] = make_float4(bfl(ra.z),bfh(ra.z),bfl(ra.w),bfh(ra.w));
    Bs[r*97+2*q]   = make_float4(bfl(rb.x),bfh(rb.x),bfl(rb.y),bfh(rb.y));
    Bs[r*97+2*q+1] = make_float4(bfl(rb.z),bfh(rb.z),bfl(rb.w),bfh(rb.w));
  }
  __syncthreads();
  int i = t >> 4, j = t & 15;
  const float4* ar = As + i*97;
  const float4* br = Bs + j*97;
  float acc = 0.f;
  #pragma unroll 8
  for (int k=0;k<96;k++){
    float4 a = ar[k], b = br[k];
    acc += a.x*b.x + a.y*b.y + a.z*b.z + a.w*b.w;
  }
  if (i<na && j<nb){
    bf16t v = f2bf(acc);
    S [(size_t)g*SMM*SMM + (size_t)(it*16+i)*SMM + (jt*16+j)] = v;
    ST[(size_t)g*SMM*SMM + (size_t)(jt*16+j)*SMM + (it*16+i)] = v;
  }
}

// ---------- interaction part 2 via MFMA: out = Srow @ src ----------
__global__ __launch_bounds__(256) void k_apply(bf16t* __restrict__ f1, bf16t* __restrict__ f2,
                                               const int* __restrict__ st1, const int* __restrict__ st2,
                                               const bf16t* __restrict__ S, const bf16t* __restrict__ ST){
  __shared__ bf16t tbuf[32*392];   // 24.5 KB
  int bx = blockIdx.x;
  int side = bx >> 8, g = bx & (NB-1);
  int a0 = st1[g]; int n1 = st1[g+1]-a0; if (n1>SMM) n1=SMM;
  int b0 = st2[g]; int n2 = st2[g+1]-b0; if (n2>SMM) n2=SMM;
  int cnt = side? n2 : n1;
  int J   = side? n1 : n2;
  int r0 = blockIdx.y*32;
  if (r0 >= cnt) return;
  const bf16t* src = side? (f1 + (size_t)a0*D6) : (f2 + (size_t)b0*D6);
  bf16t* dst = (side? (f2 + (size_t)b0*D6) : (f1 + (size_t)a0*D6)) + D3;
  const bf16t* Sg = (side? ST : S) + (size_t)g*SMM*SMM;
  int t = threadIdx.x, w = t>>6, lane = t&63;
  int lm = lane & 15, quad = lane >> 4;
  int mt1 = (cnt - r0 > 16) ? 2 : 1;
  f32x4 acc[2][6] = {};
  for (int kb = 0; kb < J; kb += 32){
    __syncthreads();
    for (int idx = t; idx < 32*48; idx += 256){
      int j = idx/48, cg = idx - j*48;
      uint4 v = (kb+j < J)? ((const uint4*)(src + (size_t)(kb+j)*D6))[cg] : make_uint4(0,0,0,0);
      *(uint4*)(tbuf + j*392 + cg*8) = v;
    }
    short8v af0, af1;
    {
      const bf16t* ap = Sg + (size_t)(r0 + lm)*SMM + kb + quad*8;
      af0 = *(const short8v*)ap;
      af1 = (mt1 > 1)? *(const short8v*)(ap + 16*SMM) : af0;
    }
    __syncthreads();
    #pragma unroll
    for (int ni = 0; ni < 6; ni++){
      int nt = w*6 + ni;
      short8v bf;
      #pragma unroll
      for (int ji = 0; ji < 8; ji++)
        bf[ji] = (short)tbuf[(quad*8 + ji)*392 + nt*16 + lm];
      acc[0][ni] = __builtin_amdgcn_mfma_f32_16x16x32_bf16(af0, bf, acc[0][ni], 0, 0, 0);
      if (mt1 > 1)
        acc[1][ni] = __builtin_amdgcn_mfma_f32_16x16x32_bf16(af1, bf, acc[1][ni], 0, 0, 0);
    }
  }
  for (int mt = 0; mt < mt1; mt++)
    for (int ni = 0; ni < 6; ni++){
      int nt = w*6 + ni;
      #pragma unroll
      for (int r = 0; r < 4; r++){
        int row = r0 + mt*16 + quad*4 + r;
        if (row < cnt) dst[(size_t)row*D6 + nt*16 + lm] = f2bf(acc[mt][ni][r]);
      }
    }
}

// ---------- set2set ----------

__global__ void k_h0(const float* bih, const float* bhh, float* h0, float* c0){
  int j = threadIdx.x;
  float gi = bih[j]      + bhh[j];
  float gg = bih[2*D6+j] + bhh[2*D6+j];
  float go = bih[3*D6+j] + bhh[3*D6+j];
  float c = sigf(gi)*tanhf(gg);
  c0[j]=c;
  h0[j]=sigf(go)*tanhf(c);
}

__global__ __launch_bounds__(64) void k_cvec(const float* __restrict__ Wih, const float* __restrict__ Whh,
                                             const float* bih, const float* bhh,
                                             const float* __restrict__ h0, float* __restrict__ cvec){
  int j = blockIdx.x, lane = threadIdx.x;
  const float4* wi = (const float4*)(Wih + (size_t)j*(2*D6));
  const float4* wh = (const float4*)(Whh + (size_t)j*D6);
  const float4* h4 = (const float4*)h0;
  float acc=0;
  #pragma unroll
  for (int m=0;m<3;m++){
    float4 hv = h4[m*64+lane];
    float4 a = wi[m*64+lane];
    float4 b = wh[m*64+lane];
    acc += hv.x*(a.x+b.x) + hv.y*(a.y+b.y) + hv.z*(a.z+b.z) + hv.w*(a.w+b.w);
  }
  #pragma unroll
  for (int m=1;m<64;m<<=1) acc += __shfl_xor(acc,m,64);
  if (lane==0) cvec[j]=acc+bih[j]+bhh[j];
}

// fused attention: e=x.hv, segment softmax, r=sum a*x; x is bf16; r written bf16
__global__ __launch_bounds__(256) void k_att(const bf16t* __restrict__ f1, const bf16t* __restrict__ f2,
                                             const float* __restrict__ hbase, int perseg,
                                             const int* __restrict__ st1, const int* __restrict__ st2,
                                             bf16t* __restrict__ dst16, long sidestep, long dstride){
  __shared__ float4 hs[192];
  __shared__ float e_s[SMM];
  int side = blockIdx.x >> 8, g = blockIdx.x & (NB-1);
  const int* st = side? st2:st1;
  int n0 = st[g]; int cnt = st[g+1]-n0; if (cnt>SMM) cnt=SMM;
  const bf16t* x = (side? f2:f1) + (size_t)n0*D6;
  const float* hv = hbase + (perseg? (size_t)(side*NB+g)*D6 : 0);
  int t = threadIdx.x, w = t>>6, lane = t&63;
  if (t<192) hs[t] = ((const float4*)hv)[t];
  __syncthreads();
  for (int n=w; n<cnt; n+=4){
    const uint2* xr = (const uint2*)(x + (size_t)n*D6);
    float p = 0;
    #pragma unroll
    for (int m=0;m<3;m++){
      uint2 rv = xr[m*64+lane];
      float4 hvv = hs[m*64+lane];
      p += bfl(rv.x)*hvv.x + bfh(rv.x)*hvv.y + bfl(rv.y)*hvv.z + bfh(rv.y)*hvv.w;
    }
    #pragma unroll
    for (int m=1;m<64;m<<=1) p += __shfl_xor(p,m,64);
    if (lane==0) e_s[n]=p;
  }
  __syncthreads();
  if (w==0){
    float mx=-INFINITY;
    for (int n=lane;n<cnt;n+=64) mx=fmaxf(mx,e_s[n]);
    #pragma unroll
    for (int m=1;m<64;m<<=1) mx=fmaxf(mx,__shfl_xor(mx,m,64));
    float s=0;
    for (int n=lane;n<cnt;n+=64) s+=__expf(e_s[n]-mx);
    #pragma unroll
    for (int m=1;m<64;m<<=1) s+=__shfl_xor(s,m,64);
    float inv=1.0f/s;
    for (int n=lane;n<cnt;n+=64) e_s[n]=__expf(e_s[n]-mx)*inv;
  }
  __syncthreads();
  if (t<192){
    float4 acc={0,0,0,0};
    for (int n=0;n<cnt;n++){
      float a = e_s[n];
      uint2 rv = ((const uint2*)(x + (size_t)n*D6))[t];
      acc.x+=a*bfl(rv.x); acc.y+=a*bfh(rv.x); acc.z+=a*bfl(rv.y); acc.w+=a*bfh(rv.y);
    }
    ushort4 o = make_ushort4(f2bf(acc.x), f2bf(acc.y), f2bf(acc.z), f2bf(acc.w));
    ((ushort4*)(dst16 + side*sidestep + (size_t)g*dstride))[t]=o;
  }
}

// gates GEMM via bf16 MFMA, no split-K: pout[512][3072]
__global__ __launch_bounds__(256) void k_gemm_mfma(const short* __restrict__ A16,
                                                   const short* __restrict__ B16,
                                                   float* __restrict__ pout){
  int w = threadIdx.x >> 6, lane = threadIdx.x & 63;
  int lm = lane & 15, quad = lane >> 4;
  int bm = blockIdx.x * 16;
  int bn = blockIdx.y * 256 + w * 64;
  const short* a = A16 + (size_t)(bm + lm)*768 + quad*8;
  const short* b = B16 + (size_t)(bn + lm)*768 + quad*8;
  f32x4 acc0={0,0,0,0}, acc1={0,0,0,0}, acc2={0,0,0,0}, acc3={0,0,0,0};
  for (int k=0; k<768; k+=32){
    short8v af = *(const short8v*)(a + k);
    short8v b0 = *(const short8v*)(b + k);
    short8v b1 = *(const short8v*)(b + 16*768 + k);
    short8v b2 = *(const short8v*)(b + 32*768 + k);
    short8v b3 = *(const short8v*)(b + 48*768 + k);
    acc0 = __builtin_amdgcn_mfma_f32_16x16x32_bf16(af, b0, acc0, 0, 0, 0);
    acc1 = __builtin_amdgcn_mfma_f32_16x16x32_bf16(af, b1, acc1, 0, 0, 0);
    acc2 = __builtin_amdgcn_mfma_f32_16x16x32_bf16(af, b2, acc2, 0, 0, 0);
    acc3 = __builtin_amdgcn_mfma_f32_16x16x32_bf16(af, b3, acc3, 0, 0, 0);
  }
  #pragma unroll
  for (int r=0;r<4;r++){
    size_t base = (size_t)(bm + quad*4 + r)*3072 + bn + lm;
    pout[base]      = acc0[r];
    pout[base + 16] = acc1[r];
    pout[base + 32] = acc2[r];
    pout[base + 48] = acc3[r];
  }
}

// p1 GEMM via MFMA, split-K=16: pout[z][256x256] = Z16[256x3072-chunk] @ Wp116^T
__global__ __launch_bounds__(256) void k_gemm_mfma_p1(const short* __restrict__ A16,
                                                      const short* __restrict__ B16,
                                                      float* __restrict__ pout){
  int w = threadIdx.x >> 6, lane = threadIdx.x & 63;
  int lm = lane & 15, quad = lane >> 4;
  int bm = blockIdx.x * 16;
  int bn = w * 64;
  int kbase = blockIdx.y * 192;
  const short* a = A16 + (size_t)(bm + lm)*3072 + quad*8 + kbase;
  const short* b = B16 + (size_t)(bn + lm)*3072 + quad*8 + kbase;
  f32x4 acc0={0,0,0,0}, acc1={0,0,0,0}, acc2={0,0,0,0}, acc3={0,0,0,0};
  for (int k=0; k<192; k+=32){
    short8v af = *(const short8v*)(a + k);
    short8v b0 = *(const short8v*)(b + k);
    short8v b1 = *(const short8v*)(b + 16*3072 + k);
    short8v b2 = *(const short8v*)(b + 32*3072 + k);
    short8v b3 = *(const short8v*)(b + 48*3072 + k);
    acc0 = __builtin_amdgcn_mfma_f32_16x16x32_bf16(af, b0, acc0, 0, 0, 0);
    acc1 = __builtin_amdgcn_mfma_f32_16x16x32_bf16(af, b1, acc1, 0, 0, 0);
    acc2 = __builtin_amdgcn_mfma_f32_16x16x32_bf16(af, b2, acc2, 0, 0, 0);
    acc3 = __builtin_amdgcn_mfma_f32_16x16x32_bf16(af, b3, acc3, 0, 0, 0);
  }
  float* po = pout + (size_t)blockIdx.y*256*256;
  #pragma unroll
  for (int r=0;r<4;r++){
    size_t base = (size_t)(bm + quad*4 + r)*256 + bn + lm;
    po[base]      = acc0[r];
    po[base + 16] = acc1[r];
    po[base + 32] = acc2[r];
    po[base + 48] = acc3[r];
  }
}

// Wih right half -> contiguous bf16 [3072][768]
__global__ __launch_bounds__(256) void k_conv_w(const float* __restrict__ W, short* __restrict__ dst){
  int t = blockIdx.x*256 + threadIdx.x;
  int n = t/192, q = t - n*192;
  float4 v = ((const float4*)(W + (size_t)n*1536 + 768))[q];
  short4 o = { (short)f2bf(v.x), (short)f2bf(v.y), (short)f2bf(v.z), (short)f2bf(v.w) };
  ((short4*)dst)[t] = o;
}

// generic fp32 -> bf16 contiguous convert (t over float4)
__global__ __launch_bounds__(256) void k_conv(const float* __restrict__ src, short* __restrict__ dst){
  int t = blockIdx.x*256 + threadIdx.x;
  float4 v = ((const float4*)src)[t];
  short4 o = { (short)f2bf(v.x), (short)f2bf(v.y), (short)f2bf(v.z), (short)f2bf(v.w) };
  ((short4*)dst)[t] = o;
}

// split-K GEMM (small MLP layer p2)
__global__ __launch_bounds__(256) void k_gemm_sk(const float* __restrict__ A, int lda,
                                                 const float* __restrict__ B, int ldb,
                                                 float* __restrict__ partial,
                                                 int M, int N, int kchunk){
  __shared__ float As[16][68];
  __shared__ float Bs[16][68];
  int bm = blockIdx.y*64, bn = blockIdx.x*64;
  int kbase = blockIdx.z*kchunk;
  int t = threadIdx.x;
  int tx = t & 15, ty = t >> 4;
  float acc[4][4] = {};
  for (int k0=kbase;k0<kbase+kchunk;k0+=16){
    for (int l=t;l<64*16;l+=256){
      int m = l>>4, k = l&15;
      As[k][m] = A[(size_t)(bm+m)*lda + k0+k];
      Bs[k][m] = B[(size_t)(bn+m)*ldb + k0+k];
    }
    __syncthreads();
    #pragma unroll
    for (int k=0;k<16;k++){
      float4 av = *(const float4*)&As[k][ty*4];
      float4 bv = *(const float4*)&Bs[k][tx*4];
      float a4[4]={av.x,av.y,av.z,av.w};
      float b4[4]={bv.x,bv.y,bv.z,bv.w};
      #pragma unroll
      for (int i=0;i<4;i++)
        #pragma unroll
        for (int j=0;j<4;j++) acc[i][j]+=a4[i]*b4[j];
    }
    __syncthreads();
  }
  float* pout = partial + (size_t)blockIdx.z*M*N;
  #pragma unroll
  for (int i=0;i<4;i++)
    #pragma unroll
    for (int j=0;j<4;j++){
      int m = bm+ty*4+i, n = bn+tx*4+j;
      pout[(size_t)m*N+n]=acc[i][j];
    }
}

__global__ __launch_bounds__(256) void k_reduce(const float* __restrict__ partial, int S, long MN,
                                                const float* __restrict__ cv, float* __restrict__ dst,
                                                int N, int act){
  long idx = (long)blockIdx.x*256 + threadIdx.x;
  if (idx >= MN) return;
  float s = 0;
  for (int p=0;p<S;p++) s += partial[(size_t)p*MN + idx];
  s += cv[idx % N];
  if (act) s = fmaxf(s,0.f);
  dst[idx]=s;
}

// fused: gates + cvec + LSTM step-1 pointwise; z written bf16
__global__ __launch_bounds__(256) void k_lstm_red(const float* __restrict__ pbuf,
                                                  const float* __restrict__ cvec,
                                                  const float* __restrict__ c0,
                                                  float* __restrict__ h1s, bf16t* __restrict__ z16){
  int t = blockIdx.x*256 + threadIdx.x;   // 512*768
  int m = t/D6, j = t - m*D6;
  const float* p0 = pbuf + (size_t)m*3072 + j;
  float g4[4];
  #pragma unroll
  for (int q=0;q<4;q++) g4[q] = cvec[q*D6 + j] + p0[q*D6];
  float c = sigf(g4[1])*c0[j] + sigf(g4[0])*tanhf(g4[2]);
  float h = sigf(g4[3])*tanhf(c);
  h1s[(size_t)m*D6 + j] = h;
  int side = m>>8, g = m&255;
  z16[(size_t)g*3072 + side*1536 + j] = f2bf(h);
}

__global__ __launch_bounds__(128) void k_p3(const float* __restrict__ z2, const float* __restrict__ W,
                                            const float* b, float* __restrict__ out){
  int m=blockIdx.x, t=threadIdx.x;
  float p = z2[m*128+t]*W[t];
  #pragma unroll
  for (int o=32;o;o>>=1) p += __shfl_down(p,o,64);
  __shared__ float ws[2];
  if ((t&63)==0) ws[t>>6]=p;
  __syncthreads();
  if (t==0){ float v=ws[0]+ws[1]+b[0]; out[m]=1.0f/(1.0f+__expf(-v)); }
}

// ---------- launch ----------

extern "C" void kernel_launch(void* const* d_in, const int* in_sizes, int n_in,
                              void* d_out, int out_size, void* d_ws, size_t ws_size,
                              hipStream_t stream){
  const float* feat1=(const float*)d_in[0];
  const float* feat2=(const float*)d_in[1];
  const float* ea1  =(const float*)d_in[2];
  const float* ea2  =(const float*)d_in[3];
  const float* W0=(const float*)d_in[4];  const float* b0=(const float*)d_in[5];
  const float* W1=(const float*)d_in[6];  const float* b1=(const float*)d_in[7];
  const float* W2=(const float*)d_in[8];  const float* b2=(const float*)d_in[9];
  const float* Wih=(const float*)d_in[10]; const float* bih=(const float*)d_in[11];
  const float* Whh=(const float*)d_in[12]; const float* bhh=(const float*)d_in[13];
  const float* Wp1=(const float*)d_in[14]; const float* bp1=(const float*)d_in[15];
  const float* Wp2=(const float*)d_in[16]; const float* bp2=(const float*)d_in[17];
  const float* Wp3=(const float*)d_in[18]; const float* bp3=(const float*)d_in[19];
  const int* ei1=(const int*)d_in[20]; const int* ei2=(const int*)d_in[21];
  const int* batch1=(const int*)d_in[22]; const int* batch2=(const int*)d_in[23];
  float* out = (float*)d_out;

  float* base = (float*)d_ws;
  size_t off = 0;
  auto alloc = [&](size_t n)->float* { float* r = base + off; off += (n + 255) & ~(size_t)255; return r; };
  float* deg1 = alloc(N_NODES);          float* deg2 = alloc(N_NODES);
  bf16t* xw1  = (bf16t*)alloc((size_t)N_NODES*NH/2);
  bf16t* xw2  = (bf16t*)alloc((size_t)N_NODES*NH/2);
  float* h1   = alloc((size_t)N_NODES*D3);
  float* h2   = alloc((size_t)N_NODES*D3);
  bf16t* f1   = (bf16t*)alloc((size_t)N_NODES*D6/2);
  bf16t* f2   = (bf16t*)alloc((size_t)N_NODES*D6/2);
  float* ecoef1 = alloc(N_EDGES);        float* ecoef2 = alloc(N_EDGES);
  float* h0   = alloc(D6);  float* c0 = alloc(D6);  float* cvec = alloc(4*D6);
  bf16t* Sbuf = (bf16t*)alloc((size_t)NB*SMM*SMM);       // S followed by ST
  bf16t* STbuf= Sbuf + (size_t)NB*SMM*SMM;
  float* h1s  = alloc((size_t)512*D6);
  bf16t* zbuf16 = (bf16t*)alloc((size_t)256*3072/2);
  float* z1   = alloc((size_t)256*256);
  float* z2b  = alloc((size_t)256*128);
  float* pbuf = alloc((size_t)4*512*3072);
  short* Abuf16 = (short*)alloc((size_t)512*D6/2);
  short* Wih16  = (short*)alloc((size_t)3072*D6/2);
  short* Wp116  = (short*)alloc((size_t)256*3072/2);
  int* cnt1 = (int*)alloc(NB);   int* cnt2 = (int*)alloc(NB);
  int* st1  = (int*)alloc(NB+1); int* st2  = (int*)alloc(NB+1);
  int* ecnt1= (int*)alloc(N_NODES); int* ecnt2 = (int*)alloc(N_NODES);
  int* eoff1= (int*)alloc(N_NODES+1); int* eoff2 = (int*)alloc(N_NODES+1);
  int* ecur1= (int*)alloc(N_NODES); int* ecur2 = (int*)alloc(N_NODES);
  int* esrc1= (int*)alloc(N_EDGES); int* esrc2 = (int*)alloc(N_EDGES);
  (void)ws_size; (void)in_sizes; (void)n_in; (void)out_size;

  k_init   <<<32,256,0,stream>>>(deg1,deg2,ecnt1,ecnt2,cnt1,cnt2);
  k_deg    <<<1024,256,0,stream>>>(ei1,ea1,deg1,ecnt1, ei2,ea2,deg2,ecnt2, batch1,batch2,cnt1,cnt2);
  k_dinv   <<<32,256,0,stream>>>(deg1,deg2);
  k_scan256<<<2,256,0,stream>>>(cnt1,cnt2,st1,st2);
  k_escan  <<<2,1024,0,stream>>>(ecnt1,ecnt2,eoff1,ecur1,eoff2,ecur2);
  k_fill   <<<1024,256,0,stream>>>(ei1,ea1,deg1,ecur1,esrc1,ecoef1, ei2,ea2,deg2,ecur2,esrc2,ecoef2);
  k_conv_w <<<2304,256,0,stream>>>(Wih, Wih16);
  k_conv   <<<768,256,0,stream>>>(Wp1, Wp116);
  k_szero  <<<2304,256,0,stream>>>((uint4*)Sbuf);

  const float* Ws[3]={W0,W1,W2}; const float* bs[3]={b0,b1,b2};
  for (int l=0;l<3;l++){
    const float* x1 = (l==0)? feat1 : (h1 + (l-1)*NH);
    const float* x2 = (l==0)? feat2 : (h2 + (l-1)*NH);
    int xs = (l==0)? 64 : D3;
    int K  = (l==0)? 64 : NH;
    k_xw    <<<2048,128,0,stream>>>(x1,x2,xs,K,Ws[l],xw1,xw2);
    k_gather<<<2048,256,0,stream>>>(xw1,xw2,eoff1,eoff2,esrc1,esrc2,ecoef1,ecoef2,
                                    deg1,deg2,bs[l],h1,h2,l*NH);
  }

  k_l2norm<<<16384,128,0,stream>>>(h1,h2,f1,f2);
  k_smat  <<<dim3(256,36),256,0,stream>>>(f1,f2,st1,st2,Sbuf,STbuf);
  k_apply <<<dim3(512,3),256,0,stream>>>(f1,f2,st1,st2,Sbuf,STbuf);

  k_h0  <<<1,768,0,stream>>>(bih,bhh,h0,c0);
  k_cvec<<<3072,64,0,stream>>>(Wih,Whh,bih,bhh,h0,cvec);

  // step-1 attention (shared h0) -> Abuf16 bf16 rows [side*256+g]
  k_att<<<512,256,0,stream>>>(f1,f2,h0,0,st1,st2,(bf16t*)Abuf16,(long)256*D6,(long)D6);

  // gates = Abuf16 @ Wih16^T + cvec via bf16 MFMA, fused reduce+LSTM (z in bf16)
  k_gemm_mfma<<<dim3(32,12),256,0,stream>>>(Abuf16, Wih16, pbuf);
  k_lstm_red <<<1536,256,0,stream>>>(pbuf,cvec,c0,h1s,zbuf16);

  // step-2 attention (per-segment h) -> zbuf16 r-slots (bf16)
  k_att<<<512,256,0,stream>>>(f1,f2,h1s,1,st1,st2,zbuf16+768,(long)1536,(long)3072);

  // MLP: p1 via MFMA (split-K=16) + reduce(bias,relu); p2 split-K fp32; p3
  k_gemm_mfma_p1<<<dim3(16,16),256,0,stream>>>((const short*)zbuf16, Wp116, pbuf);
  k_reduce <<<256,256,0,stream>>>(pbuf,16,(long)256*256, bp1, z1, 256, 1);
  k_gemm_sk<<<dim3(2,4,4),256,0,stream>>>(z1,256, Wp2,256, pbuf, 256, 128, 64);
  k_reduce <<<128,256,0,stream>>>(pbuf,4,(long)256*128, bp2, z2b, 128, 1);
  k_p3  <<<256,128,0,stream>>>(z2b,Wp3,bp3,out);
}

// Round 13
// 393.989 us; speedup vs baseline: 1.2015x; 1.0219x over previous
//
#include <hip/hip_runtime.h>
#include <cmath>

#define N_NODES 8192
#define N_EDGES 131072
#define NB      256
#define NH      128
#define D3      384
#define D6      768
#define SMM     96   // max nodes per (graph,side); Binomial(8192,1/256) mean 32, 96 = 11 sigma

typedef __attribute__((ext_vector_type(8))) short short8v;
typedef __attribute__((ext_vector_type(4))) float f32x4;
typedef unsigned short bf16t;

__device__ __forceinline__ float sigf(float x){ return 1.0f/(1.0f+__expf(-x)); }
__device__ __forceinline__ unsigned short f2bf(float x){
  unsigned u = __float_as_uint(x);
  unsigned r = u + 0x7FFF + ((u>>16)&1);   // round-to-nearest-even
  return (unsigned short)(r>>16);
}
__device__ __forceinline__ float bfl(unsigned u){ return __uint_as_float(u<<16); }
__device__ __forceinline__ float bfh(unsigned u){ return __uint_as_float(u & 0xFFFF0000u); }
__device__ __forceinline__ float b2f(bf16t u){ return __uint_as_float(((unsigned)u)<<16); }

// ---------- setup ----------

__global__ void k_init(float* deg1, float* deg2, int* ecnt1, int* ecnt2, int* cnt1, int* cnt2){
  int t = blockIdx.x*blockDim.x + threadIdx.x;
  if (t < N_NODES){ deg1[t]=1.f; deg2[t]=1.f; ecnt1[t]=0; ecnt2[t]=0; }
  if (t < NB){ cnt1[t]=0; cnt2[t]=0; }
}

__global__ void k_deg(const int* __restrict__ ei1, const float* __restrict__ ea1, float* deg1, int* ecnt1,
                      const int* __restrict__ ei2, const float* __restrict__ ea2, float* deg2, int* ecnt2,
                      const int* __restrict__ b1, const int* __restrict__ b2, int* cnt1, int* cnt2){
  int idx = blockIdx.x*blockDim.x + threadIdx.x;
  int side = idx >= N_EDGES;
  int e = idx & (N_EDGES-1);
  const int* ei = side? ei2:ei1; const float* ea = side? ea2:ea1;
  float* deg = side? deg2:deg1;  int* ecnt = side? ecnt2:ecnt1;
  int d = ei[N_EDGES+e];
  atomicAdd(&deg[d], ea[e]);
  atomicAdd(&ecnt[d], 1);
  if (idx < N_NODES){ atomicAdd(&cnt1[b1[idx]],1); atomicAdd(&cnt2[b2[idx]],1); }
}

__global__ void k_dinv(float* deg1, float* deg2){
  int t = blockIdx.x*blockDim.x + threadIdx.x;
  if (t < N_NODES){ deg1[t]=rsqrtf(deg1[t]); deg2[t]=rsqrtf(deg2[t]); }
}

__global__ __launch_bounds__(256) void k_scan256(const int* c1, const int* c2, int* s1, int* s2){
  const int* c = blockIdx.x? c2:c1; int* st = blockIdx.x? s2:s1;
  __shared__ int ps[256];
  int t = threadIdx.x;
  ps[t]=c[t]; __syncthreads();
  for (int d=1; d<256; d<<=1){
    int v = (t>=d)? ps[t-d]:0;
    __syncthreads();
    ps[t]+=v;
    __syncthreads();
  }
  st[t+1]=ps[t];
  if (t==0) st[0]=0;
}

__global__ __launch_bounds__(1024) void k_escan(const int* ec1, const int* ec2,
                                                int* off1, int* cur1, int* off2, int* cur2){
  const int* cnt = blockIdx.x? ec2:ec1;
  int* off = blockIdx.x? off2:off1;
  int* cur = blockIdx.x? cur2:cur1;
  __shared__ int ps[1024];
  int t = threadIdx.x;
  int base = t*8;
  int loc[8]; int s=0;
  #pragma unroll
  for (int k=0;k<8;k++){ loc[k]=s; s+=cnt[base+k]; }
  ps[t]=s; __syncthreads();
  for (int d=1; d<1024; d<<=1){
    int v = (t>=d)? ps[t-d]:0;
    __syncthreads();
    ps[t]+=v;
    __syncthreads();
  }
  int pre = (t==0)? 0 : ps[t-1];
  #pragma unroll
  for (int k=0;k<8;k++){ int v=pre+loc[k]; off[base+k]=v; cur[base+k]=v; }
  if (t==1023) off[N_NODES]=ps[1023];
}

__global__ void k_fill(const int* __restrict__ ei1, const float* __restrict__ ea1, const float* __restrict__ d1,
                       int* cur1, int* es1, float* ec1,
                       const int* __restrict__ ei2, const float* __restrict__ ea2, const float* __restrict__ d2,
                       int* cur2, int* es2, float* ec2){
  int idx = blockIdx.x*blockDim.x + threadIdx.x;
  int side = idx >= N_EDGES;
  int e = idx & (N_EDGES-1);
  const int* ei = side? ei2:ei1; const float* ea = side? ea2:ea1;
  const float* dinv = side? d2:d1;
  int* cur = side? cur2:cur1; int* es = side? es2:es1; float* ec = side? ec2:ec1;
  int s = ei[e], d = ei[N_EDGES+e];
  int pos = atomicAdd(&cur[d], 1);
  es[pos] = s;
  ec[pos] = dinv[s]*ea[e]*dinv[d];
}

// zero S and ST: 2 * NB*96*96 bf16 = 589824 uint4
__global__ __launch_bounds__(256) void k_szero(uint4* p){
  p[blockIdx.x*256 + threadIdx.x] = make_uint4(0,0,0,0);
}

// ---------- GCN ----------

// xw = x@W in fp32, stored bf16 (halves gather's random-read bytes)
__global__ __launch_bounds__(128) void k_xw(const float* __restrict__ x1, const float* __restrict__ x2,
                                            int xs, int K, const float* __restrict__ W,
                                            bf16t* __restrict__ xw1, bf16t* __restrict__ xw2){
  __shared__ float xr[8][128];
  int blk = blockIdx.x;
  int side = blk >> 10; int b = blk & 1023;
  const float* x = side? x2:x1;
  bf16t* xw = side? xw2:xw1;
  int i0 = b*8;
  int c = threadIdx.x;
  for (int idx=c; idx<8*K; idx+=128){
    int r = idx / K, k = idx - r*K;
    xr[r][k] = x[(size_t)(i0+r)*xs + k];
  }
  __syncthreads();
  float acc[8]={0,0,0,0,0,0,0,0};
  for (int k=0;k<K;k++){
    float w = W[k*NH+c];
    #pragma unroll
    for (int r=0;r<8;r++) acc[r]+=xr[r][k]*w;
  }
  #pragma unroll
  for (int r=0;r<8;r++) xw[(size_t)(i0+r)*NH+c]=f2bf(acc[r]);
}

// fused self-loop + CSR gather + bias + leaky; xw bf16, fp32 accumulate
__global__ __launch_bounds__(256) void k_gather(const bf16t* __restrict__ xw1, const bf16t* __restrict__ xw2,
                                                const int* __restrict__ off1, const int* __restrict__ off2,
                                                const int* __restrict__ es1, const int* __restrict__ es2,
                                                const float* __restrict__ ec1, const float* __restrict__ ec2,
                                                const float* __restrict__ d1, const float* __restrict__ d2,
                                                const float* __restrict__ b,
                                                float* __restrict__ h1, float* __restrict__ h2, int loff){
  int blk = blockIdx.x;
  int side = blk >> 10; int bb = blk & 1023;
  const ushort4* xw = (const ushort4*)(side? xw2:xw1);
  const int* off = side? off2:off1;
  const int* es  = side? es2:es1;
  const float* ec= side? ec2:ec1;
  const float* dinv = side? d2:d1;
  float* h = side? h2:h1;
  int t = threadIdx.x;
  int i = bb*8 + (t>>5);
  int c4 = t & 31;
  float dv = dinv[i];
  ushort4 v = xw[(size_t)i*32 + c4];
  float sc = dv*dv;
  float4 acc = {b2f(v.x)*sc, b2f(v.y)*sc, b2f(v.z)*sc, b2f(v.w)*sc};
  int r = off[i], r1 = off[i+1];
  for (; r+3<r1; r+=4){
    int s0=es[r], s1=es[r+1], s2=es[r+2], s3=es[r+3];
    float w0=ec[r], w1=ec[r+1], w2=ec[r+2], w3=ec[r+3];
    ushort4 u0 = xw[(size_t)s0*32 + c4];
    ushort4 u1 = xw[(size_t)s1*32 + c4];
    ushort4 u2 = xw[(size_t)s2*32 + c4];
    ushort4 u3 = xw[(size_t)s3*32 + c4];
    acc.x += b2f(u0.x)*w0 + b2f(u1.x)*w1 + b2f(u2.x)*w2 + b2f(u3.x)*w3;
    acc.y += b2f(u0.y)*w0 + b2f(u1.y)*w1 + b2f(u2.y)*w2 + b2f(u3.y)*w3;
    acc.z += b2f(u0.z)*w0 + b2f(u1.z)*w1 + b2f(u2.z)*w2 + b2f(u3.z)*w3;
    acc.w += b2f(u0.w)*w0 + b2f(u1.w)*w1 + b2f(u2.w)*w2 + b2f(u3.w)*w3;
  }
  for (; r<r1; r++){
    int s0=es[r]; float w0=ec[r];
    ushort4 u0 = xw[(size_t)s0*32 + c4];
    acc.x+=b2f(u0.x)*w0; acc.y+=b2f(u0.y)*w0; acc.z+=b2f(u0.z)*w0; acc.w+=b2f(u0.w)*w0;
  }
  float4 bv = ((const float4*)b)[c4];
  acc.x+=bv.x; acc.y+=bv.y; acc.z+=bv.z; acc.w+=bv.w;
  acc.x = (acc.x>0.f)?acc.x:0.2f*acc.x;
  acc.y = (acc.y>0.f)?acc.y:0.2f*acc.y;
  acc.z = (acc.z>0.f)?acc.z:0.2f*acc.z;
  acc.w = (acc.w>0.f)?acc.w:0.2f*acc.w;
  ((float4*)(h + (size_t)i*D3 + loff))[c4] = acc;
}

// ---------- l2 normalize -> bf16 f[:, 0:384] ----------
__global__ __launch_bounds__(128) void k_l2norm(const float* __restrict__ h1, const float* __restrict__ h2,
                                                bf16t* __restrict__ f1, bf16t* __restrict__ f2){
  int blk = blockIdx.x;
  int side = blk >> 13; int i = blk & (N_NODES-1);
  const float* h = side? h2:h1; bf16t* f = side? f2:f1;
  int t = threadIdx.x;
  float v0=h[(size_t)i*D3+t], v1=h[(size_t)i*D3+128+t], v2=h[(size_t)i*D3+256+t];
  float ss = v0*v0+v1*v1+v2*v2;
  #pragma unroll
  for (int o=32;o;o>>=1) ss += __shfl_down(ss,o,64);
  __shared__ float ws[2];
  if ((t&63)==0) ws[t>>6]=ss;
  __syncthreads();
  float scale = 1.0f/fmaxf(sqrtf(ws[0]+ws[1]), 1e-12f);
  f[(size_t)i*D6+t]      = f2bf(v0*scale);
  f[(size_t)i*D6+128+t]  = f2bf(v1*scale);
  f[(size_t)i*D6+256+t]  = f2bf(v2*scale);
}

// ---------- interaction part 1 via MFMA: S = f1.f2^T, direct global frags ----------
// grid (256 graphs, 9 supertiles of 32x32); 4 waves = 4 16x16 tiles; K=384 = 12 MFMA
__global__ __launch_bounds__(256) void k_smat(const bf16t* __restrict__ f1, const bf16t* __restrict__ f2,
                                              const int* __restrict__ st1, const int* __restrict__ st2,
                                              bf16t* __restrict__ S, bf16t* __restrict__ ST){
  int g = blockIdx.x;
  int it2 = blockIdx.y/3, jt2 = blockIdx.y - it2*3;
  int i0 = st1[g]; int n1 = st1[g+1]-i0; if (n1>SMM) n1=SMM;
  int j0 = st2[g]; int n2 = st2[g+1]-j0; if (n2>SMM) n2=SMM;
  if (it2*32 >= n1 || jt2*32 >= n2) return;
  int w = threadIdx.x >> 6, lane = threadIdx.x & 63;
  int lm = lane & 15, quad = lane >> 4;
  int ti = it2*2 + (w>>1), tj = jt2*2 + (w&1);
  if (ti*16 >= n1 || tj*16 >= n2) return;
  // both operands k-contiguous row-major -> direct global loads
  const bf16t* a = f1 + (size_t)(i0 + ti*16 + lm)*D6 + quad*8;
  const bf16t* b = f2 + (size_t)(j0 + tj*16 + lm)*D6 + quad*8;
  f32x4 acc = {0,0,0,0};
  #pragma unroll
  for (int k=0; k<384; k+=32){
    short8v af = *(const short8v*)(a + k);
    short8v bf = *(const short8v*)(b + k);
    acc = __builtin_amdgcn_mfma_f32_16x16x32_bf16(af, bf, acc, 0, 0, 0);
  }
  bf16t* Sg  = S  + (size_t)g*SMM*SMM;
  bf16t* STg = ST + (size_t)g*SMM*SMM;
  int col = tj*16 + lm;
  #pragma unroll
  for (int r=0;r<4;r++){
    int row = ti*16 + quad*4 + r;           // D: row = quad*4+reg, col = lane&15
    if (row < n1 && col < n2){
      bf16t v = f2bf(acc[r]);
      Sg [(size_t)row*SMM + col] = v;
      STg[(size_t)col*SMM + row] = v;
    }
  }
}

// ---------- interaction part 2 via MFMA: out = Srow @ src ----------
__global__ __launch_bounds__(256) void k_apply(bf16t* __restrict__ f1, bf16t* __restrict__ f2,
                                               const int* __restrict__ st1, const int* __restrict__ st2,
                                               const bf16t* __restrict__ S, const bf16t* __restrict__ ST){
  __shared__ bf16t tbuf[32*392];   // 24.5 KB
  int bx = blockIdx.x;
  int side = bx >> 8, g = bx & (NB-1);
  int a0 = st1[g]; int n1 = st1[g+1]-a0; if (n1>SMM) n1=SMM;
  int b0 = st2[g]; int n2 = st2[g+1]-b0; if (n2>SMM) n2=SMM;
  int cnt = side? n2 : n1;
  int J   = side? n1 : n2;
  int r0 = blockIdx.y*32;
  if (r0 >= cnt) return;
  const bf16t* src = side? (f1 + (size_t)a0*D6) : (f2 + (size_t)b0*D6);
  bf16t* dst = (side? (f2 + (size_t)b0*D6) : (f1 + (size_t)a0*D6)) + D3;
  const bf16t* Sg = (side? ST : S) + (size_t)g*SMM*SMM;
  int t = threadIdx.x, w = t>>6, lane = t&63;
  int lm = lane & 15, quad = lane >> 4;
  int mt1 = (cnt - r0 > 16) ? 2 : 1;
  f32x4 acc[2][6] = {};
  for (int kb = 0; kb < J; kb += 32){
    __syncthreads();
    for (int idx = t; idx < 32*48; idx += 256){
      int j = idx/48, cg = idx - j*48;
      uint4 v = (kb+j < J)? ((const uint4*)(src + (size_t)(kb+j)*D6))[cg] : make_uint4(0,0,0,0);
      *(uint4*)(tbuf + j*392 + cg*8) = v;
    }
    short8v af0, af1;
    {
      const bf16t* ap = Sg + (size_t)(r0 + lm)*SMM + kb + quad*8;
      af0 = *(const short8v*)ap;
      af1 = (mt1 > 1)? *(const short8v*)(ap + 16*SMM) : af0;
    }
    __syncthreads();
    #pragma unroll
    for (int ni = 0; ni < 6; ni++){
      int nt = w*6 + ni;
      short8v bf;
      #pragma unroll
      for (int ji = 0; ji < 8; ji++)
        bf[ji] = (short)tbuf[(quad*8 + ji)*392 + nt*16 + lm];
      acc[0][ni] = __builtin_amdgcn_mfma_f32_16x16x32_bf16(af0, bf, acc[0][ni], 0, 0, 0);
      if (mt1 > 1)
        acc[1][ni] = __builtin_amdgcn_mfma_f32_16x16x32_bf16(af1, bf, acc[1][ni], 0, 0, 0);
    }
  }
  for (int mt = 0; mt < mt1; mt++)
    for (int ni = 0; ni < 6; ni++){
      int nt = w*6 + ni;
      #pragma unroll
      for (int r = 0; r < 4; r++){
        int row = r0 + mt*16 + quad*4 + r;
        if (row < cnt) dst[(size_t)row*D6 + nt*16 + lm] = f2bf(acc[mt][ni][r]);
      }
    }
}

// ---------- set2set ----------

__global__ void k_h0(const float* bih, const float* bhh, float* h0, float* c0){
  int j = threadIdx.x;
  float gi = bih[j]      + bhh[j];
  float gg = bih[2*D6+j] + bhh[2*D6+j];
  float go = bih[3*D6+j] + bhh[3*D6+j];
  float c = sigf(gi)*tanhf(gg);
  c0[j]=c;
  h0[j]=sigf(go)*tanhf(c);
}

__global__ __launch_bounds__(64) void k_cvec(const float* __restrict__ Wih, const float* __restrict__ Whh,
                                             const float* bih, const float* bhh,
                                             const float* __restrict__ h0, float* __restrict__ cvec){
  int j = blockIdx.x, lane = threadIdx.x;
  const float4* wi = (const float4*)(Wih + (size_t)j*(2*D6));
  const float4* wh = (const float4*)(Whh + (size_t)j*D6);
  const float4* h4 = (const float4*)h0;
  float acc=0;
  #pragma unroll
  for (int m=0;m<3;m++){
    float4 hv = h4[m*64+lane];
    float4 a = wi[m*64+lane];
    float4 b = wh[m*64+lane];
    acc += hv.x*(a.x+b.x) + hv.y*(a.y+b.y) + hv.z*(a.z+b.z) + hv.w*(a.w+b.w);
  }
  #pragma unroll
  for (int m=1;m<64;m<<=1) acc += __shfl_xor(acc,m,64);
  if (lane==0) cvec[j]=acc+bih[j]+bhh[j];
}

// fused attention: e=x.hv, segment softmax, r=sum a*x; x bf16; r written bf16
__global__ __launch_bounds__(256) void k_att(const bf16t* __restrict__ f1, const bf16t* __restrict__ f2,
                                             const float* __restrict__ hbase, int perseg,
                                             const int* __restrict__ st1, const int* __restrict__ st2,
                                             bf16t* __restrict__ dst16, long sidestep, long dstride){
  __shared__ float4 hs[192];
  __shared__ float e_s[SMM];
  int side = blockIdx.x >> 8, g = blockIdx.x & (NB-1);
  const int* st = side? st2:st1;
  int n0 = st[g]; int cnt = st[g+1]-n0; if (cnt>SMM) cnt=SMM;
  const bf16t* x = (side? f2:f1) + (size_t)n0*D6;
  const float* hv = hbase + (perseg? (size_t)(side*NB+g)*D6 : 0);
  int t = threadIdx.x, w = t>>6, lane = t&63;
  if (t<192) hs[t] = ((const float4*)hv)[t];
  __syncthreads();
  for (int n=w; n<cnt; n+=4){
    const uint2* xr = (const uint2*)(x + (size_t)n*D6);
    float p = 0;
    #pragma unroll
    for (int m=0;m<3;m++){
      uint2 rv = xr[m*64+lane];
      float4 hvv = hs[m*64+lane];
      p += bfl(rv.x)*hvv.x + bfh(rv.x)*hvv.y + bfl(rv.y)*hvv.z + bfh(rv.y)*hvv.w;
    }
    #pragma unroll
    for (int m=1;m<64;m<<=1) p += __shfl_xor(p,m,64);
    if (lane==0) e_s[n]=p;
  }
  __syncthreads();
  if (w==0){
    float mx=-INFINITY;
    for (int n=lane;n<cnt;n+=64) mx=fmaxf(mx,e_s[n]);
    #pragma unroll
    for (int m=1;m<64;m<<=1) mx=fmaxf(mx,__shfl_xor(mx,m,64));
    float s=0;
    for (int n=lane;n<cnt;n+=64) s+=__expf(e_s[n]-mx);
    #pragma unroll
    for (int m=1;m<64;m<<=1) s+=__shfl_xor(s,m,64);
    float inv=1.0f/s;
    for (int n=lane;n<cnt;n+=64) e_s[n]=__expf(e_s[n]-mx)*inv;
  }
  __syncthreads();
  if (t<192){
    float4 acc={0,0,0,0};
    for (int n=0;n<cnt;n++){
      float a = e_s[n];
      uint2 rv = ((const uint2*)(x + (size_t)n*D6))[t];
      acc.x+=a*bfl(rv.x); acc.y+=a*bfh(rv.x); acc.z+=a*bfl(rv.y); acc.w+=a*bfh(rv.y);
    }
    ushort4 o = make_ushort4(f2bf(acc.x), f2bf(acc.y), f2bf(acc.z), f2bf(acc.w));
    ((ushort4*)(dst16 + side*sidestep + (size_t)g*dstride))[t]=o;
  }
}

// gates GEMM via bf16 MFMA: pout[512][3072]
__global__ __launch_bounds__(256) void k_gemm_mfma(const short* __restrict__ A16,
                                                   const short* __restrict__ B16,
                                                   float* __restrict__ pout){
  int w = threadIdx.x >> 6, lane = threadIdx.x & 63;
  int lm = lane & 15, quad = lane >> 4;
  int bm = blockIdx.x * 16;
  int bn = blockIdx.y * 256 + w * 64;
  const short* a = A16 + (size_t)(bm + lm)*768 + quad*8;
  const short* b = B16 + (size_t)(bn + lm)*768 + quad*8;
  f32x4 acc0={0,0,0,0}, acc1={0,0,0,0}, acc2={0,0,0,0}, acc3={0,0,0,0};
  for (int k=0; k<768; k+=32){
    short8v af = *(const short8v*)(a + k);
    short8v b0 = *(const short8v*)(b + k);
    short8v b1 = *(const short8v*)(b + 16*768 + k);
    short8v b2 = *(const short8v*)(b + 32*768 + k);
    short8v b3 = *(const short8v*)(b + 48*768 + k);
    acc0 = __builtin_amdgcn_mfma_f32_16x16x32_bf16(af, b0, acc0, 0, 0, 0);
    acc1 = __builtin_amdgcn_mfma_f32_16x16x32_bf16(af, b1, acc1, 0, 0, 0);
    acc2 = __builtin_amdgcn_mfma_f32_16x16x32_bf16(af, b2, acc2, 0, 0, 0);
    acc3 = __builtin_amdgcn_mfma_f32_16x16x32_bf16(af, b3, acc3, 0, 0, 0);
  }
  #pragma unroll
  for (int r=0;r<4;r++){
    size_t base = (size_t)(bm + quad*4 + r)*3072 + bn + lm;
    pout[base]      = acc0[r];
    pout[base + 16] = acc1[r];
    pout[base + 32] = acc2[r];
    pout[base + 48] = acc3[r];
  }
}

// p1 GEMM via MFMA, split-K=16: pout[z][256x256]
__global__ __launch_bounds__(256) void k_gemm_mfma_p1(const short* __restrict__ A16,
                                                      const short* __restrict__ B16,
                                                      float* __restrict__ pout){
  int w = threadIdx.x >> 6, lane = threadIdx.x & 63;
  int lm = lane & 15, quad = lane >> 4;
  int bm = blockIdx.x * 16;
  int bn = w * 64;
  int kbase = blockIdx.y * 192;
  const short* a = A16 + (size_t)(bm + lm)*3072 + quad*8 + kbase;
  const short* b = B16 + (size_t)(bn + lm)*3072 + quad*8 + kbase;
  f32x4 acc0={0,0,0,0}, acc1={0,0,0,0}, acc2={0,0,0,0}, acc3={0,0,0,0};
  for (int k=0; k<192; k+=32){
    short8v af = *(const short8v*)(a + k);
    short8v b0 = *(const short8v*)(b + k);
    short8v b1 = *(const short8v*)(b + 16*3072 + k);
    short8v b2 = *(const short8v*)(b + 32*3072 + k);
    short8v b3 = *(const short8v*)(b + 48*3072 + k);
    acc0 = __builtin_amdgcn_mfma_f32_16x16x32_bf16(af, b0, acc0, 0, 0, 0);
    acc1 = __builtin_amdgcn_mfma_f32_16x16x32_bf16(af, b1, acc1, 0, 0, 0);
    acc2 = __builtin_amdgcn_mfma_f32_16x16x32_bf16(af, b2, acc2, 0, 0, 0);
    acc3 = __builtin_amdgcn_mfma_f32_16x16x32_bf16(af, b3, acc3, 0, 0, 0);
  }
  float* po = pout + (size_t)blockIdx.y*256*256;
  #pragma unroll
  for (int r=0;r<4;r++){
    size_t base = (size_t)(bm + quad*4 + r)*256 + bn + lm;
    po[base]      = acc0[r];
    po[base + 16] = acc1[r];
    po[base + 32] = acc2[r];
    po[base + 48] = acc3[r];
  }
}

// Wih right half -> contiguous bf16 [3072][768]
__global__ __launch_bounds__(256) void k_conv_w(const float* __restrict__ W, short* __restrict__ dst){
  int t = blockIdx.x*256 + threadIdx.x;
  int n = t/192, q = t - n*192;
  float4 v = ((const float4*)(W + (size_t)n*1536 + 768))[q];
  short4 o = { (short)f2bf(v.x), (short)f2bf(v.y), (short)f2bf(v.z), (short)f2bf(v.w) };
  ((short4*)dst)[t] = o;
}

// generic fp32 -> bf16 contiguous convert
__global__ __launch_bounds__(256) void k_conv(const float* __restrict__ src, short* __restrict__ dst){
  int t = blockIdx.x*256 + threadIdx.x;
  float4 v = ((const float4*)src)[t];
  short4 o = { (short)f2bf(v.x), (short)f2bf(v.y), (short)f2bf(v.z), (short)f2bf(v.w) };
  ((short4*)dst)[t] = o;
}

__global__ __launch_bounds__(256) void k_reduce(const float* __restrict__ partial, int S, long MN,
                                                const float* __restrict__ cv, float* __restrict__ dst,
                                                int N, int act){
  long idx = (long)blockIdx.x*256 + threadIdx.x;
  if (idx >= MN) return;
  float s = 0;
  for (int p=0;p<S;p++) s += partial[(size_t)p*MN + idx];
  s += cv[idx % N];
  if (act) s = fmaxf(s,0.f);
  dst[idx]=s;
}

// fused: gates + cvec + LSTM step-1 pointwise; z written bf16
__global__ __launch_bounds__(256) void k_lstm_red(const float* __restrict__ pbuf,
                                                  const float* __restrict__ cvec,
                                                  const float* __restrict__ c0,
                                                  float* __restrict__ h1s, bf16t* __restrict__ z16){
  int t = blockIdx.x*256 + threadIdx.x;   // 512*768
  int m = t/D6, j = t - m*D6;
  const float* p0 = pbuf + (size_t)m*3072 + j;
  float g4[4];
  #pragma unroll
  for (int q=0;q<4;q++) g4[q] = cvec[q*D6 + j] + p0[q*D6];
  float c = sigf(g4[1])*c0[j] + sigf(g4[0])*tanhf(g4[2]);
  float h = sigf(g4[3])*tanhf(c);
  h1s[(size_t)m*D6 + j] = h;
  int side = m>>8, g = m&255;
  z16[(size_t)g*3072 + side*1536 + j] = f2bf(h);
}

// fused p2+p3: z2 = relu(z1@Wp2^T+bp2); out = sigmoid(z2@Wp3^T+bp3). block per batch row.
__global__ __launch_bounds__(128) void k_p23(const float* __restrict__ z1,
                                             const float* __restrict__ Wp2, const float* __restrict__ bp2,
                                             const float* __restrict__ Wp3, const float* __restrict__ bp3,
                                             float* __restrict__ out){
  __shared__ float zr[256];
  __shared__ float ws[2];
  int m = blockIdx.x, t = threadIdx.x;
  ((float2*)zr)[t] = ((const float2*)(z1 + m*256))[t];
  __syncthreads();
  const float4* wrow = (const float4*)(Wp2 + (size_t)t*256);
  const float4* z4 = (const float4*)zr;
  float acc = bp2[t];
  #pragma unroll 8
  for (int k=0;k<64;k++){
    float4 wv = wrow[k], zv = z4[k];
    acc += wv.x*zv.x + wv.y*zv.y + wv.z*zv.z + wv.w*zv.w;
  }
  float p = fmaxf(acc,0.f)*Wp3[t];
  #pragma unroll
  for (int o=32;o;o>>=1) p += __shfl_down(p,o,64);
  if ((t&63)==0) ws[t>>6]=p;
  __syncthreads();
  if (t==0){ float v=ws[0]+ws[1]+bp3[0]; out[m]=1.0f/(1.0f+__expf(-v)); }
}

// ---------- launch ----------

extern "C" void kernel_launch(void* const* d_in, const int* in_sizes, int n_in,
                              void* d_out, int out_size, void* d_ws, size_t ws_size,
                              hipStream_t stream){
  const float* feat1=(const float*)d_in[0];
  const float* feat2=(const float*)d_in[1];
  const float* ea1  =(const float*)d_in[2];
  const float* ea2  =(const float*)d_in[3];
  const float* W0=(const float*)d_in[4];  const float* b0=(const float*)d_in[5];
  const float* W1=(const float*)d_in[6];  const float* b1=(const float*)d_in[7];
  const float* W2=(const float*)d_in[8];  const float* b2=(const float*)d_in[9];
  const float* Wih=(const float*)d_in[10]; const float* bih=(const float*)d_in[11];
  const float* Whh=(const float*)d_in[12]; const float* bhh=(const float*)d_in[13];
  const float* Wp1=(const float*)d_in[14]; const float* bp1=(const float*)d_in[15];
  const float* Wp2=(const float*)d_in[16]; const float* bp2=(const float*)d_in[17];
  const float* Wp3=(const float*)d_in[18]; const float* bp3=(const float*)d_in[19];
  const int* ei1=(const int*)d_in[20]; const int* ei2=(const int*)d_in[21];
  const int* batch1=(const int*)d_in[22]; const int* batch2=(const int*)d_in[23];
  float* out = (float*)d_out;

  float* base = (float*)d_ws;
  size_t off = 0;
  auto alloc = [&](size_t n)->float* { float* r = base + off; off += (n + 255) & ~(size_t)255; return r; };
  float* deg1 = alloc(N_NODES);          float* deg2 = alloc(N_NODES);
  bf16t* xw1  = (bf16t*)alloc((size_t)N_NODES*NH/2);
  bf16t* xw2  = (bf16t*)alloc((size_t)N_NODES*NH/2);
  float* h1   = alloc((size_t)N_NODES*D3);
  float* h2   = alloc((size_t)N_NODES*D3);
  bf16t* f1   = (bf16t*)alloc((size_t)N_NODES*D6/2);
  bf16t* f2   = (bf16t*)alloc((size_t)N_NODES*D6/2);
  float* ecoef1 = alloc(N_EDGES);        float* ecoef2 = alloc(N_EDGES);
  float* h0   = alloc(D6);  float* c0 = alloc(D6);  float* cvec = alloc(4*D6);
  bf16t* Sbuf = (bf16t*)alloc((size_t)NB*SMM*SMM);       // S followed by ST
  bf16t* STbuf= Sbuf + (size_t)NB*SMM*SMM;
  float* h1s  = alloc((size_t)512*D6);
  bf16t* zbuf16 = (bf16t*)alloc((size_t)256*3072/2);
  float* z1   = alloc((size_t)256*256);
  float* pbuf = alloc((size_t)4*512*3072);
  short* Abuf16 = (short*)alloc((size_t)512*D6/2);
  short* Wih16  = (short*)alloc((size_t)3072*D6/2);
  short* Wp116  = (short*)alloc((size_t)256*3072/2);
  int* cnt1 = (int*)alloc(NB);   int* cnt2 = (int*)alloc(NB);
  int* st1  = (int*)alloc(NB+1); int* st2  = (int*)alloc(NB+1);
  int* ecnt1= (int*)alloc(N_NODES); int* ecnt2 = (int*)alloc(N_NODES);
  int* eoff1= (int*)alloc(N_NODES+1); int* eoff2 = (int*)alloc(N_NODES+1);
  int* ecur1= (int*)alloc(N_NODES); int* ecur2 = (int*)alloc(N_NODES);
  int* esrc1= (int*)alloc(N_EDGES); int* esrc2 = (int*)alloc(N_EDGES);
  (void)ws_size; (void)in_sizes; (void)n_in; (void)out_size;

  k_init   <<<32,256,0,stream>>>(deg1,deg2,ecnt1,ecnt2,cnt1,cnt2);
  k_deg    <<<1024,256,0,stream>>>(ei1,ea1,deg1,ecnt1, ei2,ea2,deg2,ecnt2, batch1,batch2,cnt1,cnt2);
  k_dinv   <<<32,256,0,stream>>>(deg1,deg2);
  k_scan256<<<2,256,0,stream>>>(cnt1,cnt2,st1,st2);
  k_escan  <<<2,1024,0,stream>>>(ecnt1,ecnt2,eoff1,ecur1,eoff2,ecur2);
  k_fill   <<<1024,256,0,stream>>>(ei1,ea1,deg1,ecur1,esrc1,ecoef1, ei2,ea2,deg2,ecur2,esrc2,ecoef2);
  k_conv_w <<<2304,256,0,stream>>>(Wih, Wih16);
  k_conv   <<<768,256,0,stream>>>(Wp1, Wp116);
  k_szero  <<<2304,256,0,stream>>>((uint4*)Sbuf);

  const float* Ws[3]={W0,W1,W2}; const float* bs[3]={b0,b1,b2};
  for (int l=0;l<3;l++){
    const float* x1 = (l==0)? feat1 : (h1 + (l-1)*NH);
    const float* x2 = (l==0)? feat2 : (h2 + (l-1)*NH);
    int xs = (l==0)? 64 : D3;
    int K  = (l==0)? 64 : NH;
    k_xw    <<<2048,128,0,stream>>>(x1,x2,xs,K,Ws[l],xw1,xw2);
    k_gather<<<2048,256,0,stream>>>(xw1,xw2,eoff1,eoff2,esrc1,esrc2,ecoef1,ecoef2,
                                    deg1,deg2,bs[l],h1,h2,l*NH);
  }

  k_l2norm<<<16384,128,0,stream>>>(h1,h2,f1,f2);
  k_smat  <<<dim3(256,9),256,0,stream>>>(f1,f2,st1,st2,Sbuf,STbuf);
  k_apply <<<dim3(512,3),256,0,stream>>>(f1,f2,st1,st2,Sbuf,STbuf);

  k_h0  <<<1,768,0,stream>>>(bih,bhh,h0,c0);
  k_cvec<<<3072,64,0,stream>>>(Wih,Whh,bih,bhh,h0,cvec);

  // step-1 attention (shared h0) -> Abuf16 bf16 rows [side*256+g]
  k_att<<<512,256,0,stream>>>(f1,f2,h0,0,st1,st2,(bf16t*)Abuf16,(long)256*D6,(long)D6);

  // gates via bf16 MFMA, fused reduce+LSTM (z in bf16)
  k_gemm_mfma<<<dim3(32,12),256,0,stream>>>(Abuf16, Wih16, pbuf);
  k_lstm_red <<<1536,256,0,stream>>>(pbuf,cvec,c0,h1s,zbuf16);

  // step-2 attention (per-segment h) -> zbuf16 r-slots (bf16)
  k_att<<<512,256,0,stream>>>(f1,f2,h1s,1,st1,st2,zbuf16+768,(long)1536,(long)3072);

  // MLP: p1 via MFMA + reduce(bias,relu); fused p2+p3
  k_gemm_mfma_p1<<<dim3(16,16),256,0,stream>>>((const short*)zbuf16, Wp116, pbuf);
  k_reduce <<<256,256,0,stream>>>(pbuf,16,(long)256*256, bp1, z1, 256, 1);
  k_p23 <<<256,128,0,stream>>>(z1, Wp2, bp2, Wp3, bp3, out);
}

// Round 14
// 389.016 us; speedup vs baseline: 1.2169x; 1.0128x over previous
//
#include <hip/hip_runtime.h>
#include <cmath>

#define N_NODES 8192
#define N_EDGES 131072
#define NB      256
#define NH      128
#define D3      384
#define D6      768
#define SMM     96   // max nodes per (graph,side); Binomial(8192,1/256) mean 32, 96 = 11 sigma

typedef __attribute__((ext_vector_type(8))) short short8v;
typedef __attribute__((ext_vector_type(4))) float f32x4;
typedef unsigned short bf16t;

__device__ __forceinline__ float sigf(float x){ return 1.0f/(1.0f+__expf(-x)); }
__device__ __forceinline__ unsigned short f2bf(float x){
  unsigned u = __float_as_uint(x);
  unsigned r = u + 0x7FFF + ((u>>16)&1);   // round-to-nearest-even
  return (unsigned short)(r>>16);
}
__device__ __forceinline__ float bfl(unsigned u){ return __uint_as_float(u<<16); }
__device__ __forceinline__ float bfh(unsigned u){ return __uint_as_float(u & 0xFFFF0000u); }
__device__ __forceinline__ float b2f(bf16t u){ return __uint_as_float(((unsigned)u)<<16); }
// h0[j] from LSTM step-0 collapse (q_star=h=c=0)
__device__ __forceinline__ float h0val(const float* bih, const float* bhh, int j){
  float c = sigf(bih[j]+bhh[j]) * tanhf(bih[2*D6+j]+bhh[2*D6+j]);
  return sigf(bih[3*D6+j]+bhh[3*D6+j]) * tanhf(c);
}

// ---------- setup ----------

__global__ void k_init(float* deg1, float* deg2, int* ecnt1, int* ecnt2, int* cnt1, int* cnt2){
  int t = blockIdx.x*blockDim.x + threadIdx.x;
  if (t < N_NODES){ deg1[t]=1.f; deg2[t]=1.f; ecnt1[t]=0; ecnt2[t]=0; }
  if (t < NB){ cnt1[t]=0; cnt2[t]=0; }
}

__global__ void k_deg(const int* __restrict__ ei1, const float* __restrict__ ea1, float* deg1, int* ecnt1,
                      const int* __restrict__ ei2, const float* __restrict__ ea2, float* deg2, int* ecnt2,
                      const int* __restrict__ b1, const int* __restrict__ b2, int* cnt1, int* cnt2){
  int idx = blockIdx.x*blockDim.x + threadIdx.x;
  int side = idx >= N_EDGES;
  int e = idx & (N_EDGES-1);
  const int* ei = side? ei2:ei1; const float* ea = side? ea2:ea1;
  float* deg = side? deg2:deg1;  int* ecnt = side? ecnt2:ecnt1;
  int d = ei[N_EDGES+e];
  atomicAdd(&deg[d], ea[e]);
  atomicAdd(&ecnt[d], 1);
  if (idx < N_NODES){ atomicAdd(&cnt1[b1[idx]],1); atomicAdd(&cnt2[b2[idx]],1); }
}

__global__ __launch_bounds__(256) void k_scan256(const int* c1, const int* c2, int* s1, int* s2){
  const int* c = blockIdx.x? c2:c1; int* st = blockIdx.x? s2:s1;
  __shared__ int ps[256];
  int t = threadIdx.x;
  ps[t]=c[t]; __syncthreads();
  for (int d=1; d<256; d<<=1){
    int v = (t>=d)? ps[t-d]:0;
    __syncthreads();
    ps[t]+=v;
    __syncthreads();
  }
  st[t+1]=ps[t];
  if (t==0) st[0]=0;
}

__global__ __launch_bounds__(1024) void k_escan(const int* ec1, const int* ec2,
                                                int* off1, int* cur1, int* off2, int* cur2){
  const int* cnt = blockIdx.x? ec2:ec1;
  int* off = blockIdx.x? off2:off1;
  int* cur = blockIdx.x? cur2:cur1;
  __shared__ int ps[1024];
  int t = threadIdx.x;
  int base = t*8;
  int loc[8]; int s=0;
  #pragma unroll
  for (int k=0;k<8;k++){ loc[k]=s; s+=cnt[base+k]; }
  ps[t]=s; __syncthreads();
  for (int d=1; d<1024; d<<=1){
    int v = (t>=d)? ps[t-d]:0;
    __syncthreads();
    ps[t]+=v;
    __syncthreads();
  }
  int pre = (t==0)? 0 : ps[t-1];
  #pragma unroll
  for (int k=0;k<8;k++){ int v=pre+loc[k]; off[base+k]=v; cur[base+k]=v; }
  if (t==1023) off[N_NODES]=ps[1023];
}

// CSR fill; norm coefficient rsqrt(deg_s)*w*rsqrt(deg_d) inline (k_dinv folded)
__global__ void k_fill(const int* __restrict__ ei1, const float* __restrict__ ea1, const float* __restrict__ d1,
                       int* cur1, int* es1, float* ec1,
                       const int* __restrict__ ei2, const float* __restrict__ ea2, const float* __restrict__ d2,
                       int* cur2, int* es2, float* ec2){
  int idx = blockIdx.x*blockDim.x + threadIdx.x;
  int side = idx >= N_EDGES;
  int e = idx & (N_EDGES-1);
  const int* ei = side? ei2:ei1; const float* ea = side? ea2:ea1;
  const float* deg = side? d2:d1;
  int* cur = side? cur2:cur1; int* es = side? es2:es1; float* ec = side? ec2:ec1;
  int s = ei[e], d = ei[N_EDGES+e];
  int pos = atomicAdd(&cur[d], 1);
  es[pos] = s;
  ec[pos] = rsqrtf(deg[s])*ea[e]*rsqrtf(deg[d]);
}

// zero S and ST: 2 * NB*96*96 bf16 = 589824 uint4
__global__ __launch_bounds__(256) void k_szero(uint4* p){
  p[blockIdx.x*256 + threadIdx.x] = make_uint4(0,0,0,0);
}

// ---------- GCN ----------

// xw = x@W in fp32, stored bf16
__global__ __launch_bounds__(128) void k_xw(const float* __restrict__ x1, const float* __restrict__ x2,
                                            int xs, int K, const float* __restrict__ W,
                                            bf16t* __restrict__ xw1, bf16t* __restrict__ xw2){
  __shared__ float xr[8][128];
  int blk = blockIdx.x;
  int side = blk >> 10; int b = blk & 1023;
  const float* x = side? x2:x1;
  bf16t* xw = side? xw2:xw1;
  int i0 = b*8;
  int c = threadIdx.x;
  for (int idx=c; idx<8*K; idx+=128){
    int r = idx / K, k = idx - r*K;
    xr[r][k] = x[(size_t)(i0+r)*xs + k];
  }
  __syncthreads();
  float acc[8]={0,0,0,0,0,0,0,0};
  for (int k=0;k<K;k++){
    float w = W[k*NH+c];
    #pragma unroll
    for (int r=0;r<8;r++) acc[r]+=xr[r][k]*w;
  }
  #pragma unroll
  for (int r=0;r<8;r++) xw[(size_t)(i0+r)*NH+c]=f2bf(acc[r]);
}

// fused self-loop + CSR gather + bias + leaky; l2mode: layers 0/1 write h fp32,
// layer 2 fuses l2-normalize over all 384 ch and writes bf16 f directly (no h write)
__global__ __launch_bounds__(256) void k_gather(const bf16t* __restrict__ xw1, const bf16t* __restrict__ xw2,
                                                const int* __restrict__ off1, const int* __restrict__ off2,
                                                const int* __restrict__ es1, const int* __restrict__ es2,
                                                const float* __restrict__ ec1, const float* __restrict__ ec2,
                                                const float* __restrict__ d1, const float* __restrict__ d2,
                                                const float* __restrict__ b,
                                                float* __restrict__ h1, float* __restrict__ h2, int loff,
                                                int l2mode, bf16t* __restrict__ f1, bf16t* __restrict__ f2){
  int blk = blockIdx.x;
  int side = blk >> 10; int bb = blk & 1023;
  const ushort4* xw = (const ushort4*)(side? xw2:xw1);
  const int* off = side? off2:off1;
  const int* es  = side? es2:es1;
  const float* ec= side? ec2:ec1;
  const float* deg = side? d2:d1;
  float* h = side? h2:h1;
  int t = threadIdx.x;
  int i = bb*8 + (t>>5);
  int c4 = t & 31;
  float sc = 1.0f/deg[i];
  ushort4 v = xw[(size_t)i*32 + c4];
  float4 acc = {b2f(v.x)*sc, b2f(v.y)*sc, b2f(v.z)*sc, b2f(v.w)*sc};
  int r = off[i], r1 = off[i+1];
  for (; r+3<r1; r+=4){
    int s0=es[r], s1=es[r+1], s2=es[r+2], s3=es[r+3];
    float w0=ec[r], w1=ec[r+1], w2=ec[r+2], w3=ec[r+3];
    ushort4 u0 = xw[(size_t)s0*32 + c4];
    ushort4 u1 = xw[(size_t)s1*32 + c4];
    ushort4 u2 = xw[(size_t)s2*32 + c4];
    ushort4 u3 = xw[(size_t)s3*32 + c4];
    acc.x += b2f(u0.x)*w0 + b2f(u1.x)*w1 + b2f(u2.x)*w2 + b2f(u3.x)*w3;
    acc.y += b2f(u0.y)*w0 + b2f(u1.y)*w1 + b2f(u2.y)*w2 + b2f(u3.y)*w3;
    acc.z += b2f(u0.z)*w0 + b2f(u1.z)*w1 + b2f(u2.z)*w2 + b2f(u3.z)*w3;
    acc.w += b2f(u0.w)*w0 + b2f(u1.w)*w1 + b2f(u2.w)*w2 + b2f(u3.w)*w3;
  }
  for (; r<r1; r++){
    int s0=es[r]; float w0=ec[r];
    ushort4 u0 = xw[(size_t)s0*32 + c4];
    acc.x+=b2f(u0.x)*w0; acc.y+=b2f(u0.y)*w0; acc.z+=b2f(u0.z)*w0; acc.w+=b2f(u0.w)*w0;
  }
  float4 bv = ((const float4*)b)[c4];
  acc.x+=bv.x; acc.y+=bv.y; acc.z+=bv.z; acc.w+=bv.w;
  acc.x = (acc.x>0.f)?acc.x:0.2f*acc.x;
  acc.y = (acc.y>0.f)?acc.y:0.2f*acc.y;
  acc.z = (acc.z>0.f)?acc.z:0.2f*acc.z;
  acc.w = (acc.w>0.f)?acc.w:0.2f*acc.w;
  if (!l2mode){
    ((float4*)(h + (size_t)i*D3 + loff))[c4] = acc;
  } else {
    // layer 2: fused l2-normalize; acc = channels 256+c4*4..+3
    float4 v0 = ((const float4*)(h + (size_t)i*D3))[c4];
    float4 v1 = ((const float4*)(h + (size_t)i*D3 + 128))[c4];
    float ss = v0.x*v0.x+v0.y*v0.y+v0.z*v0.z+v0.w*v0.w
             + v1.x*v1.x+v1.y*v1.y+v1.z*v1.z+v1.w*v1.w
             + acc.x*acc.x+acc.y*acc.y+acc.z*acc.z+acc.w*acc.w;
    #pragma unroll
    for (int m=1;m<32;m<<=1) ss += __shfl_xor(ss, m, 64);   // 32-lane node group
    float scale = 1.0f/fmaxf(sqrtf(ss), 1e-12f);
    bf16t* f = side? f2:f1;
    ((ushort4*)(f + (size_t)i*D6))[c4]       = make_ushort4(f2bf(v0.x*scale),f2bf(v0.y*scale),f2bf(v0.z*scale),f2bf(v0.w*scale));
    ((ushort4*)(f + (size_t)i*D6 + 128))[c4] = make_ushort4(f2bf(v1.x*scale),f2bf(v1.y*scale),f2bf(v1.z*scale),f2bf(v1.w*scale));
    ((ushort4*)(f + (size_t)i*D6 + 256))[c4] = make_ushort4(f2bf(acc.x*scale),f2bf(acc.y*scale),f2bf(acc.z*scale),f2bf(acc.w*scale));
  }
}

// ---------- interaction part 1 via MFMA: S = f1.f2^T, direct global frags ----------
__global__ __launch_bounds__(256) void k_smat(const bf16t* __restrict__ f1, const bf16t* __restrict__ f2,
                                              const int* __restrict__ st1, const int* __restrict__ st2,
                                              bf16t* __restrict__ S, bf16t* __restrict__ ST){
  int g = blockIdx.x;
  int it2 = blockIdx.y/3, jt2 = blockIdx.y - it2*3;
  int i0 = st1[g]; int n1 = st1[g+1]-i0; if (n1>SMM) n1=SMM;
  int j0 = st2[g]; int n2 = st2[g+1]-j0; if (n2>SMM) n2=SMM;
  if (it2*32 >= n1 || jt2*32 >= n2) return;
  int w = threadIdx.x >> 6, lane = threadIdx.x & 63;
  int lm = lane & 15, quad = lane >> 4;
  int ti = it2*2 + (w>>1), tj = jt2*2 + (w&1);
  if (ti*16 >= n1 || tj*16 >= n2) return;
  const bf16t* a = f1 + (size_t)(i0 + ti*16 + lm)*D6 + quad*8;
  const bf16t* b = f2 + (size_t)(j0 + tj*16 + lm)*D6 + quad*8;
  f32x4 acc = {0,0,0,0};
  #pragma unroll
  for (int k=0; k<384; k+=32){
    short8v af = *(const short8v*)(a + k);
    short8v bf = *(const short8v*)(b + k);
    acc = __builtin_amdgcn_mfma_f32_16x16x32_bf16(af, bf, acc, 0, 0, 0);
  }
  bf16t* Sg  = S  + (size_t)g*SMM*SMM;
  bf16t* STg = ST + (size_t)g*SMM*SMM;
  int col = tj*16 + lm;
  #pragma unroll
  for (int r=0;r<4;r++){
    int row = ti*16 + quad*4 + r;
    if (row < n1 && col < n2){
      bf16t v = f2bf(acc[r]);
      Sg [(size_t)row*SMM + col] = v;
      STg[(size_t)col*SMM + row] = v;
    }
  }
}

// ---------- interaction part 2 via MFMA ----------
__global__ __launch_bounds__(256) void k_apply(bf16t* __restrict__ f1, bf16t* __restrict__ f2,
                                               const int* __restrict__ st1, const int* __restrict__ st2,
                                               const bf16t* __restrict__ S, const bf16t* __restrict__ ST){
  __shared__ bf16t tbuf[32*392];   // 24.5 KB
  int bx = blockIdx.x;
  int side = bx >> 8, g = bx & (NB-1);
  int a0 = st1[g]; int n1 = st1[g+1]-a0; if (n1>SMM) n1=SMM;
  int b0 = st2[g]; int n2 = st2[g+1]-b0; if (n2>SMM) n2=SMM;
  int cnt = side? n2 : n1;
  int J   = side? n1 : n2;
  int r0 = blockIdx.y*32;
  if (r0 >= cnt) return;
  const bf16t* src = side? (f1 + (size_t)a0*D6) : (f2 + (size_t)b0*D6);
  bf16t* dst = (side? (f2 + (size_t)b0*D6) : (f1 + (size_t)a0*D6)) + D3;
  const bf16t* Sg = (side? ST : S) + (size_t)g*SMM*SMM;
  int t = threadIdx.x, w = t>>6, lane = t&63;
  int lm = lane & 15, quad = lane >> 4;
  int mt1 = (cnt - r0 > 16) ? 2 : 1;
  f32x4 acc[2][6] = {};
  for (int kb = 0; kb < J; kb += 32){
    __syncthreads();
    for (int idx = t; idx < 32*48; idx += 256){
      int j = idx/48, cg = idx - j*48;
      uint4 v = (kb+j < J)? ((const uint4*)(src + (size_t)(kb+j)*D6))[cg] : make_uint4(0,0,0,0);
      *(uint4*)(tbuf + j*392 + cg*8) = v;
    }
    short8v af0, af1;
    {
      const bf16t* ap = Sg + (size_t)(r0 + lm)*SMM + kb + quad*8;
      af0 = *(const short8v*)ap;
      af1 = (mt1 > 1)? *(const short8v*)(ap + 16*SMM) : af0;
    }
    __syncthreads();
    #pragma unroll
    for (int ni = 0; ni < 6; ni++){
      int nt = w*6 + ni;
      short8v bf;
      #pragma unroll
      for (int ji = 0; ji < 8; ji++)
        bf[ji] = (short)tbuf[(quad*8 + ji)*392 + nt*16 + lm];
      acc[0][ni] = __builtin_amdgcn_mfma_f32_16x16x32_bf16(af0, bf, acc[0][ni], 0, 0, 0);
      if (mt1 > 1)
        acc[1][ni] = __builtin_amdgcn_mfma_f32_16x16x32_bf16(af1, bf, acc[1][ni], 0, 0, 0);
    }
  }
  for (int mt = 0; mt < mt1; mt++)
    for (int ni = 0; ni < 6; ni++){
      int nt = w*6 + ni;
      #pragma unroll
      for (int r = 0; r < 4; r++){
        int row = r0 + mt*16 + quad*4 + r;
        if (row < cnt) dst[(size_t)row*D6 + nt*16 + lm] = f2bf(acc[mt][ni][r]);
      }
    }
}

// ---------- set2set ----------

// cvec[j] = h0 . (Wih[j,0:768]+Whh[j,:]) + bih[j]+bhh[j]; h0 computed inline per block
__global__ __launch_bounds__(64) void k_cvec(const float* __restrict__ Wih, const float* __restrict__ Whh,
                                             const float* __restrict__ bih, const float* __restrict__ bhh,
                                             float* __restrict__ cvec){
  __shared__ float hs[D6];
  int j = blockIdx.x, lane = threadIdx.x;
  for (int k=lane; k<D6; k+=64) hs[k] = h0val(bih,bhh,k);
  __syncthreads();
  const float4* wi = (const float4*)(Wih + (size_t)j*(2*D6));
  const float4* wh = (const float4*)(Whh + (size_t)j*D6);
  const float4* h4 = (const float4*)hs;
  float acc=0;
  #pragma unroll
  for (int m=0;m<3;m++){
    float4 hv = h4[m*64+lane];
    float4 a = wi[m*64+lane];
    float4 b = wh[m*64+lane];
    acc += hv.x*(a.x+b.x) + hv.y*(a.y+b.y) + hv.z*(a.z+b.z) + hv.w*(a.w+b.w);
  }
  #pragma unroll
  for (int m=1;m<64;m<<=1) acc += __shfl_xor(acc,m,64);
  if (lane==0) cvec[j]=acc+bih[j]+bhh[j];
}

// fused attention: e=x.hv, segment softmax, r=sum a*x (wave-parallel); x bf16; r bf16.
// perseg=0: hv = h0 computed inline from biases; perseg=1: hv = hbase row.
__global__ __launch_bounds__(256) void k_att(const bf16t* __restrict__ f1, const bf16t* __restrict__ f2,
                                             const float* __restrict__ hbase, int perseg,
                                             const float* __restrict__ bih, const float* __restrict__ bhh,
                                             const int* __restrict__ st1, const int* __restrict__ st2,
                                             bf16t* __restrict__ dst16, long sidestep, long dstride){
  __shared__ float4 hs[192];
  __shared__ float e_s[SMM];
  __shared__ float part[4][D6];   // 12 KB wave partials
  int side = blockIdx.x >> 8, g = blockIdx.x & (NB-1);
  const int* st = side? st2:st1;
  int n0 = st[g]; int cnt = st[g+1]-n0; if (cnt>SMM) cnt=SMM;
  const bf16t* x = (side? f2:f1) + (size_t)n0*D6;
  int t = threadIdx.x, w = t>>6, lane = t&63;
  if (t<192){
    if (perseg){
      hs[t] = ((const float4*)(hbase + (size_t)(side*NB+g)*D6))[t];
    } else {
      int j = t*4;
      hs[t] = make_float4(h0val(bih,bhh,j), h0val(bih,bhh,j+1), h0val(bih,bhh,j+2), h0val(bih,bhh,j+3));
    }
  }
  __syncthreads();
  for (int n=w; n<cnt; n+=4){
    const uint2* xr = (const uint2*)(x + (size_t)n*D6);
    float p = 0;
    #pragma unroll
    for (int m=0;m<3;m++){
      uint2 rv = xr[m*64+lane];
      float4 hvv = hs[m*64+lane];
      p += bfl(rv.x)*hvv.x + bfh(rv.x)*hvv.y + bfl(rv.y)*hvv.z + bfh(rv.y)*hvv.w;
    }
    #pragma unroll
    for (int m=1;m<64;m<<=1) p += __shfl_xor(p,m,64);
    if (lane==0) e_s[n]=p;
  }
  __syncthreads();
  if (w==0){
    float mx=-INFINITY;
    for (int n=lane;n<cnt;n+=64) mx=fmaxf(mx,e_s[n]);
    #pragma unroll
    for (int m=1;m<64;m<<=1) mx=fmaxf(mx,__shfl_xor(mx,m,64));
    float s=0;
    for (int n=lane;n<cnt;n+=64) s+=__expf(e_s[n]-mx);
    #pragma unroll
    for (int m=1;m<64;m<<=1) s+=__shfl_xor(s,m,64);
    float inv=1.0f/s;
    for (int n=lane;n<cnt;n+=64) e_s[n]=__expf(e_s[n]-mx)*inv;
  }
  __syncthreads();
  // r-phase: each wave accumulates its nodes; lane owns 12 channels
  float av[3][4] = {};
  for (int n=w; n<cnt; n+=4){
    float a = e_s[n];
    const uint2* xr = (const uint2*)(x + (size_t)n*D6);
    #pragma unroll
    for (int m=0;m<3;m++){
      uint2 rv = xr[m*64+lane];
      av[m][0]+=a*bfl(rv.x); av[m][1]+=a*bfh(rv.x); av[m][2]+=a*bfl(rv.y); av[m][3]+=a*bfh(rv.y);
    }
  }
  #pragma unroll
  for (int m=0;m<3;m++)
    *(float4*)&part[w][(m*64+lane)*4] = make_float4(av[m][0],av[m][1],av[m][2],av[m][3]);
  __syncthreads();
  if (t<192){
    float4 p0 = *(const float4*)&part[0][t*4];
    float4 p1 = *(const float4*)&part[1][t*4];
    float4 p2 = *(const float4*)&part[2][t*4];
    float4 p3 = *(const float4*)&part[3][t*4];
    float4 s = make_float4(p0.x+p1.x+p2.x+p3.x, p0.y+p1.y+p2.y+p3.y,
                           p0.z+p1.z+p2.z+p3.z, p0.w+p1.w+p2.w+p3.w);
    ushort4 o = make_ushort4(f2bf(s.x), f2bf(s.y), f2bf(s.z), f2bf(s.w));
    ((ushort4*)(dst16 + side*sidestep + (size_t)g*dstride))[t]=o;
  }
}

// gates GEMM via bf16 MFMA: pout[512][3072]
__global__ __launch_bounds__(256) void k_gemm_mfma(const short* __restrict__ A16,
                                                   const short* __restrict__ B16,
                                                   float* __restrict__ pout){
  int w = threadIdx.x >> 6, lane = threadIdx.x & 63;
  int lm = lane & 15, quad = lane >> 4;
  int bm = blockIdx.x * 16;
  int bn = blockIdx.y * 256 + w * 64;
  const short* a = A16 + (size_t)(bm + lm)*768 + quad*8;
  const short* b = B16 + (size_t)(bn + lm)*768 + quad*8;
  f32x4 acc0={0,0,0,0}, acc1={0,0,0,0}, acc2={0,0,0,0}, acc3={0,0,0,0};
  for (int k=0; k<768; k+=32){
    short8v af = *(const short8v*)(a + k);
    short8v b0 = *(const short8v*)(b + k);
    short8v b1 = *(const short8v*)(b + 16*768 + k);
    short8v b2 = *(const short8v*)(b + 32*768 + k);
    short8v b3 = *(const short8v*)(b + 48*768 + k);
    acc0 = __builtin_amdgcn_mfma_f32_16x16x32_bf16(af, b0, acc0, 0, 0, 0);
    acc1 = __builtin_amdgcn_mfma_f32_16x16x32_bf16(af, b1, acc1, 0, 0, 0);
    acc2 = __builtin_amdgcn_mfma_f32_16x16x32_bf16(af, b2, acc2, 0, 0, 0);
    acc3 = __builtin_amdgcn_mfma_f32_16x16x32_bf16(af, b3, acc3, 0, 0, 0);
  }
  #pragma unroll
  for (int r=0;r<4;r++){
    size_t base = (size_t)(bm + quad*4 + r)*3072 + bn + lm;
    pout[base]      = acc0[r];
    pout[base + 16] = acc1[r];
    pout[base + 32] = acc2[r];
    pout[base + 48] = acc3[r];
  }
}

// p1 GEMM via MFMA, split-K=16: pout[z][256x256]
__global__ __launch_bounds__(256) void k_gemm_mfma_p1(const short* __restrict__ A16,
                                                      const short* __restrict__ B16,
                                                      float* __restrict__ pout){
  int w = threadIdx.x >> 6, lane = threadIdx.x & 63;
  int lm = lane & 15, quad = lane >> 4;
  int bm = blockIdx.x * 16;
  int bn = w * 64;
  int kbase = blockIdx.y * 192;
  const short* a = A16 + (size_t)(bm + lm)*3072 + quad*8 + kbase;
  const short* b = B16 + (size_t)(bn + lm)*3072 + quad*8 + kbase;
  f32x4 acc0={0,0,0,0}, acc1={0,0,0,0}, acc2={0,0,0,0}, acc3={0,0,0,0};
  for (int k=0; k<192; k+=32){
    short8v af = *(const short8v*)(a + k);
    short8v b0 = *(const short8v*)(b + k);
    short8v b1 = *(const short8v*)(b + 16*3072 + k);
    short8v b2 = *(const short8v*)(b + 32*3072 + k);
    short8v b3 = *(const short8v*)(b + 48*3072 + k);
    acc0 = __builtin_amdgcn_mfma_f32_16x16x32_bf16(af, b0, acc0, 0, 0, 0);
    acc1 = __builtin_amdgcn_mfma_f32_16x16x32_bf16(af, b1, acc1, 0, 0, 0);
    acc2 = __builtin_amdgcn_mfma_f32_16x16x32_bf16(af, b2, acc2, 0, 0, 0);
    acc3 = __builtin_amdgcn_mfma_f32_16x16x32_bf16(af, b3, acc3, 0, 0, 0);
  }
  float* po = pout + (size_t)blockIdx.y*256*256;
  #pragma unroll
  for (int r=0;r<4;r++){
    size_t base = (size_t)(bm + quad*4 + r)*256 + bn + lm;
    po[base]      = acc0[r];
    po[base + 16] = acc1[r];
    po[base + 32] = acc2[r];
    po[base + 48] = acc3[r];
  }
}

// Wih right half -> contiguous bf16 [3072][768]
__global__ __launch_bounds__(256) void k_conv_w(const float* __restrict__ W, short* __restrict__ dst){
  int t = blockIdx.x*256 + threadIdx.x;
  int n = t/192, q = t - n*192;
  float4 v = ((const float4*)(W + (size_t)n*1536 + 768))[q];
  short4 o = { (short)f2bf(v.x), (short)f2bf(v.y), (short)f2bf(v.z), (short)f2bf(v.w) };
  ((short4*)dst)[t] = o;
}

// generic fp32 -> bf16 contiguous convert
__global__ __launch_bounds__(256) void k_conv(const float* __restrict__ src, short* __restrict__ dst){
  int t = blockIdx.x*256 + threadIdx.x;
  float4 v = ((const float4*)src)[t];
  short4 o = { (short)f2bf(v.x), (short)f2bf(v.y), (short)f2bf(v.z), (short)f2bf(v.w) };
  ((short4*)dst)[t] = o;
}

// fused: gates + cvec + LSTM step-1 pointwise; c0 inline from biases; z bf16
__global__ __launch_bounds__(256) void k_lstm_red(const float* __restrict__ pbuf,
                                                  const float* __restrict__ cvec,
                                                  const float* __restrict__ bih, const float* __restrict__ bhh,
                                                  float* __restrict__ h1s, bf16t* __restrict__ z16){
  int t = blockIdx.x*256 + threadIdx.x;   // 512*768
  int m = t/D6, j = t - m*D6;
  const float* p0 = pbuf + (size_t)m*3072 + j;
  float g4[4];
  #pragma unroll
  for (int q=0;q<4;q++) g4[q] = cvec[q*D6 + j] + p0[q*D6];
  float c0j = sigf(bih[j]+bhh[j]) * tanhf(bih[2*D6+j]+bhh[2*D6+j]);
  float c = sigf(g4[1])*c0j + sigf(g4[0])*tanhf(g4[2]);
  float h = sigf(g4[3])*tanhf(c);
  h1s[(size_t)m*D6 + j] = h;
  int side = m>>8, g = m&255;
  z16[(size_t)g*3072 + side*1536 + j] = f2bf(h);
}

// fused p1-reduce + p2 + p3: block per batch row
__global__ __launch_bounds__(128) void k_p23(const float* __restrict__ pbuf, const float* __restrict__ bp1,
                                             const float* __restrict__ Wp2, const float* __restrict__ bp2,
                                             const float* __restrict__ Wp3, const float* __restrict__ bp3,
                                             float* __restrict__ out){
  __shared__ float zr[256];
  __shared__ float ws[2];
  int m = blockIdx.x, t = threadIdx.x;
  // z1[m, 2t..2t+1] = relu(sum_16 partials + bias)
  float2 zacc = ((const float2*)(bp1))[t];
  #pragma unroll
  for (int p=0;p<16;p++){
    float2 v = ((const float2*)(pbuf + (size_t)p*256*256 + (size_t)m*256))[t];
    zacc.x += v.x; zacc.y += v.y;
  }
  zr[2*t]   = fmaxf(zacc.x, 0.f);
  zr[2*t+1] = fmaxf(zacc.y, 0.f);
  __syncthreads();
  const float4* wrow = (const float4*)(Wp2 + (size_t)t*256);
  const float4* z4 = (const float4*)zr;
  float acc = bp2[t];
  #pragma unroll 8
  for (int k=0;k<64;k++){
    float4 wv = wrow[k], zv = z4[k];
    acc += wv.x*zv.x + wv.y*zv.y + wv.z*zv.z + wv.w*zv.w;
  }
  float p = fmaxf(acc,0.f)*Wp3[t];
  #pragma unroll
  for (int o=32;o;o>>=1) p += __shfl_down(p,o,64);
  if ((t&63)==0) ws[t>>6]=p;
  __syncthreads();
  if (t==0){ float v=ws[0]+ws[1]+bp3[0]; out[m]=1.0f/(1.0f+__expf(-v)); }
}

// ---------- launch ----------

extern "C" void kernel_launch(void* const* d_in, const int* in_sizes, int n_in,
                              void* d_out, int out_size, void* d_ws, size_t ws_size,
                              hipStream_t stream){
  const float* feat1=(const float*)d_in[0];
  const float* feat2=(const float*)d_in[1];
  const float* ea1  =(const float*)d_in[2];
  const float* ea2  =(const float*)d_in[3];
  const float* W0=(const float*)d_in[4];  const float* b0=(const float*)d_in[5];
  const float* W1=(const float*)d_in[6];  const float* b1=(const float*)d_in[7];
  const float* W2=(const float*)d_in[8];  const float* b2=(const float*)d_in[9];
  const float* Wih=(const float*)d_in[10]; const float* bih=(const float*)d_in[11];
  const float* Whh=(const float*)d_in[12]; const float* bhh=(const float*)d_in[13];
  const float* Wp1=(const float*)d_in[14]; const float* bp1=(const float*)d_in[15];
  const float* Wp2=(const float*)d_in[16]; const float* bp2=(const float*)d_in[17];
  const float* Wp3=(const float*)d_in[18]; const float* bp3=(const float*)d_in[19];
  const int* ei1=(const int*)d_in[20]; const int* ei2=(const int*)d_in[21];
  const int* batch1=(const int*)d_in[22]; const int* batch2=(const int*)d_in[23];
  float* out = (float*)d_out;

  float* base = (float*)d_ws;
  size_t off = 0;
  auto alloc = [&](size_t n)->float* { float* r = base + off; off += (n + 255) & ~(size_t)255; return r; };
  float* deg1 = alloc(N_NODES);          float* deg2 = alloc(N_NODES);
  bf16t* xw1  = (bf16t*)alloc((size_t)N_NODES*NH/2);
  bf16t* xw2  = (bf16t*)alloc((size_t)N_NODES*NH/2);
  float* h1   = alloc((size_t)N_NODES*D3);
  float* h2   = alloc((size_t)N_NODES*D3);
  bf16t* f1   = (bf16t*)alloc((size_t)N_NODES*D6/2);
  bf16t* f2   = (bf16t*)alloc((size_t)N_NODES*D6/2);
  float* ecoef1 = alloc(N_EDGES);        float* ecoef2 = alloc(N_EDGES);
  float* cvec = alloc(4*D6);
  bf16t* Sbuf = (bf16t*)alloc((size_t)NB*SMM*SMM);       // S followed by ST
  bf16t* STbuf= Sbuf + (size_t)NB*SMM*SMM;
  float* h1s  = alloc((size_t)512*D6);
  bf16t* zbuf16 = (bf16t*)alloc((size_t)256*3072/2);
  float* pbuf = alloc((size_t)4*512*3072);
  short* Abuf16 = (short*)alloc((size_t)512*D6/2);
  short* Wih16  = (short*)alloc((size_t)3072*D6/2);
  short* Wp116  = (short*)alloc((size_t)256*3072/2);
  int* cnt1 = (int*)alloc(NB);   int* cnt2 = (int*)alloc(NB);
  int* st1  = (int*)alloc(NB+1); int* st2  = (int*)alloc(NB+1);
  int* ecnt1= (int*)alloc(N_NODES); int* ecnt2 = (int*)alloc(N_NODES);
  int* eoff1= (int*)alloc(N_NODES+1); int* eoff2 = (int*)alloc(N_NODES+1);
  int* ecur1= (int*)alloc(N_NODES); int* ecur2 = (int*)alloc(N_NODES);
  int* esrc1= (int*)alloc(N_EDGES); int* esrc2 = (int*)alloc(N_EDGES);
  (void)ws_size; (void)in_sizes; (void)n_in; (void)out_size;

  k_init   <<<32,256,0,stream>>>(deg1,deg2,ecnt1,ecnt2,cnt1,cnt2);
  k_deg    <<<1024,256,0,stream>>>(ei1,ea1,deg1,ecnt1, ei2,ea2,deg2,ecnt2, batch1,batch2,cnt1,cnt2);
  k_scan256<<<2,256,0,stream>>>(cnt1,cnt2,st1,st2);
  k_escan  <<<2,1024,0,stream>>>(ecnt1,ecnt2,eoff1,ecur1,eoff2,ecur2);
  k_fill   <<<1024,256,0,stream>>>(ei1,ea1,deg1,ecur1,esrc1,ecoef1, ei2,ea2,deg2,ecur2,esrc2,ecoef2);
  k_conv_w <<<2304,256,0,stream>>>(Wih, Wih16);
  k_conv   <<<768,256,0,stream>>>(Wp1, Wp116);
  k_szero  <<<2304,256,0,stream>>>((uint4*)Sbuf);

  const float* Ws[3]={W0,W1,W2}; const float* bs[3]={b0,b1,b2};
  for (int l=0;l<3;l++){
    const float* x1 = (l==0)? feat1 : (h1 + (l-1)*NH);
    const float* x2 = (l==0)? feat2 : (h2 + (l-1)*NH);
    int xs = (l==0)? 64 : D3;
    int K  = (l==0)? 64 : NH;
    k_xw    <<<2048,128,0,stream>>>(x1,x2,xs,K,Ws[l],xw1,xw2);
    k_gather<<<2048,256,0,stream>>>(xw1,xw2,eoff1,eoff2,esrc1,esrc2,ecoef1,ecoef2,
                                    deg1,deg2,bs[l],h1,h2,l*NH,(l==2)?1:0,f1,f2);
  }

  k_smat  <<<dim3(256,9),256,0,stream>>>(f1,f2,st1,st2,Sbuf,STbuf);
  k_apply <<<dim3(512,3),256,0,stream>>>(f1,f2,st1,st2,Sbuf,STbuf);

  k_cvec<<<3072,64,0,stream>>>(Wih,Whh,bih,bhh,cvec);

  // step-1 attention (inline h0) -> Abuf16 bf16 rows [side*256+g]
  k_att<<<512,256,0,stream>>>(f1,f2,(const float*)nullptr,0,bih,bhh,st1,st2,
                              (bf16t*)Abuf16,(long)256*D6,(long)D6);

  // gates via bf16 MFMA, fused reduce+LSTM (c0 inline, z bf16)
  k_gemm_mfma<<<dim3(32,12),256,0,stream>>>(Abuf16, Wih16, pbuf);
  k_lstm_red <<<1536,256,0,stream>>>(pbuf,cvec,bih,bhh,h1s,zbuf16);

  // step-2 attention (per-segment h) -> zbuf16 r-slots
  k_att<<<512,256,0,stream>>>(f1,f2,h1s,1,bih,bhh,st1,st2,
                              zbuf16+768,(long)1536,(long)3072);

  // MLP: p1 via MFMA; fused reduce+p2+p3
  k_gemm_mfma_p1<<<dim3(16,16),256,0,stream>>>((const short*)zbuf16, Wp116, pbuf);
  k_p23 <<<256,128,0,stream>>>(pbuf, bp1, Wp2, bp2, Wp3, bp3, out);
}

// Round 15
// 374.979 us; speedup vs baseline: 1.2624x; 1.0374x over previous
//
#include <hip/hip_runtime.h>
#include <cmath>

#define N_NODES 8192
#define N_EDGES 131072
#define NB      256
#define NH      128
#define D3      384
#define D6      768
#define SMM     96   // max nodes per (graph,side); Binomial(8192,1/256) mean 32, 96 = 11 sigma

typedef __attribute__((ext_vector_type(8))) short short8v;
typedef __attribute__((ext_vector_type(4))) float f32x4;
typedef unsigned short bf16t;

__device__ __forceinline__ float sigf(float x){ return 1.0f/(1.0f+__expf(-x)); }
__device__ __forceinline__ unsigned short f2bf(float x){
  unsigned u = __float_as_uint(x);
  unsigned r = u + 0x7FFF + ((u>>16)&1);   // round-to-nearest-even
  return (unsigned short)(r>>16);
}
__device__ __forceinline__ float bfl(unsigned u){ return __uint_as_float(u<<16); }
__device__ __forceinline__ float bfh(unsigned u){ return __uint_as_float(u & 0xFFFF0000u); }
__device__ __forceinline__ float b2f(bf16t u){ return __uint_as_float(((unsigned)u)<<16); }
// h0[j] from LSTM step-0 collapse (q_star=h=c=0)
__device__ __forceinline__ float h0val(const float* bih, const float* bhh, int j){
  float c = sigf(bih[j]+bhh[j]) * tanhf(bih[2*D6+j]+bhh[2*D6+j]);
  return sigf(bih[3*D6+j]+bhh[3*D6+j]) * tanhf(c);
}

// ---------- setup ----------

__global__ void k_init(float* deg1, float* deg2, int* ecnt1, int* ecnt2, int* cnt1, int* cnt2){
  int t = blockIdx.x*blockDim.x + threadIdx.x;
  if (t < N_NODES){ deg1[t]=1.f; deg2[t]=1.f; ecnt1[t]=0; ecnt2[t]=0; }
  if (t < NB){ cnt1[t]=0; cnt2[t]=0; }
}

__global__ void k_deg(const int* __restrict__ ei1, const float* __restrict__ ea1, float* deg1, int* ecnt1,
                      const int* __restrict__ ei2, const float* __restrict__ ea2, float* deg2, int* ecnt2,
                      const int* __restrict__ b1, const int* __restrict__ b2, int* cnt1, int* cnt2){
  int idx = blockIdx.x*blockDim.x + threadIdx.x;
  int side = idx >= N_EDGES;
  int e = idx & (N_EDGES-1);
  const int* ei = side? ei2:ei1; const float* ea = side? ea2:ea1;
  float* deg = side? deg2:deg1;  int* ecnt = side? ecnt2:ecnt1;
  int d = ei[N_EDGES+e];
  atomicAdd(&deg[d], ea[e]);
  atomicAdd(&ecnt[d], 1);
  if (idx < N_NODES){ atomicAdd(&cnt1[b1[idx]],1); atomicAdd(&cnt2[b2[idx]],1); }
}

__global__ __launch_bounds__(256) void k_scan256(const int* c1, const int* c2, int* s1, int* s2){
  const int* c = blockIdx.x? c2:c1; int* st = blockIdx.x? s2:s1;
  __shared__ int ps[256];
  int t = threadIdx.x;
  ps[t]=c[t]; __syncthreads();
  for (int d=1; d<256; d<<=1){
    int v = (t>=d)? ps[t-d]:0;
    __syncthreads();
    ps[t]+=v;
    __syncthreads();
  }
  st[t+1]=ps[t];
  if (t==0) st[0]=0;
}

__global__ __launch_bounds__(1024) void k_escan(const int* ec1, const int* ec2,
                                                int* off1, int* cur1, int* off2, int* cur2){
  const int* cnt = blockIdx.x? ec2:ec1;
  int* off = blockIdx.x? off2:off1;
  int* cur = blockIdx.x? cur2:cur1;
  __shared__ int ps[1024];
  int t = threadIdx.x;
  int base = t*8;
  int loc[8]; int s=0;
  #pragma unroll
  for (int k=0;k<8;k++){ loc[k]=s; s+=cnt[base+k]; }
  ps[t]=s; __syncthreads();
  for (int d=1; d<1024; d<<=1){
    int v = (t>=d)? ps[t-d]:0;
    __syncthreads();
    ps[t]+=v;
    __syncthreads();
  }
  int pre = (t==0)? 0 : ps[t-1];
  #pragma unroll
  for (int k=0;k<8;k++){ int v=pre+loc[k]; off[base+k]=v; cur[base+k]=v; }
  if (t==1023) off[N_NODES]=ps[1023];
}

// CSR fill; norm coefficient rsqrt(deg_s)*w*rsqrt(deg_d) inline
__global__ void k_fill(const int* __restrict__ ei1, const float* __restrict__ ea1, const float* __restrict__ d1,
                       int* cur1, int* es1, float* ec1,
                       const int* __restrict__ ei2, const float* __restrict__ ea2, const float* __restrict__ d2,
                       int* cur2, int* es2, float* ec2){
  int idx = blockIdx.x*blockDim.x + threadIdx.x;
  int side = idx >= N_EDGES;
  int e = idx & (N_EDGES-1);
  const int* ei = side? ei2:ei1; const float* ea = side? ea2:ea1;
  const float* deg = side? d2:d1;
  int* cur = side? cur2:cur1; int* es = side? es2:es1; float* ec = side? ec2:ec1;
  int s = ei[e], d = ei[N_EDGES+e];
  int pos = atomicAdd(&cur[d], 1);
  es[pos] = s;
  ec[pos] = rsqrtf(deg[s])*ea[e]*rsqrtf(deg[d]);
}

// zero S and ST: 2 * NB*96*96 bf16 = 589824 uint4
__global__ __launch_bounds__(256) void k_szero(uint4* p){
  p[blockIdx.x*256 + threadIdx.x] = make_uint4(0,0,0,0);
}

// both feats fp32 -> bf16 (2 x 131072 float4)
__global__ __launch_bounds__(256) void k_conv2(const float* __restrict__ a, const float* __restrict__ b,
                                               short* __restrict__ da, short* __restrict__ db){
  int t = blockIdx.x*256 + threadIdx.x;
  int side = t >= 131072; int i = t & 131071;
  float4 v = ((const float4*)(side? b:a))[i];
  short4 o = { (short)f2bf(v.x), (short)f2bf(v.y), (short)f2bf(v.z), (short)f2bf(v.w) };
  ((short4*)(side? db:da))[i] = o;
}

// transpose W_l [K x 128] fp32 -> Wt_l [128 x K] bf16; grid(3)
__global__ __launch_bounds__(256) void k_wt(const float* __restrict__ W0, const float* __restrict__ W1,
                                            const float* __restrict__ W2, bf16t* __restrict__ Wt){
  int l = blockIdx.x;
  const float* W = (l==0)? W0 : ((l==1)? W1 : W2);
  int K = (l==0)? 64 : 128;
  bf16t* dst = Wt + ((l==0)? 0 : ((l==1)? 128*64 : 128*64+128*128));
  for (int idx = threadIdx.x; idx < 128*K; idx += 256){
    int n = idx / K, k = idx - n*K;
    dst[idx] = f2bf(W[k*NH + n]);
  }
}

// ---------- GCN ----------

// xw = x @ W via MFMA; x bf16 (k-slice contiguous, row stride xs), Wt bf16 [128][K]
// grid 512: side*256+b; block 4 waves = 32 rows x 128 cols
__global__ __launch_bounds__(256) void k_xw_mfma(const bf16t* __restrict__ x1, const bf16t* __restrict__ x2,
                                                 int xs, int K, const bf16t* __restrict__ Wt,
                                                 bf16t* __restrict__ xw1, bf16t* __restrict__ xw2){
  int blk = blockIdx.x;
  int side = blk >> 8; int b = blk & 255;
  const bf16t* x = side? x2:x1;
  bf16t* xw = side? xw2:xw1;
  int w = threadIdx.x>>6, lane = threadIdx.x&63;
  int lm = lane&15, quad = lane>>4;
  int r0 = b*32 + (w>>1)*16;
  int c0 = (w&1)*64;
  const bf16t* a = x + (size_t)(r0+lm)*xs + quad*8;
  f32x4 acc[4] = {};
  for (int k=0;k<K;k+=32){
    short8v af = *(const short8v*)(a + k);
    #pragma unroll
    for (int ni=0;ni<4;ni++){
      short8v bf = *(const short8v*)(Wt + (size_t)(c0+ni*16+lm)*K + quad*8 + k);
      acc[ni] = __builtin_amdgcn_mfma_f32_16x16x32_bf16(af, bf, acc[ni], 0,0,0);
    }
  }
  #pragma unroll
  for (int ni=0;ni<4;ni++)
    #pragma unroll
    for (int r=0;r<4;r++){
      int row = r0 + quad*4 + r, col = c0 + ni*16 + lm;
      xw[(size_t)row*NH + col] = f2bf(acc[ni][r]);
    }
}

// fused self-loop + CSR gather + bias + leaky; h bf16; layer 2 fuses l2norm -> f bf16
__global__ __launch_bounds__(256) void k_gather(const bf16t* __restrict__ xw1, const bf16t* __restrict__ xw2,
                                                const int* __restrict__ off1, const int* __restrict__ off2,
                                                const int* __restrict__ es1, const int* __restrict__ es2,
                                                const float* __restrict__ ec1, const float* __restrict__ ec2,
                                                const float* __restrict__ d1, const float* __restrict__ d2,
                                                const float* __restrict__ b,
                                                bf16t* __restrict__ h1, bf16t* __restrict__ h2, int loff,
                                                int l2mode, bf16t* __restrict__ f1, bf16t* __restrict__ f2){
  int blk = blockIdx.x;
  int side = blk >> 10; int bb = blk & 1023;
  const ushort4* xw = (const ushort4*)(side? xw2:xw1);
  const int* off = side? off2:off1;
  const int* es  = side? es2:es1;
  const float* ec= side? ec2:ec1;
  const float* deg = side? d2:d1;
  bf16t* h = side? h2:h1;
  int t = threadIdx.x;
  int i = bb*8 + (t>>5);
  int c4 = t & 31;
  float sc = 1.0f/deg[i];
  ushort4 v = xw[(size_t)i*32 + c4];
  float4 acc = {b2f(v.x)*sc, b2f(v.y)*sc, b2f(v.z)*sc, b2f(v.w)*sc};
  int r = off[i], r1 = off[i+1];
  for (; r+3<r1; r+=4){
    int s0=es[r], s1=es[r+1], s2=es[r+2], s3=es[r+3];
    float w0=ec[r], w1=ec[r+1], w2=ec[r+2], w3=ec[r+3];
    ushort4 u0 = xw[(size_t)s0*32 + c4];
    ushort4 u1 = xw[(size_t)s1*32 + c4];
    ushort4 u2 = xw[(size_t)s2*32 + c4];
    ushort4 u3 = xw[(size_t)s3*32 + c4];
    acc.x += b2f(u0.x)*w0 + b2f(u1.x)*w1 + b2f(u2.x)*w2 + b2f(u3.x)*w3;
    acc.y += b2f(u0.y)*w0 + b2f(u1.y)*w1 + b2f(u2.y)*w2 + b2f(u3.y)*w3;
    acc.z += b2f(u0.z)*w0 + b2f(u1.z)*w1 + b2f(u2.z)*w2 + b2f(u3.z)*w3;
    acc.w += b2f(u0.w)*w0 + b2f(u1.w)*w1 + b2f(u2.w)*w2 + b2f(u3.w)*w3;
  }
  for (; r<r1; r++){
    int s0=es[r]; float w0=ec[r];
    ushort4 u0 = xw[(size_t)s0*32 + c4];
    acc.x+=b2f(u0.x)*w0; acc.y+=b2f(u0.y)*w0; acc.z+=b2f(u0.z)*w0; acc.w+=b2f(u0.w)*w0;
  }
  float4 bv = ((const float4*)b)[c4];
  acc.x+=bv.x; acc.y+=bv.y; acc.z+=bv.z; acc.w+=bv.w;
  acc.x = (acc.x>0.f)?acc.x:0.2f*acc.x;
  acc.y = (acc.y>0.f)?acc.y:0.2f*acc.y;
  acc.z = (acc.z>0.f)?acc.z:0.2f*acc.z;
  acc.w = (acc.w>0.f)?acc.w:0.2f*acc.w;
  if (!l2mode){
    ((ushort4*)(h + (size_t)i*D3 + loff))[c4] =
      make_ushort4(f2bf(acc.x), f2bf(acc.y), f2bf(acc.z), f2bf(acc.w));
  } else {
    // layer 2: fused l2-normalize over all 384 ch; acc = channels 256..383
    ushort4 u0 = ((const ushort4*)(h + (size_t)i*D3))[c4];
    ushort4 u1 = ((const ushort4*)(h + (size_t)i*D3 + 128))[c4];
    float4 v0 = {b2f(u0.x), b2f(u0.y), b2f(u0.z), b2f(u0.w)};
    float4 v1 = {b2f(u1.x), b2f(u1.y), b2f(u1.z), b2f(u1.w)};
    float ss = v0.x*v0.x+v0.y*v0.y+v0.z*v0.z+v0.w*v0.w
             + v1.x*v1.x+v1.y*v1.y+v1.z*v1.z+v1.w*v1.w
             + acc.x*acc.x+acc.y*acc.y+acc.z*acc.z+acc.w*acc.w;
    #pragma unroll
    for (int m=1;m<32;m<<=1) ss += __shfl_xor(ss, m, 64);   // 32-lane node group
    float scale = 1.0f/fmaxf(sqrtf(ss), 1e-12f);
    bf16t* f = side? f2:f1;
    ((ushort4*)(f + (size_t)i*D6))[c4]       = make_ushort4(f2bf(v0.x*scale),f2bf(v0.y*scale),f2bf(v0.z*scale),f2bf(v0.w*scale));
    ((ushort4*)(f + (size_t)i*D6 + 128))[c4] = make_ushort4(f2bf(v1.x*scale),f2bf(v1.y*scale),f2bf(v1.z*scale),f2bf(v1.w*scale));
    ((ushort4*)(f + (size_t)i*D6 + 256))[c4] = make_ushort4(f2bf(acc.x*scale),f2bf(acc.y*scale),f2bf(acc.z*scale),f2bf(acc.w*scale));
  }
}

// ---------- interaction part 1 via MFMA: S = f1.f2^T, direct global frags ----------
__global__ __launch_bounds__(256) void k_smat(const bf16t* __restrict__ f1, const bf16t* __restrict__ f2,
                                              const int* __restrict__ st1, const int* __restrict__ st2,
                                              bf16t* __restrict__ S, bf16t* __restrict__ ST){
  int g = blockIdx.x;
  int it2 = blockIdx.y/3, jt2 = blockIdx.y - it2*3;
  int i0 = st1[g]; int n1 = st1[g+1]-i0; if (n1>SMM) n1=SMM;
  int j0 = st2[g]; int n2 = st2[g+1]-j0; if (n2>SMM) n2=SMM;
  if (it2*32 >= n1 || jt2*32 >= n2) return;
  int w = threadIdx.x >> 6, lane = threadIdx.x & 63;
  int lm = lane & 15, quad = lane >> 4;
  int ti = it2*2 + (w>>1), tj = jt2*2 + (w&1);
  if (ti*16 >= n1 || tj*16 >= n2) return;
  const bf16t* a = f1 + (size_t)(i0 + ti*16 + lm)*D6 + quad*8;
  const bf16t* b = f2 + (size_t)(j0 + tj*16 + lm)*D6 + quad*8;
  f32x4 acc = {0,0,0,0};
  #pragma unroll
  for (int k=0; k<384; k+=32){
    short8v af = *(const short8v*)(a + k);
    short8v bf = *(const short8v*)(b + k);
    acc = __builtin_amdgcn_mfma_f32_16x16x32_bf16(af, bf, acc, 0, 0, 0);
  }
  bf16t* Sg  = S  + (size_t)g*SMM*SMM;
  bf16t* STg = ST + (size_t)g*SMM*SMM;
  int col = tj*16 + lm;
  #pragma unroll
  for (int r=0;r<4;r++){
    int row = ti*16 + quad*4 + r;
    if (row < n1 && col < n2){
      bf16t v = f2bf(acc[r]);
      Sg [(size_t)row*SMM + col] = v;
      STg[(size_t)col*SMM + row] = v;
    }
  }
}

// ---------- interaction part 2 via MFMA ----------
__global__ __launch_bounds__(256) void k_apply(bf16t* __restrict__ f1, bf16t* __restrict__ f2,
                                               const int* __restrict__ st1, const int* __restrict__ st2,
                                               const bf16t* __restrict__ S, const bf16t* __restrict__ ST){
  __shared__ bf16t tbuf[32*392];   // 24.5 KB
  int bx = blockIdx.x;
  int side = bx >> 8, g = bx & (NB-1);
  int a0 = st1[g]; int n1 = st1[g+1]-a0; if (n1>SMM) n1=SMM;
  int b0 = st2[g]; int n2 = st2[g+1]-b0; if (n2>SMM) n2=SMM;
  int cnt = side? n2 : n1;
  int J   = side? n1 : n2;
  int r0 = blockIdx.y*32;
  if (r0 >= cnt) return;
  const bf16t* src = side? (f1 + (size_t)a0*D6) : (f2 + (size_t)b0*D6);
  bf16t* dst = (side? (f2 + (size_t)b0*D6) : (f1 + (size_t)a0*D6)) + D3;
  const bf16t* Sg = (side? ST : S) + (size_t)g*SMM*SMM;
  int t = threadIdx.x, w = t>>6, lane = t&63;
  int lm = lane & 15, quad = lane >> 4;
  int mt1 = (cnt - r0 > 16) ? 2 : 1;
  f32x4 acc[2][6] = {};
  for (int kb = 0; kb < J; kb += 32){
    __syncthreads();
    for (int idx = t; idx < 32*48; idx += 256){
      int j = idx/48, cg = idx - j*48;
      uint4 v = (kb+j < J)? ((const uint4*)(src + (size_t)(kb+j)*D6))[cg] : make_uint4(0,0,0,0);
      *(uint4*)(tbuf + j*392 + cg*8) = v;
    }
    short8v af0, af1;
    {
      const bf16t* ap = Sg + (size_t)(r0 + lm)*SMM + kb + quad*8;
      af0 = *(const short8v*)ap;
      af1 = (mt1 > 1)? *(const short8v*)(ap + 16*SMM) : af0;
    }
    __syncthreads();
    #pragma unroll
    for (int ni = 0; ni < 6; ni++){
      int nt = w*6 + ni;
      short8v bf;
      #pragma unroll
      for (int ji = 0; ji < 8; ji++)
        bf[ji] = (short)tbuf[(quad*8 + ji)*392 + nt*16 + lm];
      acc[0][ni] = __builtin_amdgcn_mfma_f32_16x16x32_bf16(af0, bf, acc[0][ni], 0, 0, 0);
      if (mt1 > 1)
        acc[1][ni] = __builtin_amdgcn_mfma_f32_16x16x32_bf16(af1, bf, acc[1][ni], 0, 0, 0);
    }
  }
  for (int mt = 0; mt < mt1; mt++)
    for (int ni = 0; ni < 6; ni++){
      int nt = w*6 + ni;
      #pragma unroll
      for (int r = 0; r < 4; r++){
        int row = r0 + mt*16 + quad*4 + r;
        if (row < cnt) dst[(size_t)row*D6 + nt*16 + lm] = f2bf(acc[mt][ni][r]);
      }
    }
}

// ---------- set2set ----------

// cvec[j] = h0 . (Wih[j,0:768]+Whh[j,:]) + bih[j]+bhh[j]; h0 computed inline per block
__global__ __launch_bounds__(64) void k_cvec(const float* __restrict__ Wih, const float* __restrict__ Whh,
                                             const float* __restrict__ bih, const float* __restrict__ bhh,
                                             float* __restrict__ cvec){
  __shared__ float hs[D6];
  int j = blockIdx.x, lane = threadIdx.x;
  for (int k=lane; k<D6; k+=64) hs[k] = h0val(bih,bhh,k);
  __syncthreads();
  const float4* wi = (const float4*)(Wih + (size_t)j*(2*D6));
  const float4* wh = (const float4*)(Whh + (size_t)j*D6);
  const float4* h4 = (const float4*)hs;
  float acc=0;
  #pragma unroll
  for (int m=0;m<3;m++){
    float4 hv = h4[m*64+lane];
    float4 a = wi[m*64+lane];
    float4 b = wh[m*64+lane];
    acc += hv.x*(a.x+b.x) + hv.y*(a.y+b.y) + hv.z*(a.z+b.z) + hv.w*(a.w+b.w);
  }
  #pragma unroll
  for (int m=1;m<64;m<<=1) acc += __shfl_xor(acc,m,64);
  if (lane==0) cvec[j]=acc+bih[j]+bhh[j];
}

// fused attention: e=x.hv, segment softmax, r=sum a*x (wave-parallel); x bf16; r bf16
__global__ __launch_bounds__(256) void k_att(const bf16t* __restrict__ f1, const bf16t* __restrict__ f2,
                                             const float* __restrict__ hbase, int perseg,
                                             const float* __restrict__ bih, const float* __restrict__ bhh,
                                             const int* __restrict__ st1, const int* __restrict__ st2,
                                             bf16t* __restrict__ dst16, long sidestep, long dstride){
  __shared__ float4 hs[192];
  __shared__ float e_s[SMM];
  __shared__ float part[4][D6];
  int side = blockIdx.x >> 8, g = blockIdx.x & (NB-1);
  const int* st = side? st2:st1;
  int n0 = st[g]; int cnt = st[g+1]-n0; if (cnt>SMM) cnt=SMM;
  const bf16t* x = (side? f2:f1) + (size_t)n0*D6;
  int t = threadIdx.x, w = t>>6, lane = t&63;
  if (t<192){
    if (perseg){
      hs[t] = ((const float4*)(hbase + (size_t)(side*NB+g)*D6))[t];
    } else {
      int j = t*4;
      hs[t] = make_float4(h0val(bih,bhh,j), h0val(bih,bhh,j+1), h0val(bih,bhh,j+2), h0val(bih,bhh,j+3));
    }
  }
  __syncthreads();
  for (int n=w; n<cnt; n+=4){
    const uint2* xr = (const uint2*)(x + (size_t)n*D6);
    float p = 0;
    #pragma unroll
    for (int m=0;m<3;m++){
      uint2 rv = xr[m*64+lane];
      float4 hvv = hs[m*64+lane];
      p += bfl(rv.x)*hvv.x + bfh(rv.x)*hvv.y + bfl(rv.y)*hvv.z + bfh(rv.y)*hvv.w;
    }
    #pragma unroll
    for (int m=1;m<64;m<<=1) p += __shfl_xor(p,m,64);
    if (lane==0) e_s[n]=p;
  }
  __syncthreads();
  if (w==0){
    float mx=-INFINITY;
    for (int n=lane;n<cnt;n+=64) mx=fmaxf(mx,e_s[n]);
    #pragma unroll
    for (int m=1;m<64;m<<=1) mx=fmaxf(mx,__shfl_xor(mx,m,64));
    float s=0;
    for (int n=lane;n<cnt;n+=64) s+=__expf(e_s[n]-mx);
    #pragma unroll
    for (int m=1;m<64;m<<=1) s+=__shfl_xor(s,m,64);
    float inv=1.0f/s;
    for (int n=lane;n<cnt;n+=64) e_s[n]=__expf(e_s[n]-mx)*inv;
  }
  __syncthreads();
  float av[3][4] = {};
  for (int n=w; n<cnt; n+=4){
    float a = e_s[n];
    const uint2* xr = (const uint2*)(x + (size_t)n*D6);
    #pragma unroll
    for (int m=0;m<3;m++){
      uint2 rv = xr[m*64+lane];
      av[m][0]+=a*bfl(rv.x); av[m][1]+=a*bfh(rv.x); av[m][2]+=a*bfl(rv.y); av[m][3]+=a*bfh(rv.y);
    }
  }
  #pragma unroll
  for (int m=0;m<3;m++)
    *(float4*)&part[w][(m*64+lane)*4] = make_float4(av[m][0],av[m][1],av[m][2],av[m][3]);
  __syncthreads();
  if (t<192){
    float4 p0 = *(const float4*)&part[0][t*4];
    float4 p1 = *(const float4*)&part[1][t*4];
    float4 p2 = *(const float4*)&part[2][t*4];
    float4 p3 = *(const float4*)&part[3][t*4];
    float4 s = make_float4(p0.x+p1.x+p2.x+p3.x, p0.y+p1.y+p2.y+p3.y,
                           p0.z+p1.z+p2.z+p3.z, p0.w+p1.w+p2.w+p3.w);
    ushort4 o = make_ushort4(f2bf(s.x), f2bf(s.y), f2bf(s.z), f2bf(s.w));
    ((ushort4*)(dst16 + side*sidestep + (size_t)g*dstride))[t]=o;
  }
}

// gates GEMM via bf16 MFMA: pout[512][3072]
__global__ __launch_bounds__(256) void k_gemm_mfma(const short* __restrict__ A16,
                                                   const short* __restrict__ B16,
                                                   float* __restrict__ pout){
  int w = threadIdx.x >> 6, lane = threadIdx.x & 63;
  int lm = lane & 15, quad = lane >> 4;
  int bm = blockIdx.x * 16;
  int bn = blockIdx.y * 256 + w * 64;
  const short* a = A16 + (size_t)(bm + lm)*768 + quad*8;
  const short* b = B16 + (size_t)(bn + lm)*768 + quad*8;
  f32x4 acc0={0,0,0,0}, acc1={0,0,0,0}, acc2={0,0,0,0}, acc3={0,0,0,0};
  for (int k=0; k<768; k+=32){
    short8v af = *(const short8v*)(a + k);
    short8v b0 = *(const short8v*)(b + k);
    short8v b1 = *(const short8v*)(b + 16*768 + k);
    short8v b2 = *(const short8v*)(b + 32*768 + k);
    short8v b3 = *(const short8v*)(b + 48*768 + k);
    acc0 = __builtin_amdgcn_mfma_f32_16x16x32_bf16(af, b0, acc0, 0, 0, 0);
    acc1 = __builtin_amdgcn_mfma_f32_16x16x32_bf16(af, b1, acc1, 0, 0, 0);
    acc2 = __builtin_amdgcn_mfma_f32_16x16x32_bf16(af, b2, acc2, 0, 0, 0);
    acc3 = __builtin_amdgcn_mfma_f32_16x16x32_bf16(af, b3, acc3, 0, 0, 0);
  }
  #pragma unroll
  for (int r=0;r<4;r++){
    size_t base = (size_t)(bm + quad*4 + r)*3072 + bn + lm;
    pout[base]      = acc0[r];
    pout[base + 16] = acc1[r];
    pout[base + 32] = acc2[r];
    pout[base + 48] = acc3[r];
  }
}

// p1 GEMM via MFMA, split-K=16: pout[z][256x256]
__global__ __launch_bounds__(256) void k_gemm_mfma_p1(const short* __restrict__ A16,
                                                      const short* __restrict__ B16,
                                                      float* __restrict__ pout){
  int w = threadIdx.x >> 6, lane = threadIdx.x & 63;
  int lm = lane & 15, quad = lane >> 4;
  int bm = blockIdx.x * 16;
  int bn = w * 64;
  int kbase = blockIdx.y * 192;
  const short* a = A16 + (size_t)(bm + lm)*3072 + quad*8 + kbase;
  const short* b = B16 + (size_t)(bn + lm)*3072 + quad*8 + kbase;
  f32x4 acc0={0,0,0,0}, acc1={0,0,0,0}, acc2={0,0,0,0}, acc3={0,0,0,0};
  for (int k=0; k<192; k+=32){
    short8v af = *(const short8v*)(a + k);
    short8v b0 = *(const short8v*)(b + k);
    short8v b1 = *(const short8v*)(b + 16*3072 + k);
    short8v b2 = *(const short8v*)(b + 32*3072 + k);
    short8v b3 = *(const short8v*)(b + 48*3072 + k);
    acc0 = __builtin_amdgcn_mfma_f32_16x16x32_bf16(af, b0, acc0, 0, 0, 0);
    acc1 = __builtin_amdgcn_mfma_f32_16x16x32_bf16(af, b1, acc1, 0, 0, 0);
    acc2 = __builtin_amdgcn_mfma_f32_16x16x32_bf16(af, b2, acc2, 0, 0, 0);
    acc3 = __builtin_amdgcn_mfma_f32_16x16x32_bf16(af, b3, acc3, 0, 0, 0);
  }
  float* po = pout + (size_t)blockIdx.y*256*256;
  #pragma unroll
  for (int r=0;r<4;r++){
    size_t base = (size_t)(bm + quad*4 + r)*256 + bn + lm;
    po[base]      = acc0[r];
    po[base + 16] = acc1[r];
    po[base + 32] = acc2[r];
    po[base + 48] = acc3[r];
  }
}

// Wih right half -> contiguous bf16 [3072][768]
__global__ __launch_bounds__(256) void k_conv_w(const float* __restrict__ W, short* __restrict__ dst){
  int t = blockIdx.x*256 + threadIdx.x;
  int n = t/192, q = t - n*192;
  float4 v = ((const float4*)(W + (size_t)n*1536 + 768))[q];
  short4 o = { (short)f2bf(v.x), (short)f2bf(v.y), (short)f2bf(v.z), (short)f2bf(v.w) };
  ((short4*)dst)[t] = o;
}

// generic fp32 -> bf16 contiguous convert
__global__ __launch_bounds__(256) void k_conv(const float* __restrict__ src, short* __restrict__ dst){
  int t = blockIdx.x*256 + threadIdx.x;
  float4 v = ((const float4*)src)[t];
  short4 o = { (short)f2bf(v.x), (short)f2bf(v.y), (short)f2bf(v.z), (short)f2bf(v.w) };
  ((short4*)dst)[t] = o;
}

// fused: gates + cvec + LSTM step-1 pointwise; c0 inline; z bf16
__global__ __launch_bounds__(256) void k_lstm_red(const float* __restrict__ pbuf,
                                                  const float* __restrict__ cvec,
                                                  const float* __restrict__ bih, const float* __restrict__ bhh,
                                                  float* __restrict__ h1s, bf16t* __restrict__ z16){
  int t = blockIdx.x*256 + threadIdx.x;   // 512*768
  int m = t/D6, j = t - m*D6;
  const float* p0 = pbuf + (size_t)m*3072 + j;
  float g4[4];
  #pragma unroll
  for (int q=0;q<4;q++) g4[q] = cvec[q*D6 + j] + p0[q*D6];
  float c0j = sigf(bih[j]+bhh[j]) * tanhf(bih[2*D6+j]+bhh[2*D6+j]);
  float c = sigf(g4[1])*c0j + sigf(g4[0])*tanhf(g4[2]);
  float h = sigf(g4[3])*tanhf(c);
  h1s[(size_t)m*D6 + j] = h;
  int side = m>>8, g = m&255;
  z16[(size_t)g*3072 + side*1536 + j] = f2bf(h);
}

// fused p1-reduce + p2 + p3: block per batch row
__global__ __launch_bounds__(128) void k_p23(const float* __restrict__ pbuf, const float* __restrict__ bp1,
                                             const float* __restrict__ Wp2, const float* __restrict__ bp2,
                                             const float* __restrict__ Wp3, const float* __restrict__ bp3,
                                             float* __restrict__ out){
  __shared__ float zr[256];
  __shared__ float ws[2];
  int m = blockIdx.x, t = threadIdx.x;
  float2 zacc = ((const float2*)(bp1))[t];
  #pragma unroll
  for (int p=0;p<16;p++){
    float2 v = ((const float2*)(pbuf + (size_t)p*256*256 + (size_t)m*256))[t];
    zacc.x += v.x; zacc.y += v.y;
  }
  zr[2*t]   = fmaxf(zacc.x, 0.f);
  zr[2*t+1] = fmaxf(zacc.y, 0.f);
  __syncthreads();
  const float4* wrow = (const float4*)(Wp2 + (size_t)t*256);
  const float4* z4 = (const float4*)zr;
  float acc = bp2[t];
  #pragma unroll 8
  for (int k=0;k<64;k++){
    float4 wv = wrow[k], zv = z4[k];
    acc += wv.x*zv.x + wv.y*zv.y + wv.z*zv.z + wv.w*zv.w;
  }
  float p = fmaxf(acc,0.f)*Wp3[t];
  #pragma unroll
  for (int o=32;o;o>>=1) p += __shfl_down(p,o,64);
  if ((t&63)==0) ws[t>>6]=p;
  __syncthreads();
  if (t==0){ float v=ws[0]+ws[1]+bp3[0]; out[m]=1.0f/(1.0f+__expf(-v)); }
}

// ---------- launch ----------

extern "C" void kernel_launch(void* const* d_in, const int* in_sizes, int n_in,
                              void* d_out, int out_size, void* d_ws, size_t ws_size,
                              hipStream_t stream){
  const float* feat1=(const float*)d_in[0];
  const float* feat2=(const float*)d_in[1];
  const float* ea1  =(const float*)d_in[2];
  const float* ea2  =(const float*)d_in[3];
  const float* W0=(const float*)d_in[4];  const float* b0=(const float*)d_in[5];
  const float* W1=(const float*)d_in[6];  const float* b1=(const float*)d_in[7];
  const float* W2=(const float*)d_in[8];  const float* b2=(const float*)d_in[9];
  const float* Wih=(const float*)d_in[10]; const float* bih=(const float*)d_in[11];
  const float* Whh=(const float*)d_in[12]; const float* bhh=(const float*)d_in[13];
  const float* Wp1=(const float*)d_in[14]; const float* bp1=(const float*)d_in[15];
  const float* Wp2=(const float*)d_in[16]; const float* bp2=(const float*)d_in[17];
  const float* Wp3=(const float*)d_in[18]; const float* bp3=(const float*)d_in[19];
  const int* ei1=(const int*)d_in[20]; const int* ei2=(const int*)d_in[21];
  const int* batch1=(const int*)d_in[22]; const int* batch2=(const int*)d_in[23];
  float* out = (float*)d_out;

  float* base = (float*)d_ws;
  size_t off = 0;
  auto alloc = [&](size_t n)->float* { float* r = base + off; off += (n + 255) & ~(size_t)255; return r; };
  float* deg1 = alloc(N_NODES);          float* deg2 = alloc(N_NODES);
  bf16t* xw1  = (bf16t*)alloc((size_t)N_NODES*NH/2);
  bf16t* xw2  = (bf16t*)alloc((size_t)N_NODES*NH/2);
  bf16t* hb1  = (bf16t*)alloc((size_t)N_NODES*D3/2);
  bf16t* hb2  = (bf16t*)alloc((size_t)N_NODES*D3/2);
  bf16t* xf1  = (bf16t*)alloc((size_t)N_NODES*64/2);
  bf16t* xf2  = (bf16t*)alloc((size_t)N_NODES*64/2);
  bf16t* Wtb  = (bf16t*)alloc((size_t)(128*64 + 2*128*128)/2);
  bf16t* f1   = (bf16t*)alloc((size_t)N_NODES*D6/2);
  bf16t* f2   = (bf16t*)alloc((size_t)N_NODES*D6/2);
  float* ecoef1 = alloc(N_EDGES);        float* ecoef2 = alloc(N_EDGES);
  float* cvec = alloc(4*D6);
  bf16t* Sbuf = (bf16t*)alloc((size_t)NB*SMM*SMM);       // S followed by ST
  bf16t* STbuf= Sbuf + (size_t)NB*SMM*SMM;
  float* h1s  = alloc((size_t)512*D6);
  bf16t* zbuf16 = (bf16t*)alloc((size_t)256*3072/2);
  float* pbuf = alloc((size_t)4*512*3072);
  short* Abuf16 = (short*)alloc((size_t)512*D6/2);
  short* Wih16  = (short*)alloc((size_t)3072*D6/2);
  short* Wp116  = (short*)alloc((size_t)256*3072/2);
  int* cnt1 = (int*)alloc(NB);   int* cnt2 = (int*)alloc(NB);
  int* st1  = (int*)alloc(NB+1); int* st2  = (int*)alloc(NB+1);
  int* ecnt1= (int*)alloc(N_NODES); int* ecnt2 = (int*)alloc(N_NODES);
  int* eoff1= (int*)alloc(N_NODES+1); int* eoff2 = (int*)alloc(N_NODES+1);
  int* ecur1= (int*)alloc(N_NODES); int* ecur2 = (int*)alloc(N_NODES);
  int* esrc1= (int*)alloc(N_EDGES); int* esrc2 = (int*)alloc(N_EDGES);
  (void)ws_size; (void)in_sizes; (void)n_in; (void)out_size;

  k_init   <<<32,256,0,stream>>>(deg1,deg2,ecnt1,ecnt2,cnt1,cnt2);
  k_deg    <<<1024,256,0,stream>>>(ei1,ea1,deg1,ecnt1, ei2,ea2,deg2,ecnt2, batch1,batch2,cnt1,cnt2);
  k_scan256<<<2,256,0,stream>>>(cnt1,cnt2,st1,st2);
  k_escan  <<<2,1024,0,stream>>>(ecnt1,ecnt2,eoff1,ecur1,eoff2,ecur2);
  k_fill   <<<1024,256,0,stream>>>(ei1,ea1,deg1,ecur1,esrc1,ecoef1, ei2,ea2,deg2,ecur2,esrc2,ecoef2);
  k_conv_w <<<2304,256,0,stream>>>(Wih, Wih16);
  k_conv   <<<768,256,0,stream>>>(Wp1, Wp116);
  k_conv2  <<<1024,256,0,stream>>>(feat1, feat2, (short*)xf1, (short*)xf2);
  k_wt     <<<3,256,0,stream>>>(W0, W1, W2, Wtb);
  k_szero  <<<2304,256,0,stream>>>((uint4*)Sbuf);

  const float* bs[3]={b0,b1,b2};
  const bf16t* Wts[3]={Wtb, Wtb+128*64, Wtb+128*64+128*128};
  for (int l=0;l<3;l++){
    const bf16t* x1 = (l==0)? xf1 : (hb1 + (l-1)*NH);
    const bf16t* x2 = (l==0)? xf2 : (hb2 + (l-1)*NH);
    int xs = (l==0)? 64 : D3;
    int K  = (l==0)? 64 : NH;
    k_xw_mfma<<<512,256,0,stream>>>(x1,x2,xs,K,Wts[l],xw1,xw2);
    k_gather <<<2048,256,0,stream>>>(xw1,xw2,eoff1,eoff2,esrc1,esrc2,ecoef1,ecoef2,
                                     deg1,deg2,bs[l],hb1,hb2,l*NH,(l==2)?1:0,f1,f2);
  }

  k_smat  <<<dim3(256,9),256,0,stream>>>(f1,f2,st1,st2,Sbuf,STbuf);
  k_apply <<<dim3(512,3),256,0,stream>>>(f1,f2,st1,st2,Sbuf,STbuf);

  k_cvec<<<3072,64,0,stream>>>(Wih,Whh,bih,bhh,cvec);

  // step-1 attention (inline h0) -> Abuf16 bf16 rows [side*256+g]
  k_att<<<512,256,0,stream>>>(f1,f2,(const float*)nullptr,0,bih,bhh,st1,st2,
                              (bf16t*)Abuf16,(long)256*D6,(long)D6);

  // gates via bf16 MFMA, fused reduce+LSTM
  k_gemm_mfma<<<dim3(32,12),256,0,stream>>>(Abuf16, Wih16, pbuf);
  k_lstm_red <<<1536,256,0,stream>>>(pbuf,cvec,bih,bhh,h1s,zbuf16);

  // step-2 attention (per-segment h) -> zbuf16 r-slots
  k_att<<<512,256,0,stream>>>(f1,f2,h1s,1,bih,bhh,st1,st2,
                              zbuf16+768,(long)1536,(long)3072);

  // MLP: p1 via MFMA; fused reduce+p2+p3
  k_gemm_mfma_p1<<<dim3(16,16),256,0,stream>>>((const short*)zbuf16, Wp116, pbuf);
  k_p23 <<<256,128,0,stream>>>(pbuf, bp1, Wp2, bp2, Wp3, bp3, out);
}